// Round 1
// baseline (99617.487 us; speedup 1.0000x reference)
//
#include <hip/hip_runtime.h>
#include <hip/hip_bf16.h>
#include <math.h>

// ============================================================================
// GMMLoss2_pca: PCA(top-128 of 1024-dim Gram) + per-label Gaussian KL on MI355X
// Strategy: result is invariant to orthogonal basis of the top-128 eigenspace
// of C = xc^T xc, so compute that subspace via cushioned subspace iteration
// (m=256) + Rayleigh-Ritz (Householder tridiag + Sturm + inverse iteration),
// then evaluate the reference math literally from z = xc W.
// ============================================================================

#define B_N 8192
#define D_N 1024
#define K_N 128
#define M_N 256   // cushion size
#define NLAB 10

__device__ __forceinline__ float hashf(unsigned x) {
  x ^= x >> 16; x *= 0x7feb352du; x ^= x >> 15; x *= 0x846ca68bu; x ^= x >> 16;
  return (float)(x >> 8) * (1.0f / 16777216.0f) - 0.5f;
}

// ---------------------------------------------------------------------------
// Generic tiled f32 GEMM: C[i][j] = alpha * sum_k A(k,i)*B(k,j)  (+ epilogue)
// AKM=true : A element (k,i) at A[k*lda+i]   (used for X^T X style)
// AKM=false: A element (i,k) at A[i*lda+k]   (row-major A)
// B always (k,j) at B[k*ldb+j].
// Epilogue: + r1c*u[i]*v[j]  + raddc*radd[j] + addI*(i==j)
// M,N multiples of 64; K multiple of 32.
// ---------------------------------------------------------------------------
struct GArgs {
  const float* A; const float* B; float* C;
  int lda, ldb, ldc, K;
  float alpha;
  const float* r1u; const float* r1v; float r1c;
  const float* radd; float raddc;
  float addI;
};

template <bool AKM>
__global__ __launch_bounds__(256)
void gemm_k(GArgs g) {
  __shared__ __align__(16) float AsRaw[2176]; // AKM: [32][68]; !AKM: [64][33]
  __shared__ __align__(16) float Bs[32 * 68];
  const int tid = threadIdx.x;
  const int tx = tid & 15, ty = tid >> 4;
  const int i0 = blockIdx.x * 64, j0 = blockIdx.y * 64;
  float acc[4][4] = {};
  for (int k0 = 0; k0 < g.K; k0 += 32) {
    if (AKM) {
#pragma unroll
      for (int p = 0; p < 8; ++p) {
        int idx = tid + p * 256;
        int kk = idx >> 6, ii = idx & 63;
        AsRaw[kk * 68 + ii] = g.A[(size_t)(k0 + kk) * g.lda + i0 + ii];
      }
    } else {
#pragma unroll
      for (int p = 0; p < 8; ++p) {
        int idx = tid + p * 256;
        int ii = idx >> 5, kk = idx & 31;
        AsRaw[ii * 33 + kk] = g.A[(size_t)(i0 + ii) * g.lda + k0 + kk];
      }
    }
#pragma unroll
    for (int p = 0; p < 8; ++p) {
      int idx = tid + p * 256;
      int kk = idx >> 6, jj = idx & 63;
      Bs[kk * 68 + jj] = g.B[(size_t)(k0 + kk) * g.ldb + j0 + jj];
    }
    __syncthreads();
#pragma unroll 8
    for (int kk = 0; kk < 32; ++kk) {
      float ra[4], rb[4];
      if (AKM) {
        const float4 va = *(const float4*)&AsRaw[kk * 68 + ty * 4];
        ra[0] = va.x; ra[1] = va.y; ra[2] = va.z; ra[3] = va.w;
      } else {
#pragma unroll
        for (int r = 0; r < 4; ++r) ra[r] = AsRaw[(ty * 4 + r) * 33 + kk];
      }
      const float4 vb = *(const float4*)&Bs[kk * 68 + tx * 4];
      rb[0] = vb.x; rb[1] = vb.y; rb[2] = vb.z; rb[3] = vb.w;
#pragma unroll
      for (int r = 0; r < 4; ++r)
#pragma unroll
        for (int c = 0; c < 4; ++c) acc[r][c] += ra[r] * rb[c];
    }
    __syncthreads();
  }
#pragma unroll
  for (int r = 0; r < 4; ++r)
#pragma unroll
    for (int c = 0; c < 4; ++c) {
      int gi = i0 + ty * 4 + r, gj = j0 + tx * 4 + c;
      float v = g.alpha * acc[r][c];
      if (g.r1u) v += g.r1c * g.r1u[gi] * g.r1v[gj];
      if (g.radd) v += g.raddc * g.radd[gj];
      if (g.addI != 0.0f && gi == gj) v += g.addI;
      g.C[(size_t)gi * g.ldc + gj] = v;
    }
}

// ---------------------------------------------------------------------------
// Column means of x (B x D): one thread per column, f64 accumulate.
// ---------------------------------------------------------------------------
__global__ __launch_bounds__(256)
void colmean_k(const float* x, float* m) {
  int c = blockIdx.x * 256 + threadIdx.x;
  if (c >= D_N) return;
  double acc = 0.0;
  for (int r = 0; r < B_N; ++r) acc += (double)x[(size_t)r * D_N + c];
  m[c] = (float)(acc / (double)B_N);
}

__global__ void inits_k(float* S, int n) {
  int i = blockIdx.x * 256 + threadIdx.x;
  if (i < n) S[i] = hashf((unsigned)i * 2654435761u + 12345u);
}

// ---------------------------------------------------------------------------
// Single-WG Cholesky (lower, in-place on G) + LinvT (LinvT[c][i] = Linv[i][c])
// + optional logdet (f64) + optional Sinv = Linv^T Linv. n <= 256.
// ---------------------------------------------------------------------------
__global__ __launch_bounds__(256)
void chol_trinv_k(float* G, int n, float* LinvT, double* logdet, float* Sinv) {
  const int tid = threadIdx.x;
  __shared__ float colj[256];
  for (int j = 0; j < n; ++j) {
    if (tid == 0) G[(size_t)j * n + j] = sqrtf(fmaxf(G[(size_t)j * n + j], 1e-20f));
    __syncthreads();
    float pj = G[(size_t)j * n + j];
    for (int i = j + 1 + tid; i < n; i += 256) {
      float v = G[(size_t)i * n + j] / pj;
      G[(size_t)i * n + j] = v;
      colj[i] = v;
    }
    __syncthreads();
    for (int i = j + 1 + tid; i < n; i += 256) {
      float ci = colj[i];
      for (int t = j + 1; t <= i; ++t) G[(size_t)i * n + t] -= ci * colj[t];
    }
    __syncthreads();
  }
  if (logdet && tid == 0) {
    double s = 0.0;
    for (int j = 0; j < n; ++j) s += log((double)G[(size_t)j * n + j]);
    *logdet = 2.0 * s;
  }
  // Forward solves: column c of Linv == row c of LinvT
  for (int c = tid; c < n; c += 256) {
    for (int i = 0; i < c; ++i) LinvT[(size_t)c * n + i] = 0.0f;
    for (int i = c; i < n; ++i) {
      float s = (i == c) ? 1.0f : 0.0f;
      for (int t = c; t < i; ++t) s -= G[(size_t)i * n + t] * LinvT[(size_t)c * n + t];
      LinvT[(size_t)c * n + i] = s / G[(size_t)i * n + i];
    }
  }
  __syncthreads();
  if (Sinv) {
    for (int idx = tid; idx < n * n; idx += 256) {
      int i = idx / n, jj = idx % n;
      int t0 = (i > jj) ? i : jj;
      float s = 0.0f;
      for (int t = t0; t < n; ++t)
        s += LinvT[(size_t)i * n + t] * LinvT[(size_t)jj * n + t];
      Sinv[idx] = s;
    }
  }
}

// ---------------------------------------------------------------------------
// Single-WG Householder tridiagonalization of symmetric n x n (n=256).
// A <- 0.5(T+T^T) then reduced; Householder v's stored in A's columns.
// ---------------------------------------------------------------------------
__global__ __launch_bounds__(256)
void tridiag_k(const float* T, float* A, float* dvec, float* evec, float* tauv, int n) {
  const int tid = threadIdx.x;
  __shared__ float vbuf[256];
  __shared__ float wbuf[256];
  __shared__ double red[256];
  for (int idx = tid; idx < n * n; idx += 256) {
    int i = idx / n, j = idx % n;
    A[idx] = 0.5f * (T[idx] + T[(size_t)j * n + i]);
  }
  __syncthreads();
  for (int j = 0; j < n - 2; ++j) {
    const int lo = j + 1;
    double s = 0.0;
    for (int i = lo + 1 + tid; i < n; i += 256) {
      float xv = A[(size_t)i * n + j];
      s += (double)xv * xv;
    }
    red[tid] = s; __syncthreads();
    for (int off = 128; off > 0; off >>= 1) { if (tid < off) red[tid] += red[tid + off]; __syncthreads(); }
    double xn2 = red[0];
    float alpha = A[(size_t)lo * n + j];
    float beta, tj, scal;
    if (xn2 == 0.0) { beta = alpha; tj = 0.0f; scal = 0.0f; }
    else {
      beta = -copysignf(sqrtf((float)((double)alpha * alpha + xn2)), alpha);
      tj = (beta - alpha) / beta;
      scal = 1.0f / (alpha - beta);
    }
    __syncthreads();
    for (int i = lo + tid; i < n; i += 256) {
      float v;
      if (i == lo) v = 1.0f;
      else { v = A[(size_t)i * n + j] * scal; A[(size_t)i * n + j] = v; }
      vbuf[i] = v;
    }
    if (tid == 0) { evec[j] = beta; tauv[j] = tj; }
    __syncthreads();
    if (tj != 0.0f) {
      for (int r = lo + tid; r < n; r += 256) {
        float acc = 0.0f;
        for (int c = lo; c < n; ++c) acc += A[(size_t)r * n + c] * vbuf[c];
        wbuf[r] = tj * acc;
      }
      __syncthreads();
      double s2 = 0.0;
      for (int i = lo + tid; i < n; i += 256) s2 += (double)wbuf[i] * vbuf[i];
      red[tid] = s2; __syncthreads();
      for (int off = 128; off > 0; off >>= 1) { if (tid < off) red[tid] += red[tid + off]; __syncthreads(); }
      float half = 0.5f * tj * (float)red[0];
      __syncthreads();
      int mlen = n - lo;
      for (int idx = tid; idx < mlen * mlen; idx += 256) {
        int r = lo + idx / mlen, c = lo + idx % mlen;
        float wr = wbuf[r] - half * vbuf[r];
        float wc = wbuf[c] - half * vbuf[c];
        A[(size_t)r * n + c] -= vbuf[r] * wc + wr * vbuf[c];
      }
    }
    __syncthreads();
  }
  for (int i = tid; i < n; i += 256) dvec[i] = A[(size_t)i * n + i];
  if (tid == 0) { evec[n - 2] = A[(size_t)(n - 1) * n + (n - 2)]; tauv[n - 2] = 0.0f; }
}

// ---------------------------------------------------------------------------
// Top-k eigenvalues (descending) of tridiagonal via Sturm bisection (f64).
// ---------------------------------------------------------------------------
__global__ __launch_bounds__(128)
void sturm_k(const float* dvec, const float* evec, float* lam, int n, int ktop) {
  int k = threadIdx.x;
  if (k >= ktop) return;
  double lo = 1e30, hi = -1e30;
  for (int i = 0; i < n; ++i) {
    double e0 = (i > 0) ? fabs((double)evec[i - 1]) : 0.0;
    double e1 = (i < n - 1) ? fabs((double)evec[i]) : 0.0;
    double di = (double)dvec[i];
    lo = fmin(lo, di - e0 - e1);
    hi = fmax(hi, di + e0 + e1);
  }
  lo -= 1e-6; hi += 1e-6;
  const int target = n - k;
  for (int it = 0; it < 80; ++it) {
    double mid = 0.5 * (lo + hi);
    int cnt = 0;
    double q = 1.0;
    for (int i = 0; i < n; ++i) {
      double di = (double)dvec[i] - mid;
      if (i) { double ee = (double)evec[i - 1]; di -= ee * ee / q; }
      if (di < 0.0) cnt++;
      q = (fabs(di) < 1e-300) ? -1e-300 : di;
    }
    if (cnt >= target) hi = mid; else lo = mid;
  }
  lam[k] = (float)(0.5 * (lo + hi));
}

// ---------------------------------------------------------------------------
// Inverse iteration on tridiagonal: 128 threads, one eigenvector each.
// Pivoted LU (slagtf-style) + 3 solve/normalize rounds. scratch: 6*n*128 f32.
// ---------------------------------------------------------------------------
__global__ __launch_bounds__(128)
void invit_k(const float* dvec, const float* evec, const float* lam,
             float* scratch, float* Vtri, int n, int kdim) {
  int k = threadIdx.x;
  if (k >= kdim) return;
  float* aa = scratch;
  float* bb = aa + (size_t)n * 128;
  float* cc = bb + (size_t)n * 128;
  float* lv = cc + (size_t)n * 128;
  float* pv = lv + (size_t)n * 128;
  float* yy = pv + (size_t)n * 128;
#define IXS(i) ((size_t)(i) * 128 + k)
  double range = fabs((double)lam[0] - (double)lam[kdim - 1]) + 1e-6;
  float s = lam[k] + (float)(range * 1e-6 * (double)((k % 5) - 2));
  aa[IXS(0)] = dvec[0] - s;
  bb[IXS(0)] = evec[0];
  cc[IXS(0)] = 0.0f;
  for (int i = 0; i < n - 1; ++i) {
    float sub = evec[i];
    float dn = dvec[i + 1] - s;
    float ai = aa[IXS(i)];
    float bi = bb[IXS(i)];
    float enext = (i < n - 2) ? evec[i + 1] : 0.0f;
    if (fabsf(ai) >= fabsf(sub)) {
      float l = (ai != 0.0f) ? sub / ai : 0.0f;
      lv[IXS(i)] = l; pv[IXS(i)] = 0.0f;
      cc[IXS(i)] = 0.0f;
      aa[IXS(i + 1)] = dn - l * bi;
      bb[IXS(i + 1)] = enext;
    } else {
      float l = ai / sub;
      lv[IXS(i)] = l; pv[IXS(i)] = 1.0f;
      aa[IXS(i)] = sub; bb[IXS(i)] = dn; cc[IXS(i)] = enext;
      aa[IXS(i + 1)] = bi - l * dn;
      bb[IXS(i + 1)] = -l * enext;
    }
  }
  for (int i = 0; i < n; ++i) {
    float a = aa[IXS(i)];
    if (fabsf(a) < 1e-12f) aa[IXS(i)] = (a < 0.0f) ? -1e-12f : 1e-12f;
  }
  for (int i = 0; i < n; ++i)
    yy[IXS(i)] = hashf((unsigned)(i * 131 + k * 7919 + 977));
  for (int iter = 0; iter < 3; ++iter) {
    for (int i = 0; i < n - 1; ++i) {
      float yi = yy[IXS(i)], yn = yy[IXS(i + 1)];
      if (pv[IXS(i)] != 0.0f) { float t = yi; yi = yn; yn = t; }
      yn -= lv[IXS(i)] * yi;
      yy[IXS(i)] = yi; yy[IXS(i + 1)] = yn;
    }
    float y2 = yy[IXS(n - 1)] / aa[IXS(n - 1)];
    yy[IXS(n - 1)] = y2;
    float y1 = (yy[IXS(n - 2)] - bb[IXS(n - 2)] * y2) / aa[IXS(n - 2)];
    yy[IXS(n - 2)] = y1;
    for (int i = n - 3; i >= 0; --i) {
      float v = (yy[IXS(i)] - bb[IXS(i)] * y1 - cc[IXS(i)] * y2) / aa[IXS(i)];
      yy[IXS(i)] = v; y2 = y1; y1 = v;
    }
    double nr = 0.0;
    for (int i = 0; i < n; ++i) { float v = yy[IXS(i)]; nr += (double)v * v; }
    float inv = (float)(1.0 / sqrt(nr + 1e-300));
    for (int i = 0; i < n; ++i) yy[IXS(i)] *= inv;
  }
  for (int i = 0; i < n; ++i) Vtri[(size_t)i * kdim + k] = yy[IXS(i)];
#undef IXS
}

// ---------------------------------------------------------------------------
// Back-transform: V <- H_0 H_1 ... H_{n-3} V  (apply in reverse index order).
// ---------------------------------------------------------------------------
__global__ __launch_bounds__(256)
void backxform_k(const float* A, const float* tauv, float* V, int n, int kdim) {
  const int tid = threadIdx.x;
  __shared__ float vbuf[256];
  __shared__ float wh[2][128];
  __shared__ float wrow[128];
  for (int j = n - 3; j >= 0; --j) {
    float tj = tauv[j];
    const int lo = j + 1;
    for (int i = lo + tid; i < n; i += 256)
      vbuf[i] = (i == lo) ? 1.0f : A[(size_t)i * n + j];
    __syncthreads();
    if (tj != 0.0f) {
      int c = tid & 127, h = tid >> 7;
      float sum = 0.0f;
      for (int i = lo + h; i < n; i += 2) sum += vbuf[i] * V[(size_t)i * kdim + c];
      wh[h][c] = sum;
      __syncthreads();
      if (tid < 128) wrow[tid] = tj * (wh[0][tid] + wh[1][tid]);
      __syncthreads();
      int mlen = n - lo;
      for (int idx = tid; idx < mlen * kdim; idx += 256) {
        int i = lo + idx / kdim, c2 = idx % kdim;
        V[(size_t)i * kdim + c2] -= vbuf[i] * wrow[c2];
      }
    }
    __syncthreads();
  }
}

// ---------------------------------------------------------------------------
// mW[j] = sum_c m[c] * W[c][j]
// ---------------------------------------------------------------------------
__global__ __launch_bounds__(128)
void mw_k(const float* m, const float* W, float* mW) {
  int j = threadIdx.x;
  double acc = 0.0;
  for (int c = 0; c < D_N; ++c) acc += (double)m[c] * (double)W[(size_t)c * K_N + j];
  mW[j] = (float)acc;
}

// ---------------------------------------------------------------------------
// Label stats: blocks 0..9 -> masked column sums + count; block 10 -> mu_total
// ---------------------------------------------------------------------------
__global__ __launch_bounds__(128)
void labelstat_k(const float* z, const int* lab, float* sum_mu, float* mu_total,
                 int* counts) {
  int l = blockIdx.x;
  int j = threadIdx.x;
  double acc = 0.0;
  if (l < NLAB) {
    int cnt = 0;
    for (int r = 0; r < B_N; ++r) {
      if (lab[r] == l) { acc += (double)z[(size_t)r * K_N + j]; cnt++; }
    }
    sum_mu[l * K_N + j] = (float)acc;
    if (j == 0) counts[l] = cnt;
  } else {
    for (int r = 0; r < B_N; ++r) acc += (double)z[(size_t)r * K_N + j];
    mu_total[j] = (float)(acc / (double)B_N);
  }
}

// ---------------------------------------------------------------------------
// Per-label masked outer-product sums: SigS[l] = sum_{b:lab=l} diff_b diff_b^T
// blockIdx.x = l*4 + tile (tile over 2x2 grid of 64x64 tiles of 128x128)
// ---------------------------------------------------------------------------
__global__ __launch_bounds__(256)
void sigma_label_k(const float* z, const int* lab, const float* mu, float* SigS) {
  int l = blockIdx.x >> 2, t = blockIdx.x & 3;
  int i0 = (t >> 1) * 64, j0 = (t & 1) * 64;
  __shared__ float Zi[32][66], Zj[32][66];
  __shared__ int labs[32];
  __shared__ float muL[128];
  int tid = threadIdx.x, tx = tid & 15, ty = tid >> 4;
  if (tid < 128) muL[tid] = mu[tid];
  __syncthreads();
  float acc[4][4] = {};
  for (int r0 = 0; r0 < B_N; r0 += 32) {
#pragma unroll
    for (int p = 0; p < 8; ++p) {
      int idx = tid + p * 256;
      int rr = idx >> 6, cc = idx & 63;
      Zi[rr][cc] = z[(size_t)(r0 + rr) * K_N + i0 + cc] - muL[i0 + cc];
      Zj[rr][cc] = z[(size_t)(r0 + rr) * K_N + j0 + cc] - muL[j0 + cc];
    }
    if (tid < 32) labs[tid] = lab[r0 + tid];
    __syncthreads();
    for (int rr = 0; rr < 32; ++rr) {
      if (labs[rr] == l) {
        float ra[4], rb[4];
#pragma unroll
        for (int r = 0; r < 4; ++r) ra[r] = Zi[rr][ty * 4 + r];
#pragma unroll
        for (int c = 0; c < 4; ++c) rb[c] = Zj[rr][tx * 4 + c];
#pragma unroll
        for (int r = 0; r < 4; ++r)
#pragma unroll
          for (int c = 0; c < 4; ++c) acc[r][c] += ra[r] * rb[c];
      }
    }
    __syncthreads();
  }
#pragma unroll
  for (int r = 0; r < 4; ++r)
#pragma unroll
    for (int c = 0; c < 4; ++c)
      SigS[((size_t)l * K_N + i0 + ty * 4 + r) * K_N + j0 + tx * 4 + c] = acc[r][c];
}

// ---------------------------------------------------------------------------
// Per-label KL pieces: tr, maha, logdet_F -> kl[l]
// ---------------------------------------------------------------------------
__global__ __launch_bounds__(256)
void perlabel_k(const float* SigS, const float* Sinv, const float* mu,
                const float* sum_mu, const int* counts, const double* logdet_t,
                double* klout, int* present) {
  int l = blockIdx.x, tid = threadIdx.x;
  __shared__ float Amat[128][129];
  __shared__ double red[256];
  __shared__ float dv[128];
  __shared__ float colj[128];
  int cnt = counts[l];
  float sc = (cnt > 0) ? (float)cnt : 1.0f;
  for (int idx = tid; idx < 128 * 128; idx += 256) {
    int i = idx >> 7, j = idx & 127;
    Amat[i][j] = SigS[((size_t)l * K_N + i) * K_N + j] / sc + ((i == j) ? 1.0f : 0.0f);
  }
  if (tid < 128) dv[tid] = mu[tid] - sum_mu[l * K_N + tid] / sc;
  __syncthreads();
  double tr = 0.0, mh = 0.0;
  for (int idx = tid; idx < 128 * 128; idx += 256) {
    int i = idx >> 7, j = idx & 127;
    double sv = (double)Sinv[idx];
    tr += sv * (double)Amat[i][j];
    mh += sv * (double)dv[i] * (double)dv[j];
  }
  red[tid] = tr; __syncthreads();
  for (int off = 128; off > 0; off >>= 1) { if (tid < off) red[tid] += red[tid + off]; __syncthreads(); }
  double trv = red[0]; __syncthreads();
  red[tid] = mh; __syncthreads();
  for (int off = 128; off > 0; off >>= 1) { if (tid < off) red[tid] += red[tid + off]; __syncthreads(); }
  double mhv = red[0]; __syncthreads();
  // Cholesky of Amat in LDS
  for (int j = 0; j < 128; ++j) {
    if (tid == 0) Amat[j][j] = sqrtf(fmaxf(Amat[j][j], 1e-20f));
    __syncthreads();
    float pj = Amat[j][j];
    for (int i = j + 1 + tid; i < 128; i += 256) {
      float v = Amat[i][j] / pj;
      Amat[i][j] = v; colj[i] = v;
    }
    __syncthreads();
    for (int i = j + 1 + tid; i < 128; i += 256) {
      float ci = colj[i];
      for (int t2 = j + 1; t2 <= i; ++t2) Amat[i][t2] -= ci * colj[t2];
    }
    __syncthreads();
  }
  if (tid == 0) {
    double ld = 0.0;
    for (int j = 0; j < 128; ++j) ld += log((double)Amat[j][j]);
    ld *= 2.0;
    double kl = 0.5 * (trv + mhv - 128.0 + logdet_t[0] - ld);
    klout[l] = kl;
    present[l] = (cnt > 0) ? 1 : 0;
  }
}

__global__ void finalize_k(const double* kl, const int* present, float* out) {
  if (threadIdx.x == 0 && blockIdx.x == 0) {
    double s = 0.0; int np = 0;
    for (int l = 0; l < NLAB; ++l)
      if (present[l]) { s += kl[l]; np++; }
    out[0] = (float)((np > 0) ? s / ((double)np * (double)B_N) : 0.0);
  }
}

// ===========================================================================
// Host side
// ===========================================================================
static inline void launch_gemm(hipStream_t st, bool akm,
                               const float* A, int lda, const float* B, int ldb,
                               float* C, int ldc, int M, int N, int K, float alpha,
                               const float* u = nullptr, const float* v = nullptr,
                               float r1c = 0.0f,
                               const float* radd = nullptr, float raddc = 0.0f,
                               float addI = 0.0f) {
  GArgs g{A, B, C, lda, ldb, ldc, K, alpha, u, v, r1c, radd, raddc, addI};
  dim3 grid(M / 64, N / 64);
  if (akm) hipLaunchKernelGGL((gemm_k<true>), grid, dim3(256), 0, st, g);
  else     hipLaunchKernelGGL((gemm_k<false>), grid, dim3(256), 0, st, g);
}

extern "C" void kernel_launch(void* const* d_in, const int* in_sizes, int n_in,
                              void* d_out, int out_size, void* d_ws, size_t ws_size,
                              hipStream_t stream) {
  const float* x = (const float*)d_in[0];
  const int* lab = (const int*)d_in[1];
  float* out = (float*)d_out;

  // workspace carve-out (~14 MB)
  size_t off = 0;
  auto alloc = [&](size_t nfloats) -> float* {
    float* r = (float*)((char*)d_ws + off);
    off += ((nfloats * 4 + 255) / 256) * 256;
    return r;
  };
  float* m     = alloc(D_N);
  float* Cn    = alloc((size_t)D_N * D_N);
  float* Sa    = alloc((size_t)D_N * M_N);
  float* Sb    = alloc((size_t)D_N * M_N);
  float* G256  = alloc((size_t)M_N * M_N);
  float* Li256 = alloc((size_t)M_N * M_N);
  float* Tm    = alloc((size_t)M_N * M_N);
  float* Tw    = alloc((size_t)M_N * M_N);
  float* dvec  = alloc(M_N);
  float* evec  = alloc(M_N);
  float* tauv  = alloc(M_N);
  float* lam   = alloc(K_N);
  float* scr   = alloc((size_t)6 * M_N * 128);
  float* Vt    = alloc((size_t)M_N * K_N);
  float* Vt2   = alloc((size_t)M_N * K_N);
  float* G128  = alloc((size_t)K_N * K_N);
  float* Li128 = alloc((size_t)K_N * K_N);
  float* Wa    = alloc((size_t)D_N * K_N);
  float* Wb    = alloc((size_t)D_N * K_N);
  float* mW    = alloc(K_N);
  float* z     = alloc((size_t)B_N * K_N);
  float* summu = alloc(NLAB * K_N);
  float* muT   = alloc(K_N);
  float* SigT  = alloc((size_t)K_N * K_N);
  float* Sinv  = alloc((size_t)K_N * K_N);
  float* SigS  = alloc((size_t)NLAB * K_N * K_N);
  double* logdet_t = (double*)alloc(2);
  double* klv      = (double*)alloc(2 * NLAB);
  int* counts  = (int*)alloc(16);
  int* present = (int*)alloc(16);
  (void)in_sizes; (void)n_in; (void)out_size; (void)ws_size;

  // 1) column means; Cn = (x^T x)/B - m m^T
  hipLaunchKernelGGL(colmean_k, dim3(D_N / 256), dim3(256), 0, stream, x, m);
  launch_gemm(stream, true, x, D_N, x, D_N, Cn, D_N, D_N, D_N, B_N,
              1.0f / (float)B_N, m, m, -1.0f);

  // 2) subspace iteration, m=256 cushion, 32 applies, CholQR at {2,4,8,...,32}
  hipLaunchKernelGGL(inits_k, dim3((D_N * M_N + 255) / 256), dim3(256), 0, stream,
                     Sa, D_N * M_N);
  float* cur = Sa; float* oth = Sb;
  for (int it = 1; it <= 32; ++it) {
    launch_gemm(stream, true, Cn, D_N, cur, M_N, oth, M_N, D_N, M_N, D_N, 1.0f);
    { float* t = cur; cur = oth; oth = t; }
    if (it == 2 || (it % 4) == 0) {
      launch_gemm(stream, true, cur, M_N, cur, M_N, G256, M_N, M_N, M_N, D_N, 1.0f);
      hipLaunchKernelGGL(chol_trinv_k, dim3(1), dim3(256), 0, stream,
                         G256, M_N, Li256, (double*)nullptr, (float*)nullptr);
      launch_gemm(stream, false, cur, M_N, Li256, M_N, oth, M_N, D_N, M_N, M_N, 1.0f);
      { float* t = cur; cur = oth; oth = t; }
    }
  }

  // 3) Rayleigh-Ritz: T = S^T Cn S; tridiag; Sturm; inverse iteration
  launch_gemm(stream, true, Cn, D_N, cur, M_N, oth, M_N, D_N, M_N, D_N, 1.0f); // Yf
  launch_gemm(stream, true, cur, M_N, oth, M_N, Tm, M_N, M_N, M_N, D_N, 1.0f); // T
  hipLaunchKernelGGL(tridiag_k, dim3(1), dim3(256), 0, stream, Tm, Tw, dvec, evec, tauv, M_N);
  hipLaunchKernelGGL(sturm_k, dim3(1), dim3(128), 0, stream, dvec, evec, lam, M_N, K_N);
  hipLaunchKernelGGL(invit_k, dim3(1), dim3(128), 0, stream, dvec, evec, lam, scr, Vt, M_N, K_N);
  // CholQR polish of tridiag-basis eigenvectors (fixes cluster orthogonality)
  launch_gemm(stream, true, Vt, K_N, Vt, K_N, G128, K_N, K_N, K_N, M_N, 1.0f);
  hipLaunchKernelGGL(chol_trinv_k, dim3(1), dim3(256), 0, stream,
                     G128, K_N, Li128, (double*)nullptr, (float*)nullptr);
  launch_gemm(stream, false, Vt, K_N, Li128, K_N, Vt2, K_N, M_N, K_N, K_N, 1.0f);
  hipLaunchKernelGGL(backxform_k, dim3(1), dim3(256), 0, stream, Tw, tauv, Vt2, M_N, K_N);

  // 4) W = S * V  (+ safety CholQR)
  launch_gemm(stream, false, cur, M_N, Vt2, K_N, Wa, K_N, D_N, K_N, M_N, 1.0f);
  launch_gemm(stream, true, Wa, K_N, Wa, K_N, G128, K_N, K_N, K_N, D_N, 1.0f);
  hipLaunchKernelGGL(chol_trinv_k, dim3(1), dim3(256), 0, stream,
                     G128, K_N, Li128, (double*)nullptr, (float*)nullptr);
  launch_gemm(stream, false, Wa, K_N, Li128, K_N, Wb, K_N, D_N, K_N, K_N, 1.0f);

  // 5) z = x W - 1 (m^T W)
  hipLaunchKernelGGL(mw_k, dim3(1), dim3(128), 0, stream, m, Wb, mW);
  launch_gemm(stream, false, x, D_N, Wb, K_N, z, K_N, B_N, K_N, D_N, 1.0f,
              nullptr, nullptr, 0.0f, mW, -1.0f);

  // 6) label stats; Sigma_total = I + z^T z / B - mu mu^T; Sinv; logdet_t
  hipLaunchKernelGGL(labelstat_k, dim3(NLAB + 1), dim3(128), 0, stream,
                     z, lab, summu, muT, counts);
  launch_gemm(stream, true, z, K_N, z, K_N, SigT, K_N, K_N, K_N, B_N,
              1.0f / (float)B_N, muT, muT, -1.0f, nullptr, 0.0f, 1.0f);
  hipLaunchKernelGGL(chol_trinv_k, dim3(1), dim3(256), 0, stream,
                     SigT, K_N, Li128, logdet_t, Sinv);

  // 7) per-label covariance sums, KL, reduce
  hipLaunchKernelGGL(sigma_label_k, dim3(NLAB * 4), dim3(256), 0, stream,
                     z, lab, muT, SigS);
  hipLaunchKernelGGL(perlabel_k, dim3(NLAB), dim3(256), 0, stream,
                     SigS, Sinv, muT, summu, counts, logdet_t, klv, present);
  hipLaunchKernelGGL(finalize_k, dim3(1), dim3(64), 0, stream, klv, present, out);
}

// Round 2
// 43403.705 us; speedup vs baseline: 2.2951x; 2.2951x over previous
//
#include <hip/hip_runtime.h>
#include <hip/hip_bf16.h>
#include <math.h>

// ============================================================================
// GMMLoss2_pca: PCA(top-128 of 1024-dim Gram) + per-label Gaussian KL.
// v2: remove serial eigensolver (tridiag/sturm/invit) -> inner subspace
// iteration with LDS CholQR; sort-by-label for Sigma sums; parallel reductions.
// ============================================================================

#define B_N 8192
#define D_N 1024
#define K_N 128
#define M_N 256   // outer cushion size
#define NLAB 10

__device__ __forceinline__ float hashf(unsigned x) {
  x ^= x >> 16; x *= 0x7feb352du; x ^= x >> 15; x *= 0x846ca68bu; x ^= x >> 16;
  return (float)(x >> 8) * (1.0f / 16777216.0f) - 0.5f;
}

// ---------------------------------------------------------------------------
// Generic tiled f32 GEMM: C[i][j] = alpha * sum_k A(k,i)*B(k,j)  (+ epilogue)
// AKM=true : A element (k,i) at A[k*lda+i];  AKM=false: (i,k) at A[i*lda+k].
// B always (k,j) at B[k*ldb+j].
// Epilogue: + r1c*u[i]*v[j] + raddc*radd[j] + addI*(i==j)
// M,N multiples of 64; K multiple of 32.   (validated in round 1)
// ---------------------------------------------------------------------------
struct GArgs {
  const float* A; const float* B; float* C;
  int lda, ldb, ldc, K;
  float alpha;
  const float* r1u; const float* r1v; float r1c;
  const float* radd; float raddc;
  float addI;
};

template <bool AKM>
__global__ __launch_bounds__(256)
void gemm_k(GArgs g) {
  __shared__ __align__(16) float AsRaw[2176]; // AKM: [32][68]; !AKM: [64][33]
  __shared__ __align__(16) float Bs[32 * 68];
  const int tid = threadIdx.x;
  const int tx = tid & 15, ty = tid >> 4;
  const int i0 = blockIdx.x * 64, j0 = blockIdx.y * 64;
  float acc[4][4] = {};
  for (int k0 = 0; k0 < g.K; k0 += 32) {
    if (AKM) {
#pragma unroll
      for (int p = 0; p < 8; ++p) {
        int idx = tid + p * 256;
        int kk = idx >> 6, ii = idx & 63;
        AsRaw[kk * 68 + ii] = g.A[(size_t)(k0 + kk) * g.lda + i0 + ii];
      }
    } else {
#pragma unroll
      for (int p = 0; p < 8; ++p) {
        int idx = tid + p * 256;
        int ii = idx >> 5, kk = idx & 31;
        AsRaw[ii * 33 + kk] = g.A[(size_t)(i0 + ii) * g.lda + k0 + kk];
      }
    }
#pragma unroll
    for (int p = 0; p < 8; ++p) {
      int idx = tid + p * 256;
      int kk = idx >> 6, jj = idx & 63;
      Bs[kk * 68 + jj] = g.B[(size_t)(k0 + kk) * g.ldb + j0 + jj];
    }
    __syncthreads();
#pragma unroll 8
    for (int kk = 0; kk < 32; ++kk) {
      float ra[4], rb[4];
      if (AKM) {
        const float4 va = *(const float4*)&AsRaw[kk * 68 + ty * 4];
        ra[0] = va.x; ra[1] = va.y; ra[2] = va.z; ra[3] = va.w;
      } else {
#pragma unroll
        for (int r = 0; r < 4; ++r) ra[r] = AsRaw[(ty * 4 + r) * 33 + kk];
      }
      const float4 vb = *(const float4*)&Bs[kk * 68 + tx * 4];
      rb[0] = vb.x; rb[1] = vb.y; rb[2] = vb.z; rb[3] = vb.w;
#pragma unroll
      for (int r = 0; r < 4; ++r)
#pragma unroll
        for (int c = 0; c < 4; ++c) acc[r][c] += ra[r] * rb[c];
    }
    __syncthreads();
  }
#pragma unroll
  for (int r = 0; r < 4; ++r)
#pragma unroll
    for (int c = 0; c < 4; ++c) {
      int gi = i0 + ty * 4 + r, gj = j0 + tx * 4 + c;
      float v = g.alpha * acc[r][c];
      if (g.r1u) v += g.r1c * g.r1u[gi] * g.r1v[gj];
      if (g.radd) v += g.raddc * g.radd[gj];
      if (g.addI != 0.0f && gi == gj) v += g.addI;
      g.C[(size_t)gi * g.ldc + gj] = v;
    }
}

// ---------------------------------------------------------------------------
// Column means, 2-phase parallel.
// ---------------------------------------------------------------------------
__global__ __launch_bounds__(256)
void colmean_part_k(const float* x, double* part) {
  int col = blockIdx.x * 256 + threadIdx.x;  // blockIdx.x in 0..3
  int rs = blockIdx.y;                        // 0..15
  double acc = 0.0;
  for (int r = rs * 512; r < (rs + 1) * 512; ++r)
    acc += (double)x[(size_t)r * D_N + col];
  part[(size_t)rs * D_N + col] = acc;
}

__global__ __launch_bounds__(256)
void colmean_comb_k(const double* part, float* m) {
  int col = blockIdx.x * 256 + threadIdx.x;
  double acc = 0.0;
  for (int rs = 0; rs < 16; ++rs) acc += part[(size_t)rs * D_N + col];
  m[col] = (float)(acc / (double)B_N);
}

__global__ void inits_k(float* S, int n, unsigned seed) {
  int i = blockIdx.x * 256 + threadIdx.x;
  if (i < n) S[i] = hashf((unsigned)i * 2654435761u + seed);
}

// ---------------------------------------------------------------------------
// Single-WG Cholesky (n<=256, global, in-place) + LinvT (LinvT[c][i]=Linv[i][c])
// ---------------------------------------------------------------------------
__global__ __launch_bounds__(256)
void chol256g_k(float* G, int n, float* LinvT) {
  const int tid = threadIdx.x;
  __shared__ float colj[256];
  for (int j = 0; j < n; ++j) {
    if (tid == 0) G[(size_t)j * n + j] = sqrtf(fmaxf(G[(size_t)j * n + j], 1e-20f));
    __syncthreads();
    float pj = G[(size_t)j * n + j];
    for (int i = j + 1 + tid; i < n; i += 256) {
      float v = G[(size_t)i * n + j] / pj;
      G[(size_t)i * n + j] = v;
      colj[i] = v;
    }
    __syncthreads();
    for (int i = j + 1 + tid; i < n; i += 256) {
      float ci = colj[i];
      for (int t = j + 1; t <= i; ++t) G[(size_t)i * n + t] -= ci * colj[t];
    }
    __syncthreads();
  }
  for (int c = tid; c < n; c += 256) {
    for (int i = 0; i < c; ++i) LinvT[(size_t)c * n + i] = 0.0f;
    for (int i = c; i < n; ++i) {
      float s = (i == c) ? 1.0f : 0.0f;
      for (int t = c; t < i; ++t) s -= G[(size_t)i * n + t] * LinvT[(size_t)c * n + t];
      LinvT[(size_t)c * n + i] = s / G[(size_t)i * n + i];
    }
  }
}

// ---------------------------------------------------------------------------
// LDS Cholesky for n=128: chol + LinvT (+ optional logdet, Sinv). One WG.
// ---------------------------------------------------------------------------
__global__ __launch_bounds__(256)
void chol128_k(const float* Gin, float* LinvT, double* logdet, float* Sinv) {
  __shared__ float A[128][129];
  __shared__ float Bm[128][129];
  __shared__ float colj[128];
  const int tid = threadIdx.x;
  for (int idx = tid; idx < 128 * 128; idx += 256)
    A[idx >> 7][idx & 127] = Gin[idx];
  __syncthreads();
  for (int j = 0; j < 128; ++j) {
    if (tid == 0) A[j][j] = sqrtf(fmaxf(A[j][j], 1e-20f));
    __syncthreads();
    float pj = A[j][j];
    for (int i = j + 1 + tid; i < 128; i += 256) {
      float v = A[i][j] / pj;
      A[i][j] = v; colj[i] = v;
    }
    __syncthreads();
    for (int i = j + 1 + tid; i < 128; i += 256) {
      float ci = colj[i];
      for (int t = j + 1; t <= i; ++t) A[i][t] -= ci * colj[t];
    }
    __syncthreads();
  }
  if (logdet && tid == 0) {
    double s = 0.0;
    for (int j = 0; j < 128; ++j) s += log((double)A[j][j]);
    *logdet = 2.0 * s;
  }
  for (int c = tid; c < 128; c += 256) {
    for (int i = 0; i < c; ++i) Bm[c][i] = 0.0f;
    for (int i = c; i < 128; ++i) {
      float s = (i == c) ? 1.0f : 0.0f;
      for (int t = c; t < i; ++t) s -= A[i][t] * Bm[c][t];
      Bm[c][i] = s / A[i][i];
    }
  }
  __syncthreads();
  if (LinvT)
    for (int idx = tid; idx < 128 * 128; idx += 256)
      LinvT[idx] = Bm[idx >> 7][idx & 127];
  if (Sinv)
    for (int idx = tid; idx < 128 * 128; idx += 256) {
      int i = idx >> 7, j = idx & 127;
      int t0 = (i > j) ? i : j;
      float s = 0.0f;
      for (int t = t0; t < 128; ++t) s += Bm[i][t] * Bm[j][t];
      Sinv[idx] = s;
    }
}

// ---------------------------------------------------------------------------
// mW[j] = sum_c m[c] * W[c][j]
// ---------------------------------------------------------------------------
__global__ __launch_bounds__(128)
void mw_k(const float* m, const float* W, float* mW) {
  int j = threadIdx.x;
  double acc = 0.0;
  for (int c = 0; c < D_N; ++c) acc += (double)m[c] * (double)W[(size_t)c * K_N + j];
  mW[j] = (float)acc;
}

// ---------------------------------------------------------------------------
// Deterministic stable counting sort of 8192 labels. One WG of 256 threads.
// Outputs: perm[8192], counts[10], offs[11].
// ---------------------------------------------------------------------------
__global__ __launch_bounds__(256)
void count_sort_k(const int* lab, int* perm, int* counts, int* offs) {
  __shared__ int cnt[NLAB][256];
  __shared__ int labOff[NLAB + 1];
  const int tid = threadIdx.x;
  int lc[NLAB];
#pragma unroll
  for (int l = 0; l < NLAB; ++l) lc[l] = 0;
  for (int r = tid * 32; r < tid * 32 + 32; ++r) {
    int l = lab[r]; l = (l < 0) ? 0 : (l > 9 ? 9 : l);
    lc[l]++;
  }
#pragma unroll
  for (int l = 0; l < NLAB; ++l) cnt[l][tid] = lc[l];
  __syncthreads();
  if (tid < NLAB) {  // exclusive scan over threads for label tid
    int run = 0;
    for (int i = 0; i < 256; ++i) { int v = cnt[tid][i]; cnt[tid][i] = run; run += v; }
    counts[tid] = run;
  }
  __syncthreads();
  if (tid == 0) {
    int run = 0;
    for (int l = 0; l < NLAB; ++l) { labOff[l] = run; run += counts[l]; }
    labOff[NLAB] = run;
    for (int l = 0; l <= NLAB; ++l) offs[l] = labOff[l];
  }
  __syncthreads();
  int lc2[NLAB];
#pragma unroll
  for (int l = 0; l < NLAB; ++l) lc2[l] = 0;
  for (int r = tid * 32; r < tid * 32 + 32; ++r) {
    int l = lab[r]; l = (l < 0) ? 0 : (l > 9 ? 9 : l);
    int pos = labOff[l] + cnt[l][tid] + lc2[l];
    lc2[l]++;
    perm[pos] = r;
  }
}

// zs[d] = z[perm[d]]  (row gather, float4)
__global__ __launch_bounds__(256)
void gather_k(const float* z, const int* perm, float* zs) {
  int g = blockIdx.x * 256 + threadIdx.x;        // 8192*32 float4s
  int row = g >> 5, q = g & 31;
  const float4* zf = (const float4*)z;
  float4* of = (float4*)zs;
  of[(size_t)row * 32 + q] = zf[(size_t)perm[row] * 32 + q];
}

// ---------------------------------------------------------------------------
// Label/global column sums over sorted zs. grid 88: l=blk/8 (l==10 -> total).
// ---------------------------------------------------------------------------
__global__ __launch_bounds__(128)
void labstat_part_k(const float* zs, const int* offs, double* part) {
  int l = blockIdx.x >> 3, s = blockIdx.x & 7;
  int j = threadIdx.x;
  int r0, r1;
  if (l < NLAB) {
    int st = offs[l], en = offs[l + 1], len = en - st;
    r0 = st + (int)(((long long)len * s) >> 3);
    r1 = st + (int)(((long long)len * (s + 1)) >> 3);
  } else {
    r0 = s * 1024; r1 = r0 + 1024;
  }
  double acc = 0.0;
  for (int r = r0; r < r1; ++r) acc += (double)zs[(size_t)r * K_N + j];
  part[((size_t)l * 8 + s) * K_N + j] = acc;
}

__global__ __launch_bounds__(128)
void labstat_comb_k(const double* part, float* sum_mu, float* muT) {
  int j = threadIdx.x;
  for (int l = 0; l < NLAB; ++l) {
    double a = 0.0;
    for (int s = 0; s < 8; ++s) a += part[((size_t)l * 8 + s) * K_N + j];
    sum_mu[l * K_N + j] = (float)a;
  }
  double t = 0.0;
  for (int s = 0; s < 8; ++s) t += part[((size_t)NLAB * 8 + s) * K_N + j];
  muT[j] = (float)(t / (double)B_N);
}

// ---------------------------------------------------------------------------
// Per-label Sigma sums from sorted segments (no masking). grid 40.
// ---------------------------------------------------------------------------
__global__ __launch_bounds__(256)
void sigsum_k(const float* zs, const int* offs, const float* muT, float* SigS) {
  int l = blockIdx.x >> 2, t = blockIdx.x & 3;
  int i0 = (t >> 1) * 64, j0 = (t & 1) * 64;
  __shared__ float Zi[32][66], Zj[32][66];
  __shared__ float muL[128];
  int tid = threadIdx.x, tx = tid & 15, ty = tid >> 4;
  if (tid < 128) muL[tid] = muT[tid];
  __syncthreads();
  int start = offs[l], end = offs[l + 1];
  float acc[4][4] = {};
  for (int base = start; base < end; base += 32) {
#pragma unroll
    for (int p = 0; p < 8; ++p) {
      int idx = tid + p * 256;
      int rr = idx >> 6, cc = idx & 63;
      int r = base + rr;
      float vi = 0.0f, vj = 0.0f;
      if (r < end) {
        vi = zs[(size_t)r * K_N + i0 + cc] - muL[i0 + cc];
        vj = zs[(size_t)r * K_N + j0 + cc] - muL[j0 + cc];
      }
      Zi[rr][cc] = vi; Zj[rr][cc] = vj;
    }
    __syncthreads();
    for (int rr = 0; rr < 32; ++rr) {
      float ra[4], rb[4];
#pragma unroll
      for (int r = 0; r < 4; ++r) ra[r] = Zi[rr][ty * 4 + r];
#pragma unroll
      for (int c = 0; c < 4; ++c) rb[c] = Zj[rr][tx * 4 + c];
#pragma unroll
      for (int r = 0; r < 4; ++r)
#pragma unroll
        for (int c = 0; c < 4; ++c) acc[r][c] += ra[r] * rb[c];
    }
    __syncthreads();
  }
#pragma unroll
  for (int r = 0; r < 4; ++r)
#pragma unroll
    for (int c = 0; c < 4; ++c)
      SigS[((size_t)l * K_N + i0 + ty * 4 + r) * K_N + j0 + tx * 4 + c] = acc[r][c];
}

// SigT = I + (sum_l SigS[l]) / B
__global__ __launch_bounds__(256)
void sigt_comb_k(const float* SigS, float* SigT) {
  int idx = blockIdx.x * 256 + threadIdx.x;
  int i = idx >> 7, j = idx & 127;
  double s = 0.0;
  for (int l = 0; l < NLAB; ++l) s += (double)SigS[(size_t)l * 16384 + idx];
  SigT[idx] = (float)(s / (double)B_N) + ((i == j) ? 1.0f : 0.0f);
}

// ---------------------------------------------------------------------------
// Per-label KL pieces: tr, maha, logdet_F -> kl[l]   (round-1 validated)
// ---------------------------------------------------------------------------
__global__ __launch_bounds__(256)
void perlabel_k(const float* SigS, const float* Sinv, const float* mu,
                const float* sum_mu, const int* counts, const double* logdet_t,
                double* klout, int* present) {
  int l = blockIdx.x, tid = threadIdx.x;
  __shared__ float Amat[128][129];
  __shared__ double red[256];
  __shared__ float dv[128];
  __shared__ float colj[128];
  int cnt = counts[l];
  float sc = (cnt > 0) ? (float)cnt : 1.0f;
  for (int idx = tid; idx < 128 * 128; idx += 256) {
    int i = idx >> 7, j = idx & 127;
    Amat[i][j] = SigS[((size_t)l * K_N + i) * K_N + j] / sc + ((i == j) ? 1.0f : 0.0f);
  }
  if (tid < 128) dv[tid] = mu[tid] - sum_mu[l * K_N + tid] / sc;
  __syncthreads();
  double tr = 0.0, mh = 0.0;
  for (int idx = tid; idx < 128 * 128; idx += 256) {
    int i = idx >> 7, j = idx & 127;
    double sv = (double)Sinv[idx];
    tr += sv * (double)Amat[i][j];
    mh += sv * (double)dv[i] * (double)dv[j];
  }
  red[tid] = tr; __syncthreads();
  for (int off = 128; off > 0; off >>= 1) { if (tid < off) red[tid] += red[tid + off]; __syncthreads(); }
  double trv = red[0]; __syncthreads();
  red[tid] = mh; __syncthreads();
  for (int off = 128; off > 0; off >>= 1) { if (tid < off) red[tid] += red[tid + off]; __syncthreads(); }
  double mhv = red[0]; __syncthreads();
  for (int j = 0; j < 128; ++j) {
    if (tid == 0) Amat[j][j] = sqrtf(fmaxf(Amat[j][j], 1e-20f));
    __syncthreads();
    float pj = Amat[j][j];
    for (int i = j + 1 + tid; i < 128; i += 256) {
      float v = Amat[i][j] / pj;
      Amat[i][j] = v; colj[i] = v;
    }
    __syncthreads();
    for (int i = j + 1 + tid; i < 128; i += 256) {
      float ci = colj[i];
      for (int t2 = j + 1; t2 <= i; ++t2) Amat[i][t2] -= ci * colj[t2];
    }
    __syncthreads();
  }
  if (tid == 0) {
    double ld = 0.0;
    for (int j = 0; j < 128; ++j) ld += log((double)Amat[j][j]);
    ld *= 2.0;
    klout[l] = 0.5 * (trv + mhv - 128.0 + logdet_t[0] - ld);
    present[l] = (cnt > 0) ? 1 : 0;
  }
}

__global__ void finalize_k(const double* kl, const int* present, float* out) {
  if (threadIdx.x == 0 && blockIdx.x == 0) {
    double s = 0.0; int np = 0;
    for (int l = 0; l < NLAB; ++l)
      if (present[l]) { s += kl[l]; np++; }
    out[0] = (float)((np > 0) ? s / ((double)np * (double)B_N) : 0.0);
  }
}

// ===========================================================================
// Host side
// ===========================================================================
static inline void launch_gemm(hipStream_t st, bool akm,
                               const float* A, int lda, const float* B, int ldb,
                               float* C, int ldc, int M, int N, int K, float alpha,
                               const float* u = nullptr, const float* v = nullptr,
                               float r1c = 0.0f,
                               const float* radd = nullptr, float raddc = 0.0f,
                               float addI = 0.0f) {
  GArgs g{A, B, C, lda, ldb, ldc, K, alpha, u, v, r1c, radd, raddc, addI};
  dim3 grid(M / 64, N / 64);
  if (akm) hipLaunchKernelGGL((gemm_k<true>), grid, dim3(256), 0, st, g);
  else     hipLaunchKernelGGL((gemm_k<false>), grid, dim3(256), 0, st, g);
}

extern "C" void kernel_launch(void* const* d_in, const int* in_sizes, int n_in,
                              void* d_out, int out_size, void* d_ws, size_t ws_size,
                              hipStream_t stream) {
  const float* x = (const float*)d_in[0];
  const int* lab = (const int*)d_in[1];
  float* out = (float*)d_out;

  size_t off = 0;
  auto alloc = [&](size_t nbytes) -> void* {
    void* r = (void*)((char*)d_ws + off);
    off += ((nbytes + 255) / 256) * 256;
    return r;
  };
  float*  m     = (float*) alloc(D_N * 4);
  float*  Cn    = (float*) alloc((size_t)D_N * D_N * 4);      // later aliased by zs
  float*  S1    = (float*) alloc((size_t)D_N * M_N * 4);
  float*  S2    = (float*) alloc((size_t)D_N * M_N * 4);
  float*  G256  = (float*) alloc((size_t)M_N * M_N * 4);
  float*  Li256 = (float*) alloc((size_t)M_N * M_N * 4);
  float*  Tm    = (float*) alloc((size_t)M_N * M_N * 4);
  float*  Va    = (float*) alloc((size_t)M_N * K_N * 4);
  float*  Vb    = (float*) alloc((size_t)M_N * K_N * 4);
  float*  G128  = (float*) alloc((size_t)K_N * K_N * 4);
  float*  Li128 = (float*) alloc((size_t)K_N * K_N * 4);
  float*  Wb    = (float*) alloc((size_t)D_N * K_N * 4);
  float*  mW    = (float*) alloc(K_N * 4);
  float*  z     = (float*) alloc((size_t)B_N * K_N * 4);
  double* partM = (double*)alloc((size_t)16 * D_N * 8);
  double* partL = (double*)alloc((size_t)11 * 8 * K_N * 8);
  float*  sumMu = (float*) alloc(NLAB * K_N * 4);
  float*  muT   = (float*) alloc(K_N * 4);
  float*  SigT  = (float*) alloc((size_t)K_N * K_N * 4);
  float*  Sinv  = (float*) alloc((size_t)K_N * K_N * 4);
  float*  SigS  = (float*) alloc((size_t)NLAB * K_N * K_N * 4);
  double* logdet_t = (double*)alloc(16);
  double* klv      = (double*)alloc(NLAB * 8);
  int*    counts = (int*)alloc(16 * 4);
  int*    offs   = (int*)alloc(16 * 4);
  int*    present= (int*)alloc(16 * 4);
  int*    perm   = (int*)alloc(B_N * 4);
  float*  zs     = Cn;  // alias: Cn dead after T formation, zs written after
  (void)in_sizes; (void)n_in; (void)out_size; (void)ws_size;

  // 1) column means (2-phase); Cn = x^T x / B - m m^T
  hipLaunchKernelGGL(colmean_part_k, dim3(4, 16), dim3(256), 0, stream, x, partM);
  hipLaunchKernelGGL(colmean_comb_k, dim3(4), dim3(256), 0, stream, partM, m);
  launch_gemm(stream, true, x, D_N, x, D_N, Cn, D_N, D_N, D_N, B_N,
              1.0f / (float)B_N, m, m, -1.0f);

  // 2) outer subspace iteration: 32 applies, CholQR-256 every 8
  hipLaunchKernelGGL(inits_k, dim3((D_N * M_N + 255) / 256), dim3(256), 0, stream,
                     S1, D_N * M_N, 12345u);
  float* cur = S1; float* oth = S2;
  for (int it = 1; it <= 32; ++it) {
    launch_gemm(stream, true, Cn, D_N, cur, M_N, oth, M_N, D_N, M_N, D_N, 1.0f);
    { float* t = cur; cur = oth; oth = t; }
    if ((it & 7) == 0) {
      launch_gemm(stream, true, cur, M_N, cur, M_N, G256, M_N, M_N, M_N, D_N, 1.0f);
      hipLaunchKernelGGL(chol256g_k, dim3(1), dim3(256), 0, stream, G256, M_N, Li256);
      launch_gemm(stream, false, cur, M_N, Li256, M_N, oth, M_N, D_N, M_N, M_N, 1.0f);
      { float* t = cur; cur = oth; oth = t; }
    }
  }

  // 3) T = S^T (Cn S)
  launch_gemm(stream, true, Cn, D_N, cur, M_N, oth, M_N, D_N, M_N, D_N, 1.0f); // Yf
  launch_gemm(stream, true, cur, M_N, oth, M_N, Tm, M_N, M_N, M_N, D_N, 1.0f); // T

  // 4) inner split: 48 power applies of T on 256x128, CholQR-128 every 8.
  //    (only the SPAN of top-128 matters; boundary mixing is statistically inert)
  hipLaunchKernelGGL(inits_k, dim3((M_N * K_N + 255) / 256), dim3(256), 0, stream,
                     Va, M_N * K_N, 777u);
  float* vcur = Va; float* voth = Vb;
  for (int it = 1; it <= 48; ++it) {
    launch_gemm(stream, true, Tm, M_N, vcur, K_N, voth, K_N, M_N, K_N, M_N, 1.0f);
    { float* t = vcur; vcur = voth; voth = t; }
    if ((it & 7) == 0) {
      launch_gemm(stream, true, vcur, K_N, vcur, K_N, G128, K_N, K_N, K_N, M_N, 1.0f);
      hipLaunchKernelGGL(chol128_k, dim3(1), dim3(256), 0, stream,
                         G128, Li128, (double*)nullptr, (float*)nullptr);
      launch_gemm(stream, false, vcur, K_N, Li128, K_N, voth, K_N, M_N, K_N, K_N, 1.0f);
      { float* t = vcur; vcur = voth; voth = t; }
    }
  }

  // 5) W = S*V  (Wa reuses the dead Yf buffer), then exact CholQR-128 on W
  float* Wa = oth;  // 1024x256 buffer holds 1024x128 fine; Yf dead
  launch_gemm(stream, false, cur, M_N, vcur, K_N, Wa, K_N, D_N, K_N, M_N, 1.0f);
  launch_gemm(stream, true, Wa, K_N, Wa, K_N, G128, K_N, K_N, K_N, D_N, 1.0f);
  hipLaunchKernelGGL(chol128_k, dim3(1), dim3(256), 0, stream,
                     G128, Li128, (double*)nullptr, (float*)nullptr);
  launch_gemm(stream, false, Wa, K_N, Li128, K_N, Wb, K_N, D_N, K_N, K_N, 1.0f);

  // 6) z = x W - 1 (m^T W)
  hipLaunchKernelGGL(mw_k, dim3(1), dim3(128), 0, stream, m, Wb, mW);
  launch_gemm(stream, false, x, D_N, Wb, K_N, z, K_N, B_N, K_N, D_N, 1.0f,
              nullptr, nullptr, 0.0f, mW, -1.0f);

  // 7) sort rows by label; gather into zs (aliases Cn, now dead)
  hipLaunchKernelGGL(count_sort_k, dim3(1), dim3(256), 0, stream,
                     lab, perm, counts, offs);
  hipLaunchKernelGGL(gather_k, dim3(B_N * 32 / 256), dim3(256), 0, stream,
                     z, perm, zs);

  // 8) label and global column sums
  hipLaunchKernelGGL(labstat_part_k, dim3(11 * 8), dim3(128), 0, stream,
                     zs, offs, partL);
  hipLaunchKernelGGL(labstat_comb_k, dim3(1), dim3(128), 0, stream,
                     partL, sumMu, muT);

  // 9) per-label Sigma sums; SigT = I + (sum_l SigS)/B; Sinv + logdet
  hipLaunchKernelGGL(sigsum_k, dim3(NLAB * 4), dim3(256), 0, stream,
                     zs, offs, muT, SigS);
  hipLaunchKernelGGL(sigt_comb_k, dim3(64), dim3(256), 0, stream, SigS, SigT);
  hipLaunchKernelGGL(chol128_k, dim3(1), dim3(256), 0, stream,
                     SigT, (float*)nullptr, logdet_t, Sinv);

  // 10) per-label KL, reduce
  hipLaunchKernelGGL(perlabel_k, dim3(NLAB), dim3(256), 0, stream,
                     SigS, Sinv, muT, sumMu, counts, logdet_t, klv, present);
  hipLaunchKernelGGL(finalize_k, dim3(1), dim3(64), 0, stream, klv, present, out);
}

// Round 3
// 9189.881 us; speedup vs baseline: 10.8399x; 4.7230x over previous
//
#include <hip/hip_runtime.h>
#include <hip/hip_bf16.h>
#include <math.h>

// ============================================================================
// GMMLoss2_pca v3: Chebyshev-filtered subspace iteration (outer 256-cushion on
// Cn, inner 128 on T) with blocked-128 LDS CholQR (no global-memory chol256),
// then faithful per-label Gaussian KL. All heavy serial kernels eliminated.
// ============================================================================

#define B_N 8192
#define D_N 1024
#define K_N 128
#define M_N 256
#define NLAB 10

__device__ __forceinline__ float hashf(unsigned x) {
  x ^= x >> 16; x *= 0x7feb352du; x ^= x >> 15; x *= 0x846ca68bu; x ^= x >> 16;
  return (float)(x >> 8) * (1.0f / 16777216.0f) - 0.5f;
}

// ---------------------------------------------------------------------------
// Tiled f32 GEMM: C[i][j] = alpha * sum_k A(k,i)*B(k,j) + b1*C1 + b2*C2
//                 + r1c*u[i]*v[j] + raddc*radd[j]
// AKM=true : A(k,i) at A[k*lda+i];  AKM=false: A(i,k) at A[i*lda+k].
// BT=false : B(k,j) at B[k*ldb+j];  BT=true : B(k,j) at B[j*ldb+k].
// M,N multiples of 64; K multiple of 32.
// ---------------------------------------------------------------------------
struct GArgs {
  const float* A; const float* B; float* C;
  int lda, ldb, ldc, K;
  float alpha;
  const float* C1; float b1; int ldc1;
  const float* C2; float b2; int ldc2;
  const float* r1u; const float* r1v; float r1c;
  const float* radd; float raddc;
};

template <bool AKM, bool BT>
__global__ __launch_bounds__(256)
void gemm_k(GArgs g) {
  __shared__ __align__(16) float AsRaw[2176]; // AKM: [32][68]; !AKM: [64][33]
  __shared__ __align__(16) float Bs[32 * 68];
  const int tid = threadIdx.x;
  const int tx = tid & 15, ty = tid >> 4;
  const int i0 = blockIdx.x * 64, j0 = blockIdx.y * 64;
  float acc[4][4] = {};
  for (int k0 = 0; k0 < g.K; k0 += 32) {
    if (AKM) {
#pragma unroll
      for (int p = 0; p < 8; ++p) {
        int idx = tid + p * 256;
        int kk = idx >> 6, ii = idx & 63;
        AsRaw[kk * 68 + ii] = g.A[(size_t)(k0 + kk) * g.lda + i0 + ii];
      }
    } else {
#pragma unroll
      for (int p = 0; p < 8; ++p) {
        int idx = tid + p * 256;
        int ii = idx >> 5, kk = idx & 31;
        AsRaw[ii * 33 + kk] = g.A[(size_t)(i0 + ii) * g.lda + k0 + kk];
      }
    }
    if (BT) {
#pragma unroll
      for (int p = 0; p < 8; ++p) {
        int idx = tid + p * 256;
        int jj = idx >> 5, kk = idx & 31;
        Bs[kk * 68 + jj] = g.B[(size_t)(j0 + jj) * g.ldb + k0 + kk];
      }
    } else {
#pragma unroll
      for (int p = 0; p < 8; ++p) {
        int idx = tid + p * 256;
        int kk = idx >> 6, jj = idx & 63;
        Bs[kk * 68 + jj] = g.B[(size_t)(k0 + kk) * g.ldb + j0 + jj];
      }
    }
    __syncthreads();
#pragma unroll 8
    for (int kk = 0; kk < 32; ++kk) {
      float ra[4], rb[4];
      if (AKM) {
        const float4 va = *(const float4*)&AsRaw[kk * 68 + ty * 4];
        ra[0] = va.x; ra[1] = va.y; ra[2] = va.z; ra[3] = va.w;
      } else {
#pragma unroll
        for (int r = 0; r < 4; ++r) ra[r] = AsRaw[(ty * 4 + r) * 33 + kk];
      }
      const float4 vb = *(const float4*)&Bs[kk * 68 + tx * 4];
      rb[0] = vb.x; rb[1] = vb.y; rb[2] = vb.z; rb[3] = vb.w;
#pragma unroll
      for (int r = 0; r < 4; ++r)
#pragma unroll
        for (int c = 0; c < 4; ++c) acc[r][c] += ra[r] * rb[c];
    }
    __syncthreads();
  }
#pragma unroll
  for (int r = 0; r < 4; ++r)
#pragma unroll
    for (int c = 0; c < 4; ++c) {
      int gi = i0 + ty * 4 + r, gj = j0 + tx * 4 + c;
      float v = g.alpha * acc[r][c];
      if (g.C1) v += g.b1 * g.C1[(size_t)gi * g.ldc1 + gj];
      if (g.C2) v += g.b2 * g.C2[(size_t)gi * g.ldc2 + gj];
      if (g.r1u) v += g.r1c * g.r1u[gi] * g.r1v[gj];
      if (g.radd) v += g.raddc * g.radd[gj];
      g.C[(size_t)gi * g.ldc + gj] = v;
    }
}

// ---------------------------------------------------------------------------
// Column means, 2-phase parallel.
// ---------------------------------------------------------------------------
__global__ __launch_bounds__(256)
void colmean_part_k(const float* x, double* part) {
  int col = blockIdx.x * 256 + threadIdx.x;
  int rs = blockIdx.y;
  double acc = 0.0;
  for (int r = rs * 512; r < (rs + 1) * 512; ++r)
    acc += (double)x[(size_t)r * D_N + col];
  part[(size_t)rs * D_N + col] = acc;
}

__global__ __launch_bounds__(256)
void colmean_comb_k(const double* part, float* m) {
  int col = blockIdx.x * 256 + threadIdx.x;
  double acc = 0.0;
  for (int rs = 0; rs < 16; ++rs) acc += part[(size_t)rs * D_N + col];
  m[col] = (float)(acc / (double)B_N);
}

__global__ void inits_k(float* S, int n, unsigned seed) {
  int i = blockIdx.x * 256 + threadIdx.x;
  if (i < n) S[i] = hashf((unsigned)i * 2654435761u + seed);
}

// ---------------------------------------------------------------------------
// LDS Cholesky n=128 (input ldg), + LinvT (LinvT[c][i]=Linv[i][c]) via 2x2
// blocked triangular inverse (+ optional logdet, Sinv). One WG, 256 threads.
// ---------------------------------------------------------------------------
__global__ __launch_bounds__(256)
void chol128_k(const float* Gin, int ldg, float* LinvT, double* logdet, float* Sinv) {
  __shared__ float A[128][129];
  __shared__ float Bm[128][129];   // M[c][i] = Linv[i][c]
  __shared__ float Y[64][65];
  __shared__ float colj[128];
  const int tid = threadIdx.x;
  for (int idx = tid; idx < 128 * 128; idx += 256)
    A[idx >> 7][idx & 127] = Gin[(size_t)(idx >> 7) * ldg + (idx & 127)];
  for (int idx = tid; idx < 128 * 129; idx += 256)
    (&Bm[0][0])[idx] = 0.0f;
  __syncthreads();
  // Cholesky factor (lower) in LDS
  for (int j = 0; j < 128; ++j) {
    if (tid == 0) A[j][j] = sqrtf(fmaxf(A[j][j], 1e-20f));
    __syncthreads();
    float pj = A[j][j];
    for (int i = j + 1 + tid; i < 128; i += 256) {
      float v = A[i][j] / pj;
      A[i][j] = v; colj[i] = v;
    }
    __syncthreads();
    for (int i = j + 1 + tid; i < 128; i += 256) {
      float ci = colj[i];
      for (int t = j + 1; t <= i; ++t) A[i][t] -= ci * colj[t];
    }
    __syncthreads();
  }
  if (logdet && tid == 0) {
    double s = 0.0;
    for (int j = 0; j < 128; ++j) s += log((double)A[j][j]);
    *logdet = 2.0 * s;
  }
  // Blocked inverse: L=[[L00,0],[L10,L11]]; Linv=[[L00i,0],[-L11i L10 L00i, L11i]]
  if (tid < 128) {
    int o = (tid >> 6) * 64;
    int c = tid & 63;
    for (int i = c; i < 64; ++i) {
      float s = (i == c) ? 1.0f : 0.0f;
      for (int t = c; t < i; ++t) s -= A[o + i][o + t] * Bm[o + c][o + t];
      Bm[o + c][o + i] = s / A[o + i][o + i];
    }
  }
  __syncthreads();
  // Y = L10 * L00inv:  Y[t][c] = sum_s A[64+t][s] * Bm[c][s]
  for (int idx = tid; idx < 64 * 64; idx += 256) {
    int t = idx >> 6, c = idx & 63;
    float s = 0.0f;
    for (int s2 = c; s2 < 64; ++s2) s += A[64 + t][s2] * Bm[c][s2];
    Y[t][c] = s;
  }
  __syncthreads();
  // X[a][c] = -sum_t L11inv[a][t] * Y[t][c];  L11inv[a][t] = Bm[64+t][64+a]
  for (int idx = tid; idx < 64 * 64; idx += 256) {
    int a = idx >> 6, c = idx & 63;
    float s = 0.0f;
    for (int t = 0; t <= a; ++t) s -= Bm[64 + t][64 + a] * Y[t][c];
    Bm[c][64 + a] = s;
  }
  __syncthreads();
  if (LinvT)
    for (int idx = tid; idx < 128 * 128; idx += 256)
      LinvT[idx] = Bm[idx >> 7][idx & 127];
  if (Sinv)
    for (int idx = tid; idx < 128 * 128; idx += 256) {
      int i = idx >> 7, j = idx & 127;
      int t0 = (i > j) ? i : j;
      float s = 0.0f;
      for (int t = t0; t < 128; ++t) s += Bm[i][t] * Bm[j][t];
      Sinv[idx] = s;
    }
}

// ---------------------------------------------------------------------------
// mW[j] = sum_c m[c] * W[c][j]
// ---------------------------------------------------------------------------
__global__ __launch_bounds__(128)
void mw_k(const float* m, const float* W, float* mW) {
  int j = threadIdx.x;
  double acc = 0.0;
  for (int c = 0; c < D_N; ++c) acc += (double)m[c] * (double)W[(size_t)c * K_N + j];
  mW[j] = (float)acc;
}

// ---------------------------------------------------------------------------
// Deterministic stable counting sort of 8192 labels (one WG).
// ---------------------------------------------------------------------------
__global__ __launch_bounds__(256)
void count_sort_k(const int* lab, int* perm, int* counts, int* offs) {
  __shared__ int cnt[NLAB][256];
  __shared__ int labOff[NLAB + 1];
  const int tid = threadIdx.x;
  int lc[NLAB];
#pragma unroll
  for (int l = 0; l < NLAB; ++l) lc[l] = 0;
  for (int r = tid * 32; r < tid * 32 + 32; ++r) {
    int l = lab[r]; l = (l < 0) ? 0 : (l > 9 ? 9 : l);
    lc[l]++;
  }
#pragma unroll
  for (int l = 0; l < NLAB; ++l) cnt[l][tid] = lc[l];
  __syncthreads();
  if (tid < NLAB) {
    int run = 0;
    for (int i = 0; i < 256; ++i) { int v = cnt[tid][i]; cnt[tid][i] = run; run += v; }
    counts[tid] = run;
  }
  __syncthreads();
  if (tid == 0) {
    int run = 0;
    for (int l = 0; l < NLAB; ++l) { labOff[l] = run; run += counts[l]; }
    labOff[NLAB] = run;
    for (int l = 0; l <= NLAB; ++l) offs[l] = labOff[l];
  }
  __syncthreads();
  int lc2[NLAB];
#pragma unroll
  for (int l = 0; l < NLAB; ++l) lc2[l] = 0;
  for (int r = tid * 32; r < tid * 32 + 32; ++r) {
    int l = lab[r]; l = (l < 0) ? 0 : (l > 9 ? 9 : l);
    int pos = labOff[l] + cnt[l][tid] + lc2[l];
    lc2[l]++;
    perm[pos] = r;
  }
}

__global__ __launch_bounds__(256)
void gather_k(const float* z, const int* perm, float* zs) {
  int g = blockIdx.x * 256 + threadIdx.x;
  int row = g >> 5, q = g & 31;
  const float4* zf = (const float4*)z;
  float4* of = (float4*)zs;
  of[(size_t)row * 32 + q] = zf[(size_t)perm[row] * 32 + q];
}

// ---------------------------------------------------------------------------
// Label/global column sums over sorted zs. grid 88: l=blk/8 (l==10 -> total).
// ---------------------------------------------------------------------------
__global__ __launch_bounds__(128)
void labstat_part_k(const float* zs, const int* offs, double* part) {
  int l = blockIdx.x >> 3, s = blockIdx.x & 7;
  int j = threadIdx.x;
  int r0, r1;
  if (l < NLAB) {
    int st = offs[l], en = offs[l + 1], len = en - st;
    r0 = st + (int)(((long long)len * s) >> 3);
    r1 = st + (int)(((long long)len * (s + 1)) >> 3);
  } else {
    r0 = s * 1024; r1 = r0 + 1024;
  }
  double acc = 0.0;
  for (int r = r0; r < r1; ++r) acc += (double)zs[(size_t)r * K_N + j];
  part[((size_t)l * 8 + s) * K_N + j] = acc;
}

__global__ __launch_bounds__(128)
void labstat_comb_k(const double* part, float* sum_mu, float* muT) {
  int j = threadIdx.x;
  for (int l = 0; l < NLAB; ++l) {
    double a = 0.0;
    for (int s = 0; s < 8; ++s) a += part[((size_t)l * 8 + s) * K_N + j];
    sum_mu[l * K_N + j] = (float)a;
  }
  double t = 0.0;
  for (int s = 0; s < 8; ++s) t += part[((size_t)NLAB * 8 + s) * K_N + j];
  muT[j] = (float)(t / (double)B_N);
}

// ---------------------------------------------------------------------------
// Per-label Sigma sums from sorted segments. grid 40.
// ---------------------------------------------------------------------------
__global__ __launch_bounds__(256)
void sigsum_k(const float* zs, const int* offs, const float* muT, float* SigS) {
  int l = blockIdx.x >> 2, t = blockIdx.x & 3;
  int i0 = (t >> 1) * 64, j0 = (t & 1) * 64;
  __shared__ float Zi[32][66], Zj[32][66];
  __shared__ float muL[128];
  int tid = threadIdx.x, tx = tid & 15, ty = tid >> 4;
  if (tid < 128) muL[tid] = muT[tid];
  __syncthreads();
  int start = offs[l], end = offs[l + 1];
  float acc[4][4] = {};
  for (int base = start; base < end; base += 32) {
#pragma unroll
    for (int p = 0; p < 8; ++p) {
      int idx = tid + p * 256;
      int rr = idx >> 6, cc = idx & 63;
      int r = base + rr;
      float vi = 0.0f, vj = 0.0f;
      if (r < end) {
        vi = zs[(size_t)r * K_N + i0 + cc] - muL[i0 + cc];
        vj = zs[(size_t)r * K_N + j0 + cc] - muL[j0 + cc];
      }
      Zi[rr][cc] = vi; Zj[rr][cc] = vj;
    }
    __syncthreads();
    for (int rr = 0; rr < 32; ++rr) {
      float ra[4], rb[4];
#pragma unroll
      for (int r = 0; r < 4; ++r) ra[r] = Zi[rr][ty * 4 + r];
#pragma unroll
      for (int c = 0; c < 4; ++c) rb[c] = Zj[rr][tx * 4 + c];
#pragma unroll
      for (int r = 0; r < 4; ++r)
#pragma unroll
        for (int c = 0; c < 4; ++c) acc[r][c] += ra[r] * rb[c];
    }
    __syncthreads();
  }
#pragma unroll
  for (int r = 0; r < 4; ++r)
#pragma unroll
    for (int c = 0; c < 4; ++c)
      SigS[((size_t)l * K_N + i0 + ty * 4 + r) * K_N + j0 + tx * 4 + c] = acc[r][c];
}

__global__ __launch_bounds__(256)
void sigt_comb_k(const float* SigS, float* SigT) {
  int idx = blockIdx.x * 256 + threadIdx.x;
  int i = idx >> 7, j = idx & 127;
  double s = 0.0;
  for (int l = 0; l < NLAB; ++l) s += (double)SigS[(size_t)l * 16384 + idx];
  SigT[idx] = (float)(s / (double)B_N) + ((i == j) ? 1.0f : 0.0f);
}

// ---------------------------------------------------------------------------
// Per-label KL pieces.
// ---------------------------------------------------------------------------
__global__ __launch_bounds__(256)
void perlabel_k(const float* SigS, const float* Sinv, const float* mu,
                const float* sum_mu, const int* counts, const double* logdet_t,
                double* klout, int* present) {
  int l = blockIdx.x, tid = threadIdx.x;
  __shared__ float Amat[128][129];
  __shared__ double red[256];
  __shared__ float dv[128];
  __shared__ float colj[128];
  int cnt = counts[l];
  float sc = (cnt > 0) ? (float)cnt : 1.0f;
  for (int idx = tid; idx < 128 * 128; idx += 256) {
    int i = idx >> 7, j = idx & 127;
    Amat[i][j] = SigS[((size_t)l * K_N + i) * K_N + j] / sc + ((i == j) ? 1.0f : 0.0f);
  }
  if (tid < 128) dv[tid] = mu[tid] - sum_mu[l * K_N + tid] / sc;
  __syncthreads();
  double tr = 0.0, mh = 0.0;
  for (int idx = tid; idx < 128 * 128; idx += 256) {
    int i = idx >> 7, j = idx & 127;
    double sv = (double)Sinv[idx];
    tr += sv * (double)Amat[i][j];
    mh += sv * (double)dv[i] * (double)dv[j];
  }
  red[tid] = tr; __syncthreads();
  for (int off = 128; off > 0; off >>= 1) { if (tid < off) red[tid] += red[tid + off]; __syncthreads(); }
  double trv = red[0]; __syncthreads();
  red[tid] = mh; __syncthreads();
  for (int off = 128; off > 0; off >>= 1) { if (tid < off) red[tid] += red[tid + off]; __syncthreads(); }
  double mhv = red[0]; __syncthreads();
  for (int j = 0; j < 128; ++j) {
    if (tid == 0) Amat[j][j] = sqrtf(fmaxf(Amat[j][j], 1e-20f));
    __syncthreads();
    float pj = Amat[j][j];
    for (int i = j + 1 + tid; i < 128; i += 256) {
      float v = Amat[i][j] / pj;
      Amat[i][j] = v; colj[i] = v;
    }
    __syncthreads();
    for (int i = j + 1 + tid; i < 128; i += 256) {
      float ci = colj[i];
      for (int t2 = j + 1; t2 <= i; ++t2) Amat[i][t2] -= ci * colj[t2];
    }
    __syncthreads();
  }
  if (tid == 0) {
    double ld = 0.0;
    for (int j = 0; j < 128; ++j) ld += log((double)Amat[j][j]);
    ld *= 2.0;
    klout[l] = 0.5 * (trv + mhv - 128.0 + logdet_t[0] - ld);
    present[l] = (cnt > 0) ? 1 : 0;
  }
}

__global__ void finalize_k(const double* kl, const int* present, float* out) {
  if (threadIdx.x == 0 && blockIdx.x == 0) {
    double s = 0.0; int np = 0;
    for (int l = 0; l < NLAB; ++l)
      if (present[l]) { s += kl[l]; np++; }
    out[0] = (float)((np > 0) ? s / ((double)np * (double)B_N) : 0.0);
  }
}

// ===========================================================================
// Host side
// ===========================================================================
static inline GArgs mkg(const float* A, int lda, const float* B, int ldb,
                        float* C, int ldc, int K, float alpha) {
  GArgs g{};
  g.A = A; g.B = B; g.C = C; g.lda = lda; g.ldb = ldb; g.ldc = ldc;
  g.K = K; g.alpha = alpha;
  return g;
}

static inline void launch_g(hipStream_t st, bool akm, bool bt, const GArgs& g,
                            int M, int N) {
  dim3 grid(M / 64, N / 64);
  if (akm)     hipLaunchKernelGGL((gemm_k<true, false>),  grid, dim3(256), 0, st, g);
  else if (bt) hipLaunchKernelGGL((gemm_k<false, true>),  grid, dim3(256), 0, st, g);
  else         hipLaunchKernelGGL((gemm_k<false, false>), grid, dim3(256), 0, st, g);
}

extern "C" void kernel_launch(void* const* d_in, const int* in_sizes, int n_in,
                              void* d_out, int out_size, void* d_ws, size_t ws_size,
                              hipStream_t stream) {
  const float* x = (const float*)d_in[0];
  const int* lab = (const int*)d_in[1];
  float* out = (float*)d_out;

  size_t off = 0;
  auto alloc = [&](size_t nbytes) -> void* {
    void* r = (void*)((char*)d_ws + off);
    off += ((nbytes + 255) / 256) * 256;
    return r;
  };
  float*  m     = (float*) alloc(D_N * 4);
  float*  Cn    = (float*) alloc((size_t)D_N * D_N * 4);  // aliased by zs later
  float*  SA    = (float*) alloc((size_t)D_N * M_N * 4);
  float*  SB    = (float*) alloc((size_t)D_N * M_N * 4);
  float*  SC    = (float*) alloc((size_t)D_N * M_N * 4);
  float*  G256  = (float*) alloc((size_t)M_N * M_N * 4);
  float*  Tm    = (float*) alloc((size_t)M_N * M_N * 4);
  float*  Li11T = (float*) alloc((size_t)K_N * K_N * 4);
  float*  Li22T = (float*) alloc((size_t)K_N * K_N * 4);
  float*  L21b  = (float*) alloc((size_t)K_N * K_N * 4);
  float*  S22b  = (float*) alloc((size_t)K_N * K_N * 4);
  float*  Pb    = (float*) alloc((size_t)K_N * K_N * 4);
  float*  XTb   = (float*) alloc((size_t)K_N * K_N * 4);
  float*  VA    = (float*) alloc((size_t)M_N * K_N * 4);
  float*  VB    = (float*) alloc((size_t)M_N * K_N * 4);
  float*  VC    = (float*) alloc((size_t)M_N * K_N * 4);
  float*  G128  = (float*) alloc((size_t)K_N * K_N * 4);
  float*  Li128 = (float*) alloc((size_t)K_N * K_N * 4);
  float*  Wa    = (float*) alloc((size_t)D_N * K_N * 4);
  float*  Wb    = (float*) alloc((size_t)D_N * K_N * 4);
  float*  mW    = (float*) alloc(K_N * 4);
  float*  z     = (float*) alloc((size_t)B_N * K_N * 4);
  double* partM = (double*)alloc((size_t)16 * D_N * 8);
  double* partL = (double*)alloc((size_t)11 * 8 * K_N * 8);
  float*  sumMu = (float*) alloc(NLAB * K_N * 4);
  float*  muT   = (float*) alloc(K_N * 4);
  float*  SigT  = (float*) alloc((size_t)K_N * K_N * 4);
  float*  Sinv  = (float*) alloc((size_t)K_N * K_N * 4);
  float*  SigS  = (float*) alloc((size_t)NLAB * K_N * K_N * 4);
  double* logdet_t = (double*)alloc(16);
  double* klv      = (double*)alloc(NLAB * 8);
  int*    counts = (int*)alloc(16 * 4);
  int*    offs   = (int*)alloc(16 * 4);
  int*    present= (int*)alloc(16 * 4);
  int*    perm   = (int*)alloc(B_N * 4);
  float*  zs     = Cn;  // alias: Cn dead after T formed; zs written after that
  (void)in_sizes; (void)n_in; (void)out_size; (void)ws_size;

  // 1) column means; Cn = x^T x / B - m m^T
  hipLaunchKernelGGL(colmean_part_k, dim3(4, 16), dim3(256), 0, stream, x, partM);
  hipLaunchKernelGGL(colmean_comb_k, dim3(4), dim3(256), 0, stream, partM, m);
  {
    GArgs g = mkg(x, D_N, x, D_N, Cn, D_N, B_N, 1.0f / (float)B_N);
    g.r1u = m; g.r1v = m; g.r1c = -1.0f;
    launch_g(stream, true, false, g, D_N, D_N);
  }

  // Blocked CholQR-256: S (1024x256) -> Snew; 2x chol128-LDS + 6 small gemms.
  auto qr256 = [&](float* S, float* Snew) {
    GArgs g = mkg(S, M_N, S, M_N, G256, M_N, D_N, 1.0f);          // G = S^T S
    launch_g(stream, true, false, g, M_N, M_N);
    hipLaunchKernelGGL(chol128_k, dim3(1), dim3(256), 0, stream,
                       G256, M_N, Li11T, (double*)nullptr, (float*)nullptr);
    g = mkg(G256 + 128 * M_N, M_N, Li11T, K_N, L21b, K_N, K_N, 1.0f);  // L21
    launch_g(stream, false, false, g, K_N, K_N);
    g = mkg(L21b, K_N, L21b, K_N, S22b, K_N, K_N, -1.0f);         // Schur
    g.C1 = G256 + 128 * M_N + 128; g.b1 = 1.0f; g.ldc1 = M_N;
    launch_g(stream, false, true, g, K_N, K_N);
    hipLaunchKernelGGL(chol128_k, dim3(1), dim3(256), 0, stream,
                       S22b, K_N, Li22T, (double*)nullptr, (float*)nullptr);
    g = mkg(L21b, K_N, Li11T, K_N, Pb, K_N, K_N, 1.0f);           // P = L21*L00inv
    launch_g(stream, false, true, g, K_N, K_N);
    g = mkg(Pb, K_N, Li22T, K_N, XTb, K_N, K_N, -1.0f);           // XT[i][j]=X[j][i]
    launch_g(stream, true, false, g, K_N, K_N);
    g = mkg(S, M_N, Li11T, K_N, Snew, M_N, K_N, 1.0f);            // cols 0..127
    launch_g(stream, false, false, g, D_N, K_N);
    g = mkg(S, M_N, XTb, K_N, Snew + 128, M_N, K_N, 1.0f);        // cols 128.. (X part)
    launch_g(stream, false, false, g, D_N, K_N);
    g = mkg(S + 128, M_N, Li22T, K_N, Snew + 128, M_N, K_N, 1.0f);// += L22inv part
    g.C1 = Snew + 128; g.b1 = 1.0f; g.ldc1 = M_N;
    launch_g(stream, false, false, g, D_N, K_N);
  };

  // 2) Outer Chebyshev subspace iteration: 3 segments x 5 applies, damp [0,1.32]
  const float cO = 0.66f, dO = 0.66f;
  hipLaunchKernelGGL(inits_k, dim3((D_N * M_N + 255) / 256), dim3(256), 0, stream,
                     SA, D_N * M_N, 12345u);
  float* Scur = SA;
  float* f1 = SB;
  float* f2 = SC;
  for (int seg = 0; seg < 3; ++seg) {
    float* zp = Scur;  // Z0
    float* zc = f1;    // Z1
    float* zn = f2;
    {
      GArgs g = mkg(Cn, D_N, zp, M_N, zc, M_N, D_N, 1.0f / cO);
      g.C1 = zp; g.b1 = -dO / cO; g.ldc1 = M_N;
      launch_g(stream, true, false, g, D_N, M_N);
    }
    for (int s = 2; s <= 5; ++s) {
      GArgs g = mkg(Cn, D_N, zc, M_N, zn, M_N, D_N, 2.0f / cO);
      g.C1 = zc; g.b1 = -2.0f * dO / cO; g.ldc1 = M_N;
      g.C2 = zp; g.b2 = -1.0f; g.ldc2 = M_N;
      launch_g(stream, true, false, g, D_N, M_N);
      float* t = zp; zp = zc; zc = zn; zn = t;
    }
    // basis = zc; QR into zn; zp becomes a free buffer
    qr256(zc, zn);
    Scur = zn; f1 = zp; f2 = zc;
  }

  // 3) T = S^T (Cn S)   (Yf into f1)
  {
    GArgs g = mkg(Cn, D_N, Scur, M_N, f1, M_N, D_N, 1.0f);
    launch_g(stream, true, false, g, D_N, M_N);
    g = mkg(Scur, M_N, f1, M_N, Tm, M_N, D_N, 1.0f);
    launch_g(stream, true, false, g, M_N, M_N);
  }

  // 4) Inner Chebyshev on T (256x256): 2 segments x 8 applies, damp [0,1.45]
  const float cI = 0.725f, dI = 0.725f;
  hipLaunchKernelGGL(inits_k, dim3((M_N * K_N + 255) / 256), dim3(256), 0, stream,
                     VA, M_N * K_N, 777u);
  float* Vcur = VA;
  float* vf1 = VB;
  float* vf2 = VC;
  for (int seg = 0; seg < 2; ++seg) {
    float* zp = Vcur;
    float* zc = vf1;
    float* zn = vf2;
    {
      GArgs g = mkg(Tm, M_N, zp, K_N, zc, K_N, M_N, 1.0f / cI);
      g.C1 = zp; g.b1 = -dI / cI; g.ldc1 = K_N;
      launch_g(stream, true, false, g, M_N, K_N);
    }
    for (int s = 2; s <= 8; ++s) {
      GArgs g = mkg(Tm, M_N, zc, K_N, zn, K_N, M_N, 2.0f / cI);
      g.C1 = zc; g.b1 = -2.0f * dI / cI; g.ldc1 = K_N;
      g.C2 = zp; g.b2 = -1.0f; g.ldc2 = K_N;
      launch_g(stream, true, false, g, M_N, K_N);
      float* t = zp; zp = zc; zc = zn; zn = t;
    }
    // CholQR-128 of zc (256x128) into zn
    {
      GArgs g = mkg(zc, K_N, zc, K_N, G128, K_N, M_N, 1.0f);
      launch_g(stream, true, false, g, K_N, K_N);
      hipLaunchKernelGGL(chol128_k, dim3(1), dim3(256), 0, stream,
                         G128, K_N, Li128, (double*)nullptr, (float*)nullptr);
      g = mkg(zc, K_N, Li128, K_N, zn, K_N, K_N, 1.0f);
      launch_g(stream, false, false, g, M_N, K_N);
    }
    Vcur = zn; vf1 = zp; vf2 = zc;
  }

  // 5) W = S*V, exact CholQR-128 on W
  {
    GArgs g = mkg(Scur, M_N, Vcur, K_N, Wa, K_N, M_N, 1.0f);
    launch_g(stream, false, false, g, D_N, K_N);
    g = mkg(Wa, K_N, Wa, K_N, G128, K_N, D_N, 1.0f);
    launch_g(stream, true, false, g, K_N, K_N);
    hipLaunchKernelGGL(chol128_k, dim3(1), dim3(256), 0, stream,
                       G128, K_N, Li128, (double*)nullptr, (float*)nullptr);
    g = mkg(Wa, K_N, Li128, K_N, Wb, K_N, K_N, 1.0f);
    launch_g(stream, false, false, g, D_N, K_N);
  }

  // 6) z = x W - 1 (m^T W)
  hipLaunchKernelGGL(mw_k, dim3(1), dim3(128), 0, stream, m, Wb, mW);
  {
    GArgs g = mkg(x, D_N, Wb, K_N, z, K_N, D_N, 1.0f);
    g.radd = mW; g.raddc = -1.0f;
    launch_g(stream, false, false, g, B_N, K_N);
  }

  // 7) sort rows by label; gather into zs (aliases Cn, now dead)
  hipLaunchKernelGGL(count_sort_k, dim3(1), dim3(256), 0, stream,
                     lab, perm, counts, offs);
  hipLaunchKernelGGL(gather_k, dim3(B_N * 32 / 256), dim3(256), 0, stream,
                     z, perm, zs);

  // 8) label and global column sums
  hipLaunchKernelGGL(labstat_part_k, dim3(11 * 8), dim3(128), 0, stream,
                     zs, offs, partL);
  hipLaunchKernelGGL(labstat_comb_k, dim3(1), dim3(128), 0, stream,
                     partL, sumMu, muT);

  // 9) per-label Sigma sums; SigT = I + (sum_l SigS)/B; Sinv + logdet
  hipLaunchKernelGGL(sigsum_k, dim3(NLAB * 4), dim3(256), 0, stream,
                     zs, offs, muT, SigS);
  hipLaunchKernelGGL(sigt_comb_k, dim3(64), dim3(256), 0, stream, SigS, SigT);
  hipLaunchKernelGGL(chol128_k, dim3(1), dim3(256), 0, stream,
                     SigT, K_N, (float*)nullptr, logdet_t, Sinv);

  // 10) per-label KL, reduce
  hipLaunchKernelGGL(perlabel_k, dim3(NLAB), dim3(256), 0, stream,
                     SigS, Sinv, muT, sumMu, counts, logdet_t, klv, present);
  hipLaunchKernelGGL(finalize_k, dim3(1), dim3(64), 0, stream, klv, present, out);
}

// Round 5
// 4714.020 us; speedup vs baseline: 21.1322x; 1.9495x over previous
//
#include <hip/hip_runtime.h>
#include <hip/hip_bf16.h>
#include <math.h>

// ============================================================================
// GMMLoss2_pca v4 (resubmit after infra failure): explicit Chebyshev filter
// matrices (outer T4 on [0,1.25], inner T6 on [0,1.27], both monotone on the
// retained band), split-K GEMMs with deterministic combine epilogue, float4
// loads. Label KL phase unchanged (v3).
// ============================================================================

#define B_N 8192
#define D_N 1024
#define K_N 128
#define M_N 256
#define NLAB 10

__device__ __forceinline__ float hashf(unsigned x) {
  x ^= x >> 16; x *= 0x7feb352du; x ^= x >> 15; x *= 0x846ca68bu; x ^= x >> 16;
  return (float)(x >> 8) * (1.0f / 16777216.0f) - 0.5f;
}

// ---------------------------------------------------------------------------
// Tiled f32 GEMM: C[i][j] = alpha * sum_k A(k,i)*B(k,j)  [+ epilogue if ks==1]
// AKM=true : A(k,i) at A[k*lda+i];  AKM=false: A(i,k) at A[i*lda+k].
// BT=false : B(k,j) at B[k*ldb+j];  BT=true : B(k,j) at B[j*ldb+k].
// gridDim.z>1 => split-K partial mode: slice z covers K/gridDim.z rows,
// writes alpha*partial to Cp[z*mn + i*pn + j]; epilogue moves to combine_k.
// M,N multiples of 64; K multiple of 32*gridDim.z. All ld multiples of 4.
// ---------------------------------------------------------------------------
struct GArgs {
  const float* A; const float* B; float* C;
  int lda, ldb, ldc, K;
  float alpha;
  const float* C1; float b1; int ldc1;
  const float* C2; float b2; int ldc2;
  const float* r1u; const float* r1v; float r1c;
  const float* radd; float raddc;
  float addI;
  float* Cp; size_t mn; int pn;   // partial-mode
};

template <bool AKM, bool BT>
__global__ __launch_bounds__(256)
void gemm_k(GArgs g) {
  __shared__ __align__(16) float AsRaw[2304]; // AKM: [32][68]; !AKM: [64][36]
  __shared__ __align__(16) float Bs[2176];    // [32][68]
  const int tid = threadIdx.x;
  const int tx = tid & 15, ty = tid >> 4;
  const int i0 = blockIdx.x * 64, j0 = blockIdx.y * 64;
  const int ks = gridDim.z;
  const int Kc = g.K / ks;
  const int kbeg = blockIdx.z * Kc, kend = kbeg + Kc;
  float acc[4][4] = {};
  for (int k0 = kbeg; k0 < kend; k0 += 32) {
    if (AKM) {
#pragma unroll
      for (int p = 0; p < 2; ++p) {
        int f4 = tid + p * 256;           // 512 float4s: 32 rows x 16
        int kk = f4 >> 4, i4 = f4 & 15;
        *(float4*)(AsRaw + kk * 68 + i4 * 4) =
            *(const float4*)(g.A + (size_t)(k0 + kk) * g.lda + i0 + i4 * 4);
      }
    } else {
#pragma unroll
      for (int p = 0; p < 2; ++p) {
        int f4 = tid + p * 256;           // 512 float4s: 64 rows x 8
        int ii = f4 >> 3, k4 = f4 & 7;
        *(float4*)(AsRaw + ii * 36 + k4 * 4) =
            *(const float4*)(g.A + (size_t)(i0 + ii) * g.lda + k0 + k4 * 4);
      }
    }
    if (BT) {
#pragma unroll
      for (int p = 0; p < 8; ++p) {
        int idx = tid + p * 256;
        int jj = idx >> 5, kk = idx & 31;
        Bs[kk * 68 + jj] = g.B[(size_t)(j0 + jj) * g.ldb + k0 + kk];
      }
    } else {
#pragma unroll
      for (int p = 0; p < 2; ++p) {
        int f4 = tid + p * 256;
        int kk = f4 >> 4, j4 = f4 & 15;
        *(float4*)(Bs + kk * 68 + j4 * 4) =
            *(const float4*)(g.B + (size_t)(k0 + kk) * g.ldb + j0 + j4 * 4);
      }
    }
    __syncthreads();
#pragma unroll 8
    for (int kk = 0; kk < 32; ++kk) {
      float ra[4], rb[4];
      if (AKM) {
        const float4 va = *(const float4*)(AsRaw + kk * 68 + ty * 4);
        ra[0] = va.x; ra[1] = va.y; ra[2] = va.z; ra[3] = va.w;
      } else {
#pragma unroll
        for (int r = 0; r < 4; ++r) ra[r] = AsRaw[(ty * 4 + r) * 36 + kk];
      }
      const float4 vb = *(const float4*)(Bs + kk * 68 + tx * 4);
      rb[0] = vb.x; rb[1] = vb.y; rb[2] = vb.z; rb[3] = vb.w;
#pragma unroll
      for (int r = 0; r < 4; ++r)
#pragma unroll
        for (int c = 0; c < 4; ++c) acc[r][c] += ra[r] * rb[c];
    }
    __syncthreads();
  }
  if (ks > 1) {
    float* dst = g.Cp + (size_t)blockIdx.z * g.mn;
#pragma unroll
    for (int r = 0; r < 4; ++r)
#pragma unroll
      for (int c = 0; c < 4; ++c) {
        int gi = i0 + ty * 4 + r, gj = j0 + tx * 4 + c;
        dst[(size_t)gi * g.pn + gj] = g.alpha * acc[r][c];
      }
  } else {
#pragma unroll
    for (int r = 0; r < 4; ++r)
#pragma unroll
      for (int c = 0; c < 4; ++c) {
        int gi = i0 + ty * 4 + r, gj = j0 + tx * 4 + c;
        float v = g.alpha * acc[r][c];
        if (g.C1) v += g.b1 * g.C1[(size_t)gi * g.ldc1 + gj];
        if (g.C2) v += g.b2 * g.C2[(size_t)gi * g.ldc2 + gj];
        if (g.r1u) v += g.r1c * g.r1u[gi] * g.r1v[gj];
        if (g.radd) v += g.raddc * g.radd[gj];
        if (g.addI != 0.0f && gi == gj) v += g.addI;
        g.C[(size_t)gi * g.ldc + gj] = v;
      }
  }
}

// Deterministic split-K combine with full epilogue.
struct CArgs {
  const float* P; float* C; size_t mn; int N, ldc, ks;
  const float* C1; float b1; int ldc1;
  const float* C2; float b2; int ldc2;
  const float* r1u; const float* r1v; float r1c;
  const float* radd; float raddc;
  float addI;
};

__global__ __launch_bounds__(256)
void combine_k(CArgs c) {
  size_t idx = (size_t)blockIdx.x * 256 + threadIdx.x;
  if (idx >= c.mn) return;
  int i = (int)(idx / c.N), j = (int)(idx % c.N);
  float s = 0.0f;
  for (int z = 0; z < c.ks; ++z) s += c.P[(size_t)z * c.mn + idx];
  if (c.C1) s += c.b1 * c.C1[(size_t)i * c.ldc1 + j];
  if (c.C2) s += c.b2 * c.C2[(size_t)i * c.ldc2 + j];
  if (c.r1u) s += c.r1c * c.r1u[i] * c.r1v[j];
  if (c.radd) s += c.raddc * c.radd[j];
  if (c.addI != 0.0f && i == j) s += c.addI;
  c.C[(size_t)i * c.ldc + j] = s;
}

// out = in*sc + dg*I   (n x n)
__global__ __launch_bounds__(256)
void scaleshift_k(const float* in, float* out, int n, float sc, float dg) {
  size_t idx = (size_t)blockIdx.x * 256 + threadIdx.x;
  if (idx >= (size_t)n * n) return;
  int i = (int)(idx / n), j = (int)(idx % n);
  out[idx] = in[idx] * sc + ((i == j) ? dg : 0.0f);
}

// out = 0.5*(in+in^T)*sc + dg*I
__global__ __launch_bounds__(256)
void symscale_k(const float* in, float* out, int n, float sc, float dg) {
  size_t idx = (size_t)blockIdx.x * 256 + threadIdx.x;
  if (idx >= (size_t)n * n) return;
  int i = (int)(idx / n), j = (int)(idx % n);
  out[idx] = 0.5f * (in[idx] + in[(size_t)j * n + i]) * sc + ((i == j) ? dg : 0.0f);
}

// ---------------------------------------------------------------------------
__global__ __launch_bounds__(256)
void colmean_part_k(const float* x, double* part) {
  int col = blockIdx.x * 256 + threadIdx.x;
  int rs = blockIdx.y;
  double acc = 0.0;
  for (int r = rs * 512; r < (rs + 1) * 512; ++r)
    acc += (double)x[(size_t)r * D_N + col];
  part[(size_t)rs * D_N + col] = acc;
}

__global__ __launch_bounds__(256)
void colmean_comb_k(const double* part, float* m) {
  int col = blockIdx.x * 256 + threadIdx.x;
  double acc = 0.0;
  for (int rs = 0; rs < 16; ++rs) acc += part[(size_t)rs * D_N + col];
  m[col] = (float)(acc / (double)B_N);
}

__global__ void inits_k(float* S, int n, unsigned seed) {
  int i = blockIdx.x * 256 + threadIdx.x;
  if (i < n) S[i] = hashf((unsigned)i * 2654435761u + seed);
}

// ---------------------------------------------------------------------------
// LDS Cholesky n=128 (input ldg) + LinvT via 2x2 blocked triangular inverse
// (+ optional logdet, Sinv). One WG, 256 threads.  (validated rounds 2-3)
// ---------------------------------------------------------------------------
__global__ __launch_bounds__(256)
void chol128_k(const float* Gin, int ldg, float* LinvT, double* logdet, float* Sinv) {
  __shared__ float A[128][129];
  __shared__ float Bm[128][129];
  __shared__ float Y[64][65];
  __shared__ float colj[128];
  const int tid = threadIdx.x;
  for (int idx = tid; idx < 128 * 128; idx += 256)
    A[idx >> 7][idx & 127] = Gin[(size_t)(idx >> 7) * ldg + (idx & 127)];
  for (int idx = tid; idx < 128 * 129; idx += 256)
    (&Bm[0][0])[idx] = 0.0f;
  __syncthreads();
  for (int j = 0; j < 128; ++j) {
    if (tid == 0) A[j][j] = sqrtf(fmaxf(A[j][j], 1e-20f));
    __syncthreads();
    float pj = A[j][j];
    for (int i = j + 1 + tid; i < 128; i += 256) {
      float v = A[i][j] / pj;
      A[i][j] = v; colj[i] = v;
    }
    __syncthreads();
    for (int i = j + 1 + tid; i < 128; i += 256) {
      float ci = colj[i];
      for (int t = j + 1; t <= i; ++t) A[i][t] -= ci * colj[t];
    }
    __syncthreads();
  }
  if (logdet && tid == 0) {
    double s = 0.0;
    for (int j = 0; j < 128; ++j) s += log((double)A[j][j]);
    *logdet = 2.0 * s;
  }
  if (tid < 128) {
    int o = (tid >> 6) * 64;
    int c = tid & 63;
    for (int i = c; i < 64; ++i) {
      float s = (i == c) ? 1.0f : 0.0f;
      for (int t = c; t < i; ++t) s -= A[o + i][o + t] * Bm[o + c][o + t];
      Bm[o + c][o + i] = s / A[o + i][o + i];
    }
  }
  __syncthreads();
  for (int idx = tid; idx < 64 * 64; idx += 256) {
    int t = idx >> 6, c = idx & 63;
    float s = 0.0f;
    for (int s2 = c; s2 < 64; ++s2) s += A[64 + t][s2] * Bm[c][s2];
    Y[t][c] = s;
  }
  __syncthreads();
  for (int idx = tid; idx < 64 * 64; idx += 256) {
    int a = idx >> 6, c = idx & 63;
    float s = 0.0f;
    for (int t = 0; t <= a; ++t) s -= Bm[64 + t][64 + a] * Y[t][c];
    Bm[c][64 + a] = s;
  }
  __syncthreads();
  if (LinvT)
    for (int idx = tid; idx < 128 * 128; idx += 256)
      LinvT[idx] = Bm[idx >> 7][idx & 127];
  if (Sinv)
    for (int idx = tid; idx < 128 * 128; idx += 256) {
      int i = idx >> 7, j = idx & 127;
      int t0 = (i > j) ? i : j;
      float s = 0.0f;
      for (int t = t0; t < 128; ++t) s += Bm[i][t] * Bm[j][t];
      Sinv[idx] = s;
    }
}

__global__ __launch_bounds__(128)
void mw_k(const float* m, const float* W, float* mW) {
  int j = threadIdx.x;
  double acc = 0.0;
  for (int c = 0; c < D_N; ++c) acc += (double)m[c] * (double)W[(size_t)c * K_N + j];
  mW[j] = (float)acc;
}

// ---------------------------------------------------------------------------
__global__ __launch_bounds__(256)
void count_sort_k(const int* lab, int* perm, int* counts, int* offs) {
  __shared__ int cnt[NLAB][256];
  __shared__ int labOff[NLAB + 1];
  const int tid = threadIdx.x;
  int lc[NLAB];
#pragma unroll
  for (int l = 0; l < NLAB; ++l) lc[l] = 0;
  for (int r = tid * 32; r < tid * 32 + 32; ++r) {
    int l = lab[r]; l = (l < 0) ? 0 : (l > 9 ? 9 : l);
    lc[l]++;
  }
#pragma unroll
  for (int l = 0; l < NLAB; ++l) cnt[l][tid] = lc[l];
  __syncthreads();
  if (tid < NLAB) {
    int run = 0;
    for (int i = 0; i < 256; ++i) { int v = cnt[tid][i]; cnt[tid][i] = run; run += v; }
    counts[tid] = run;
  }
  __syncthreads();
  if (tid == 0) {
    int run = 0;
    for (int l = 0; l < NLAB; ++l) { labOff[l] = run; run += counts[l]; }
    labOff[NLAB] = run;
    for (int l = 0; l <= NLAB; ++l) offs[l] = labOff[l];
  }
  __syncthreads();
  int lc2[NLAB];
#pragma unroll
  for (int l = 0; l < NLAB; ++l) lc2[l] = 0;
  for (int r = tid * 32; r < tid * 32 + 32; ++r) {
    int l = lab[r]; l = (l < 0) ? 0 : (l > 9 ? 9 : l);
    int pos = labOff[l] + cnt[l][tid] + lc2[l];
    lc2[l]++;
    perm[pos] = r;
  }
}

__global__ __launch_bounds__(256)
void gather_k(const float* z, const int* perm, float* zs) {
  int g = blockIdx.x * 256 + threadIdx.x;
  int row = g >> 5, q = g & 31;
  const float4* zf = (const float4*)z;
  float4* of = (float4*)zs;
  of[(size_t)row * 32 + q] = zf[(size_t)perm[row] * 32 + q];
}

__global__ __launch_bounds__(128)
void labstat_part_k(const float* zs, const int* offs, double* part) {
  int l = blockIdx.x >> 3, s = blockIdx.x & 7;
  int j = threadIdx.x;
  int r0, r1;
  if (l < NLAB) {
    int st = offs[l], en = offs[l + 1], len = en - st;
    r0 = st + (int)(((long long)len * s) >> 3);
    r1 = st + (int)(((long long)len * (s + 1)) >> 3);
  } else {
    r0 = s * 1024; r1 = r0 + 1024;
  }
  double acc = 0.0;
  for (int r = r0; r < r1; ++r) acc += (double)zs[(size_t)r * K_N + j];
  part[((size_t)l * 8 + s) * K_N + j] = acc;
}

__global__ __launch_bounds__(128)
void labstat_comb_k(const double* part, float* sum_mu, float* muT) {
  int j = threadIdx.x;
  for (int l = 0; l < NLAB; ++l) {
    double a = 0.0;
    for (int s = 0; s < 8; ++s) a += part[((size_t)l * 8 + s) * K_N + j];
    sum_mu[l * K_N + j] = (float)a;
  }
  double t = 0.0;
  for (int s = 0; s < 8; ++s) t += part[((size_t)NLAB * 8 + s) * K_N + j];
  muT[j] = (float)(t / (double)B_N);
}

__global__ __launch_bounds__(256)
void sigsum_k(const float* zs, const int* offs, const float* muT, float* SigS) {
  int l = blockIdx.x >> 2, t = blockIdx.x & 3;
  int i0 = (t >> 1) * 64, j0 = (t & 1) * 64;
  __shared__ float Zi[32][66], Zj[32][66];
  __shared__ float muL[128];
  int tid = threadIdx.x, tx = tid & 15, ty = tid >> 4;
  if (tid < 128) muL[tid] = muT[tid];
  __syncthreads();
  int start = offs[l], end = offs[l + 1];
  float acc[4][4] = {};
  for (int base = start; base < end; base += 32) {
#pragma unroll
    for (int p = 0; p < 8; ++p) {
      int idx = tid + p * 256;
      int rr = idx >> 6, cc = idx & 63;
      int r = base + rr;
      float vi = 0.0f, vj = 0.0f;
      if (r < end) {
        vi = zs[(size_t)r * K_N + i0 + cc] - muL[i0 + cc];
        vj = zs[(size_t)r * K_N + j0 + cc] - muL[j0 + cc];
      }
      Zi[rr][cc] = vi; Zj[rr][cc] = vj;
    }
    __syncthreads();
    for (int rr = 0; rr < 32; ++rr) {
      float ra[4], rb[4];
#pragma unroll
      for (int r = 0; r < 4; ++r) ra[r] = Zi[rr][ty * 4 + r];
#pragma unroll
      for (int c = 0; c < 4; ++c) rb[c] = Zj[rr][tx * 4 + c];
#pragma unroll
      for (int r = 0; r < 4; ++r)
#pragma unroll
        for (int c = 0; c < 4; ++c) acc[r][c] += ra[r] * rb[c];
    }
    __syncthreads();
  }
#pragma unroll
  for (int r = 0; r < 4; ++r)
#pragma unroll
    for (int c = 0; c < 4; ++c)
      SigS[((size_t)l * K_N + i0 + ty * 4 + r) * K_N + j0 + tx * 4 + c] = acc[r][c];
}

__global__ __launch_bounds__(256)
void sigt_comb_k(const float* SigS, float* SigT) {
  int idx = blockIdx.x * 256 + threadIdx.x;
  int i = idx >> 7, j = idx & 127;
  double s = 0.0;
  for (int l = 0; l < NLAB; ++l) s += (double)SigS[(size_t)l * 16384 + idx];
  SigT[idx] = (float)(s / (double)B_N) + ((i == j) ? 1.0f : 0.0f);
}

__global__ __launch_bounds__(256)
void perlabel_k(const float* SigS, const float* Sinv, const float* mu,
                const float* sum_mu, const int* counts, const double* logdet_t,
                double* klout, int* present) {
  int l = blockIdx.x, tid = threadIdx.x;
  __shared__ float Amat[128][129];
  __shared__ double red[256];
  __shared__ float dv[128];
  __shared__ float colj[128];
  int cnt = counts[l];
  float sc = (cnt > 0) ? (float)cnt : 1.0f;
  for (int idx = tid; idx < 128 * 128; idx += 256) {
    int i = idx >> 7, j = idx & 127;
    Amat[i][j] = SigS[((size_t)l * K_N + i) * K_N + j] / sc + ((i == j) ? 1.0f : 0.0f);
  }
  if (tid < 128) dv[tid] = mu[tid] - sum_mu[l * K_N + tid] / sc;
  __syncthreads();
  double tr = 0.0, mh = 0.0;
  for (int idx = tid; idx < 128 * 128; idx += 256) {
    int i = idx >> 7, j = idx & 127;
    double sv = (double)Sinv[idx];
    tr += sv * (double)Amat[i][j];
    mh += sv * (double)dv[i] * (double)dv[j];
  }
  red[tid] = tr; __syncthreads();
  for (int off = 128; off > 0; off >>= 1) { if (tid < off) red[tid] += red[tid + off]; __syncthreads(); }
  double trv = red[0]; __syncthreads();
  red[tid] = mh; __syncthreads();
  for (int off = 128; off > 0; off >>= 1) { if (tid < off) red[tid] += red[tid + off]; __syncthreads(); }
  double mhv = red[0]; __syncthreads();
  for (int j = 0; j < 128; ++j) {
    if (tid == 0) Amat[j][j] = sqrtf(fmaxf(Amat[j][j], 1e-20f));
    __syncthreads();
    float pj = Amat[j][j];
    for (int i = j + 1 + tid; i < 128; i += 256) {
      float v = Amat[i][j] / pj;
      Amat[i][j] = v; colj[i] = v;
    }
    __syncthreads();
    for (int i = j + 1 + tid; i < 128; i += 256) {
      float ci = colj[i];
      for (int t2 = j + 1; t2 <= i; ++t2) Amat[i][t2] -= ci * colj[t2];
    }
    __syncthreads();
  }
  if (tid == 0) {
    double ld = 0.0;
    for (int j = 0; j < 128; ++j) ld += log((double)Amat[j][j]);
    ld *= 2.0;
    klout[l] = 0.5 * (trv + mhv - 128.0 + logdet_t[0] - ld);
    present[l] = (cnt > 0) ? 1 : 0;
  }
}

__global__ void finalize_k(const double* kl, const int* present, float* out) {
  if (threadIdx.x == 0 && blockIdx.x == 0) {
    double s = 0.0; int np = 0;
    for (int l = 0; l < NLAB; ++l)
      if (present[l]) { s += kl[l]; np++; }
    out[0] = (float)((np > 0) ? s / ((double)np * (double)B_N) : 0.0);
  }
}

// ===========================================================================
// Host side
// ===========================================================================
static inline GArgs mkg(const float* A, int lda, const float* B, int ldb,
                        float* C, int ldc, int K, float alpha) {
  GArgs g{};
  g.A = A; g.B = B; g.C = C; g.lda = lda; g.ldb = ldb; g.ldc = ldc;
  g.K = K; g.alpha = alpha;
  return g;
}

static inline void run_g(hipStream_t st, bool akm, bool bt, GArgs g,
                         int M, int N, int ks, float* Ppart) {
  if (ks > 1) {
    g.Cp = Ppart; g.mn = (size_t)M * N; g.pn = N;
    dim3 grid(M / 64, N / 64, ks);
    if (akm)     hipLaunchKernelGGL((gemm_k<true, false>),  grid, dim3(256), 0, st, g);
    else if (bt) hipLaunchKernelGGL((gemm_k<false, true>),  grid, dim3(256), 0, st, g);
    else         hipLaunchKernelGGL((gemm_k<false, false>), grid, dim3(256), 0, st, g);
    CArgs c{Ppart, g.C, (size_t)M * N, N, g.ldc, ks,
            g.C1, g.b1, g.ldc1, g.C2, g.b2, g.ldc2,
            g.r1u, g.r1v, g.r1c, g.radd, g.raddc, g.addI};
    hipLaunchKernelGGL(combine_k, dim3((unsigned)(((size_t)M * N + 255) / 256)),
                       dim3(256), 0, st, c);
  } else {
    dim3 grid(M / 64, N / 64);
    if (akm)     hipLaunchKernelGGL((gemm_k<true, false>),  grid, dim3(256), 0, st, g);
    else if (bt) hipLaunchKernelGGL((gemm_k<false, true>),  grid, dim3(256), 0, st, g);
    else         hipLaunchKernelGGL((gemm_k<false, false>), grid, dim3(256), 0, st, g);
  }
}

extern "C" void kernel_launch(void* const* d_in, const int* in_sizes, int n_in,
                              void* d_out, int out_size, void* d_ws, size_t ws_size,
                              hipStream_t stream) {
  const float* x = (const float*)d_in[0];
  const int* lab = (const int*)d_in[1];
  float* out = (float*)d_out;

  size_t off = 0;
  auto alloc = [&](size_t nbytes) -> void* {
    void* r = (void*)((char*)d_ws + off);
    off += ((nbytes + 255) / 256) * 256;
    return r;
  };
  float*  m     = (float*) alloc(D_N * 4);
  float*  Cn    = (float*) alloc((size_t)D_N * D_N * 4);
  float*  At    = (float*) alloc((size_t)D_N * D_N * 4);  // Atilde; later zs
  float*  T2    = (float*) alloc((size_t)D_N * D_N * 4);  // later z
  float*  Fo    = (float*) alloc((size_t)D_N * D_N * 4);  // outer filter matrix
  float*  SA    = (float*) alloc((size_t)D_N * M_N * 4);
  float*  SB    = (float*) alloc((size_t)D_N * M_N * 4);
  float*  SC    = (float*) alloc((size_t)D_N * M_N * 4);
  float*  G256  = (float*) alloc((size_t)M_N * M_N * 4);
  float*  Tm    = (float*) alloc((size_t)M_N * M_N * 4);
  float*  Li11T = (float*) alloc((size_t)K_N * K_N * 4);
  float*  Li22T = (float*) alloc((size_t)K_N * K_N * 4);
  float*  L21b  = (float*) alloc((size_t)K_N * K_N * 4);
  float*  S22b  = (float*) alloc((size_t)K_N * K_N * 4);
  float*  Pb    = (float*) alloc((size_t)K_N * K_N * 4);
  float*  XTb   = (float*) alloc((size_t)K_N * K_N * 4);
  float*  Tt    = (float*) alloc((size_t)M_N * M_N * 4);  // Ttilde
  float*  T2i   = (float*) alloc((size_t)M_N * M_N * 4);
  float*  T4i   = (float*) alloc((size_t)M_N * M_N * 4);
  float*  F6i   = (float*) alloc((size_t)M_N * M_N * 4);
  float*  VA    = (float*) alloc((size_t)M_N * K_N * 4);
  float*  VB    = (float*) alloc((size_t)M_N * K_N * 4);
  float*  G128  = (float*) alloc((size_t)K_N * K_N * 4);
  float*  Li128 = (float*) alloc((size_t)K_N * K_N * 4);
  float*  Wa    = (float*) alloc((size_t)D_N * K_N * 4);
  float*  Wb    = (float*) alloc((size_t)D_N * K_N * 4);
  float*  mW    = (float*) alloc(K_N * 4);
  double* partM = (double*)alloc((size_t)16 * D_N * 8);
  double* partL = (double*)alloc((size_t)11 * 8 * K_N * 8);
  float*  sumMu = (float*) alloc(NLAB * K_N * 4);
  float*  muT   = (float*) alloc(K_N * 4);
  float*  SigT  = (float*) alloc((size_t)K_N * K_N * 4);
  float*  Sinv  = (float*) alloc((size_t)K_N * K_N * 4);
  float*  SigS  = (float*) alloc((size_t)NLAB * K_N * K_N * 4);
  double* logdet_t = (double*)alloc(16);
  double* klv      = (double*)alloc(NLAB * 8);
  int*    counts = (int*)alloc(16 * 4);
  int*    offs   = (int*)alloc(16 * 4);
  int*    present= (int*)alloc(16 * 4);
  int*    perm   = (int*)alloc(B_N * 4);
  float*  zs     = At;  // alias: Atilde dead after T2 built
  float*  z      = T2;  // alias: T2 dead after Fo built
  // Split-K partial buffer: carved from remaining workspace.
  size_t rem = (ws_size > off) ? (ws_size - off) : 0;
  int KS = 1;
  if (rem >= (size_t)16 * 1024 * 1024 + 4096) KS = 4;
  else if (rem >= (size_t)8 * 1024 * 1024 + 4096) KS = 2;
  float* Ppart = (float*)alloc((size_t)KS * 4 * 1024 * 1024);  // KS x 4MB max
  (void)in_sizes; (void)n_in; (void)out_size;

  // 1) column means; Cn = x^T x / B - m m^T   (split-K)
  hipLaunchKernelGGL(colmean_part_k, dim3(4, 16), dim3(256), 0, stream, x, partM);
  hipLaunchKernelGGL(colmean_comb_k, dim3(4), dim3(256), 0, stream, partM, m);
  {
    GArgs g = mkg(x, D_N, x, D_N, Cn, D_N, B_N, 1.0f / (float)B_N);
    g.r1u = m; g.r1v = m; g.r1c = -1.0f;
    run_g(stream, true, false, g, D_N, D_N, KS, Ppart);
  }

  // 2) Outer filter matrix Fo = T4(At), At=(Cn-0.625 I)/0.625  (monotone band)
  hipLaunchKernelGGL(scaleshift_k, dim3((D_N * D_N + 255) / 256), dim3(256), 0,
                     stream, Cn, At, D_N, 1.6f, -1.0f);
  {
    GArgs g = mkg(At, D_N, At, D_N, T2, D_N, D_N, 2.0f);  // T2 = 2 At^2 - I
    g.addI = -1.0f;
    run_g(stream, true, false, g, D_N, D_N, KS, Ppart);
    g = mkg(T2, D_N, T2, D_N, Fo, D_N, D_N, 2.0f);        // Fo = 2 T2^2 - I
    g.addI = -1.0f;
    run_g(stream, true, false, g, D_N, D_N, KS, Ppart);
  }

  // Blocked CholQR-256 (validated): S -> Snew
  auto qr256 = [&](float* S, float* Snew) {
    GArgs g = mkg(S, M_N, S, M_N, G256, M_N, D_N, 1.0f);
    run_g(stream, true, false, g, M_N, M_N, KS, Ppart);
    hipLaunchKernelGGL(chol128_k, dim3(1), dim3(256), 0, stream,
                       G256, M_N, Li11T, (double*)nullptr, (float*)nullptr);
    g = mkg(G256 + 128 * M_N, M_N, Li11T, K_N, L21b, K_N, K_N, 1.0f);
    run_g(stream, false, false, g, K_N, K_N, 1, nullptr);
    g = mkg(L21b, K_N, L21b, K_N, S22b, K_N, K_N, -1.0f);
    g.C1 = G256 + 128 * M_N + 128; g.b1 = 1.0f; g.ldc1 = M_N;
    run_g(stream, false, true, g, K_N, K_N, 1, nullptr);
    hipLaunchKernelGGL(chol128_k, dim3(1), dim3(256), 0, stream,
                       S22b, K_N, Li22T, (double*)nullptr, (float*)nullptr);
    g = mkg(L21b, K_N, Li11T, K_N, Pb, K_N, K_N, 1.0f);
    run_g(stream, false, true, g, K_N, K_N, 1, nullptr);
    g = mkg(Pb, K_N, Li22T, K_N, XTb, K_N, K_N, -1.0f);
    run_g(stream, true, false, g, K_N, K_N, 1, nullptr);
    g = mkg(S, M_N, Li11T, K_N, Snew, M_N, K_N, 1.0f);
    run_g(stream, false, false, g, D_N, K_N, 1, nullptr);
    g = mkg(S, M_N, XTb, K_N, Snew + 128, M_N, K_N, 1.0f);
    run_g(stream, false, false, g, D_N, K_N, 1, nullptr);
    g = mkg(S + 128, M_N, Li22T, K_N, Snew + 128, M_N, K_N, 1.0f);
    g.C1 = Snew + 128; g.b1 = 1.0f; g.ldc1 = M_N;
    run_g(stream, false, false, g, D_N, K_N, 1, nullptr);
  };

  // 3) Outer: 3 segments of {S <- Fo @ S ; CholQR-256}
  hipLaunchKernelGGL(inits_k, dim3((D_N * M_N + 255) / 256), dim3(256), 0, stream,
                     SA, D_N * M_N, 12345u);
  float* Scur = SA; float* t1 = SB; float* t2 = SC;
  for (int seg = 0; seg < 3; ++seg) {
    GArgs g = mkg(Fo, D_N, Scur, M_N, t1, M_N, D_N, 1.0f);
    run_g(stream, true, false, g, D_N, M_N, KS, Ppart);
    qr256(t1, t2);
    float* t = Scur; Scur = t2; t2 = t;  // t1 stays scratch
  }

  // 4) T = S^T (Cn S)
  {
    GArgs g = mkg(Cn, D_N, Scur, M_N, t1, M_N, D_N, 1.0f);  // Yf = Cn S
    run_g(stream, true, false, g, D_N, M_N, KS, Ppart);
    g = mkg(Scur, M_N, t1, M_N, Tm, M_N, D_N, 1.0f);
    run_g(stream, true, false, g, M_N, M_N, KS, Ppart);
  }

  // 5) Inner filter F6i = T6(Tt), Tt = (sym(Tm)-0.635 I)/0.635
  hipLaunchKernelGGL(symscale_k, dim3((M_N * M_N + 255) / 256), dim3(256), 0,
                     stream, Tm, Tt, M_N, 1.0f / 0.635f, -1.0f);
  {
    GArgs g = mkg(Tt, M_N, Tt, M_N, T2i, M_N, M_N, 2.0f);   // T2i = 2 Tt^2 - I
    g.addI = -1.0f;
    run_g(stream, true, false, g, M_N, M_N, 1, nullptr);
    g = mkg(T2i, M_N, T2i, M_N, T4i, M_N, M_N, 2.0f);       // T4i = 2 T2i^2 - I
    g.addI = -1.0f;
    run_g(stream, true, false, g, M_N, M_N, 1, nullptr);
    g = mkg(T2i, M_N, T4i, M_N, F6i, M_N, M_N, 2.0f);       // F6i = 2 T2i T4i - T2i
    g.C1 = T2i; g.b1 = -1.0f; g.ldc1 = M_N;
    run_g(stream, true, false, g, M_N, M_N, 1, nullptr);
  }

  // 6) Inner: 2 segments of {V <- F6i @ V ; CholQR-128}
  hipLaunchKernelGGL(inits_k, dim3((M_N * K_N + 255) / 256), dim3(256), 0, stream,
                     VA, M_N * K_N, 777u);
  float* Vcur = VA; float* Voth = VB;
  for (int seg = 0; seg < 2; ++seg) {
    GArgs g = mkg(F6i, M_N, Vcur, K_N, Voth, K_N, M_N, 1.0f);
    run_g(stream, true, false, g, M_N, K_N, 1, nullptr);
    g = mkg(Voth, K_N, Voth, K_N, G128, K_N, M_N, 1.0f);
    run_g(stream, true, false, g, K_N, K_N, 1, nullptr);
    hipLaunchKernelGGL(chol128_k, dim3(1), dim3(256), 0, stream,
                       G128, K_N, Li128, (double*)nullptr, (float*)nullptr);
    g = mkg(Voth, K_N, Li128, K_N, Vcur, K_N, K_N, 1.0f);
    run_g(stream, false, false, g, M_N, K_N, 1, nullptr);
  }

  // 7) W = S*V, exact CholQR-128 on W
  {
    GArgs g = mkg(Scur, M_N, Vcur, K_N, Wa, K_N, M_N, 1.0f);
    run_g(stream, false, false, g, D_N, K_N, 1, nullptr);
    g = mkg(Wa, K_N, Wa, K_N, G128, K_N, D_N, 1.0f);
    run_g(stream, true, false, g, K_N, K_N, KS, Ppart);
    hipLaunchKernelGGL(chol128_k, dim3(1), dim3(256), 0, stream,
                       G128, K_N, Li128, (double*)nullptr, (float*)nullptr);
    g = mkg(Wa, K_N, Li128, K_N, Wb, K_N, K_N, 1.0f);
    run_g(stream, false, false, g, D_N, K_N, 1, nullptr);
  }

  // 8) z = x W - 1 (m^T W)    (z aliases T2, dead since Fo was built)
  hipLaunchKernelGGL(mw_k, dim3(1), dim3(128), 0, stream, m, Wb, mW);
  {
    GArgs g = mkg(x, D_N, Wb, K_N, z, K_N, D_N, 1.0f);
    g.radd = mW; g.raddc = -1.0f;
    run_g(stream, false, false, g, B_N, K_N, KS, Ppart);
  }

  // 9) sort rows by label; gather into zs (aliases At, dead since T2)
  hipLaunchKernelGGL(count_sort_k, dim3(1), dim3(256), 0, stream,
                     lab, perm, counts, offs);
  hipLaunchKernelGGL(gather_k, dim3(B_N * 32 / 256), dim3(256), 0, stream,
                     z, perm, zs);

  // 10) label and global column sums
  hipLaunchKernelGGL(labstat_part_k, dim3(11 * 8), dim3(128), 0, stream,
                     zs, offs, partL);
  hipLaunchKernelGGL(labstat_comb_k, dim3(1), dim3(128), 0, stream,
                     partL, sumMu, muT);

  // 11) per-label Sigma sums; SigT; Sinv + logdet
  hipLaunchKernelGGL(sigsum_k, dim3(NLAB * 4), dim3(256), 0, stream,
                     zs, offs, muT, SigS);
  hipLaunchKernelGGL(sigt_comb_k, dim3(64), dim3(256), 0, stream, SigS, SigT);
  hipLaunchKernelGGL(chol128_k, dim3(1), dim3(256), 0, stream,
                     SigT, K_N, (float*)nullptr, logdet_t, Sinv);

  // 12) per-label KL, reduce
  hipLaunchKernelGGL(perlabel_k, dim3(NLAB), dim3(256), 0, stream,
                     SigS, Sinv, muT, sumMu, counts, logdet_t, klv, present);
  hipLaunchKernelGGL(finalize_k, dim3(1), dim3(64), 0, stream, klv, present, out);
}

// Round 6
// 3576.485 us; speedup vs baseline: 27.8535x; 1.3181x over previous
//
#include <hip/hip_runtime.h>
#include <hip/hip_bf16.h>
#include <math.h>

// ============================================================================
// GMMLoss2_pca v5: outer 2xT6 / inner 1xT12 Chebyshev filters (fewer CholQRs),
// one-barrier LDL^T Cholesky (no serial pivot phase, 1 barrier/column),
// split-K GEMMs with fused combine epilogue. Label KL phase as v3/v4.
// ============================================================================

#define B_N 8192
#define D_N 1024
#define K_N 128
#define M_N 256
#define NLAB 10

__device__ __forceinline__ float hashf(unsigned x) {
  x ^= x >> 16; x *= 0x7feb352du; x ^= x >> 15; x *= 0x846ca68bu; x ^= x >> 16;
  return (float)(x >> 8) * (1.0f / 16777216.0f) - 0.5f;
}

// ---------------------------------------------------------------------------
// Tiled f32 GEMM: C[i][j] = alpha * sum_k A(k,i)*B(k,j)  [+ epilogue if ks==1]
// AKM=true : A(k,i) at A[k*lda+i];  AKM=false: A(i,k) at A[i*lda+k].
// BT=false : B(k,j) at B[k*ldb+j];  BT=true : B(k,j) at B[j*ldb+k].
// gridDim.z>1 => split-K partial mode; epilogue moves to combine_k.
// M,N multiples of 64; K multiple of 32*gridDim.z. All ld multiples of 4.
// ---------------------------------------------------------------------------
struct GArgs {
  const float* A; const float* B; float* C;
  int lda, ldb, ldc, K;
  float alpha;
  const float* C1; float b1; int ldc1;
  const float* C2; float b2; int ldc2;
  const float* r1u; const float* r1v; float r1c;
  const float* radd; float raddc;
  float addI;
  float* Cp; size_t mn; int pn;      // partial-mode
  float* out2; float sc2, dg2;       // second output (combine only)
};

template <bool AKM, bool BT>
__global__ __launch_bounds__(256)
void gemm_k(GArgs g) {
  __shared__ __align__(16) float AsRaw[2304]; // AKM: [32][68]; !AKM: [64][36]
  __shared__ __align__(16) float Bs[2176];    // [32][68]
  const int tid = threadIdx.x;
  const int tx = tid & 15, ty = tid >> 4;
  const int i0 = blockIdx.x * 64, j0 = blockIdx.y * 64;
  const int ks = gridDim.z;
  const int Kc = g.K / ks;
  const int kbeg = blockIdx.z * Kc, kend = kbeg + Kc;
  float acc[4][4] = {};
  for (int k0 = kbeg; k0 < kend; k0 += 32) {
    if (AKM) {
#pragma unroll
      for (int p = 0; p < 2; ++p) {
        int f4 = tid + p * 256;
        int kk = f4 >> 4, i4 = f4 & 15;
        *(float4*)(AsRaw + kk * 68 + i4 * 4) =
            *(const float4*)(g.A + (size_t)(k0 + kk) * g.lda + i0 + i4 * 4);
      }
    } else {
#pragma unroll
      for (int p = 0; p < 2; ++p) {
        int f4 = tid + p * 256;
        int ii = f4 >> 3, k4 = f4 & 7;
        *(float4*)(AsRaw + ii * 36 + k4 * 4) =
            *(const float4*)(g.A + (size_t)(i0 + ii) * g.lda + k0 + k4 * 4);
      }
    }
    if (BT) {
#pragma unroll
      for (int p = 0; p < 8; ++p) {
        int idx = tid + p * 256;
        int jj = idx >> 5, kk = idx & 31;
        Bs[kk * 68 + jj] = g.B[(size_t)(j0 + jj) * g.ldb + k0 + kk];
      }
    } else {
#pragma unroll
      for (int p = 0; p < 2; ++p) {
        int f4 = tid + p * 256;
        int kk = f4 >> 4, j4 = f4 & 15;
        *(float4*)(Bs + kk * 68 + j4 * 4) =
            *(const float4*)(g.B + (size_t)(k0 + kk) * g.ldb + j0 + j4 * 4);
      }
    }
    __syncthreads();
#pragma unroll 8
    for (int kk = 0; kk < 32; ++kk) {
      float ra[4], rb[4];
      if (AKM) {
        const float4 va = *(const float4*)(AsRaw + kk * 68 + ty * 4);
        ra[0] = va.x; ra[1] = va.y; ra[2] = va.z; ra[3] = va.w;
      } else {
#pragma unroll
        for (int r = 0; r < 4; ++r) ra[r] = AsRaw[(ty * 4 + r) * 36 + kk];
      }
      const float4 vb = *(const float4*)(Bs + kk * 68 + tx * 4);
      rb[0] = vb.x; rb[1] = vb.y; rb[2] = vb.z; rb[3] = vb.w;
#pragma unroll
      for (int r = 0; r < 4; ++r)
#pragma unroll
        for (int c = 0; c < 4; ++c) acc[r][c] += ra[r] * rb[c];
    }
    __syncthreads();
  }
  if (ks > 1) {
    float* dst = g.Cp + (size_t)blockIdx.z * g.mn;
#pragma unroll
    for (int r = 0; r < 4; ++r)
#pragma unroll
      for (int c = 0; c < 4; ++c) {
        int gi = i0 + ty * 4 + r, gj = j0 + tx * 4 + c;
        dst[(size_t)gi * g.pn + gj] = g.alpha * acc[r][c];
      }
  } else {
#pragma unroll
    for (int r = 0; r < 4; ++r)
#pragma unroll
      for (int c = 0; c < 4; ++c) {
        int gi = i0 + ty * 4 + r, gj = j0 + tx * 4 + c;
        float v = g.alpha * acc[r][c];
        if (g.C1) v += g.b1 * g.C1[(size_t)gi * g.ldc1 + gj];
        if (g.C2) v += g.b2 * g.C2[(size_t)gi * g.ldc2 + gj];
        if (g.r1u) v += g.r1c * g.r1u[gi] * g.r1v[gj];
        if (g.radd) v += g.raddc * g.radd[gj];
        if (g.addI != 0.0f && gi == gj) v += g.addI;
        g.C[(size_t)gi * g.ldc + gj] = v;
      }
  }
}

// Deterministic split-K combine with full epilogue (+ optional 2nd output).
struct CArgs {
  const float* P; float* C; size_t mn; int N, ldc, ks;
  const float* C1; float b1; int ldc1;
  const float* C2; float b2; int ldc2;
  const float* r1u; const float* r1v; float r1c;
  const float* radd; float raddc;
  float addI;
  float* out2; float sc2, dg2;
};

__global__ __launch_bounds__(256)
void combine_k(CArgs c) {
  size_t idx = (size_t)blockIdx.x * 256 + threadIdx.x;
  if (idx >= c.mn) return;
  int i = (int)(idx / c.N), j = (int)(idx % c.N);
  float s = 0.0f;
  for (int z = 0; z < c.ks; ++z) s += c.P[(size_t)z * c.mn + idx];
  if (c.C1) s += c.b1 * c.C1[(size_t)i * c.ldc1 + j];
  if (c.C2) s += c.b2 * c.C2[(size_t)i * c.ldc2 + j];
  if (c.r1u) s += c.r1c * c.r1u[i] * c.r1v[j];
  if (c.radd) s += c.raddc * c.radd[j];
  if (c.addI != 0.0f && i == j) s += c.addI;
  c.C[(size_t)i * c.ldc + j] = s;
  if (c.out2) c.out2[(size_t)i * c.N + j] = s * c.sc2 + ((i == j) ? c.dg2 : 0.0f);
}

// out = in*sc + dg*I   (n x n)  (fallback when KS==1)
__global__ __launch_bounds__(256)
void scaleshift_k(const float* in, float* out, int n, float sc, float dg) {
  size_t idx = (size_t)blockIdx.x * 256 + threadIdx.x;
  if (idx >= (size_t)n * n) return;
  int i = (int)(idx / n), j = (int)(idx % n);
  out[idx] = in[idx] * sc + ((i == j) ? dg : 0.0f);
}

// out = 0.5*(in+in^T)*sc + dg*I
__global__ __launch_bounds__(256)
void symscale_k(const float* in, float* out, int n, float sc, float dg) {
  size_t idx = (size_t)blockIdx.x * 256 + threadIdx.x;
  if (idx >= (size_t)n * n) return;
  int i = (int)(idx / n), j = (int)(idx % n);
  out[idx] = 0.5f * (in[idx] + in[(size_t)j * n + i]) * sc + ((i == j) ? dg : 0.0f);
}

// ---------------------------------------------------------------------------
__global__ __launch_bounds__(256)
void colmean_part_k(const float* x, double* part) {
  int col = blockIdx.x * 256 + threadIdx.x;
  int rs = blockIdx.y;
  double acc = 0.0;
  for (int r = rs * 512; r < (rs + 1) * 512; ++r)
    acc += (double)x[(size_t)r * D_N + col];
  part[(size_t)rs * D_N + col] = acc;
}

__global__ __launch_bounds__(256)
void colmean_comb_k(const double* part, float* m) {
  int col = blockIdx.x * 256 + threadIdx.x;
  double acc = 0.0;
  for (int rs = 0; rs < 16; ++rs) acc += part[(size_t)rs * D_N + col];
  m[col] = (float)(acc / (double)B_N);
}

__global__ void inits_k(float* S, int n, unsigned seed) {
  int i = blockIdx.x * 256 + threadIdx.x;
  if (i < n) S[i] = hashf((unsigned)i * 2654435761u + seed);
}

// ---------------------------------------------------------------------------
// LDS Cholesky n=128 via one-barrier right-looking LDL^T, then L recovery,
// then LinvT via 2x2 blocked triangular inverse (+ optional logdet, Sinv).
// One WG, 256 threads. Update mapping: thread (tx,ty) owns rows i=j+1+ty+16a,
// cols t=j+1+tx+16b (t<=i) -> unique writer per element, no serial phase.
// ---------------------------------------------------------------------------
__global__ __launch_bounds__(256)
void chol128_k(const float* Gin, int ldg, float* LinvT, double* logdet, float* Sinv) {
  __shared__ float A[128][129];
  __shared__ float Bm[128][129];
  __shared__ float Y[64][65];
  __shared__ float rsv[128];
  const int tid = threadIdx.x;
  const int tx = tid & 15, ty = tid >> 4;
  for (int idx = tid; idx < 128 * 128; idx += 256)
    A[idx >> 7][idx & 127] = Gin[(size_t)(idx >> 7) * ldg + (idx & 127)];
  for (int idx = tid; idx < 128 * 129; idx += 256)
    (&Bm[0][0])[idx] = 0.0f;
  __syncthreads();
  // LDL^T factor: one barrier per column, no serialized pivot phase.
  for (int j = 0; j < 127; ++j) {
    float dj = fmaxf(A[j][j], 1e-30f);
    float rj = 1.0f / dj;
    for (int i = j + 1 + ty; i < 128; i += 16) {
      float uij = A[i][j] * rj;
      for (int t = j + 1 + tx; t <= i; t += 16)
        A[i][t] -= uij * A[t][j];
    }
    __syncthreads();
  }
  if (logdet && tid == 0) {
    double s = 0.0;
    for (int j = 0; j < 128; ++j) s += log((double)fmaxf(A[j][j], 1e-30f));
    *logdet = s;   // det(G) = prod D_j
  }
  // Recover chol L: L[i][j] = u[i][j] / sqrt(D_j)  (works for diagonal too)
  if (tid < 128) rsv[tid] = 1.0f / sqrtf(fmaxf(A[tid][tid], 1e-30f));
  __syncthreads();
  for (int idx = tid; idx < 128 * 128; idx += 256) {
    int i = idx >> 7, j = idx & 127;
    if (j <= i) A[i][j] *= rsv[j];
  }
  __syncthreads();
  // Blocked inverse (validated): L=[[L00,0],[L10,L11]]
  if (tid < 128) {
    int o = (tid >> 6) * 64;
    int c = tid & 63;
    for (int i = c; i < 64; ++i) {
      float s = (i == c) ? 1.0f : 0.0f;
      for (int t = c; t < i; ++t) s -= A[o + i][o + t] * Bm[o + c][o + t];
      Bm[o + c][o + i] = s / A[o + i][o + i];
    }
  }
  __syncthreads();
  for (int idx = tid; idx < 64 * 64; idx += 256) {
    int t = idx >> 6, c = idx & 63;
    float s = 0.0f;
    for (int s2 = c; s2 < 64; ++s2) s += A[64 + t][s2] * Bm[c][s2];
    Y[t][c] = s;
  }
  __syncthreads();
  for (int idx = tid; idx < 64 * 64; idx += 256) {
    int a = idx >> 6, c = idx & 63;
    float s = 0.0f;
    for (int t = 0; t <= a; ++t) s -= Bm[64 + t][64 + a] * Y[t][c];
    Bm[c][64 + a] = s;
  }
  __syncthreads();
  if (LinvT)
    for (int idx = tid; idx < 128 * 128; idx += 256)
      LinvT[idx] = Bm[idx >> 7][idx & 127];
  if (Sinv)
    for (int idx = tid; idx < 128 * 128; idx += 256) {
      int i = idx >> 7, j = idx & 127;
      int t0 = (i > j) ? i : j;
      float s = 0.0f;
      for (int t = t0; t < 128; ++t) s += Bm[i][t] * Bm[j][t];
      Sinv[idx] = s;
    }
}

__global__ __launch_bounds__(128)
void mw_k(const float* m, const float* W, float* mW) {
  int j = threadIdx.x;
  double acc = 0.0;
  for (int c = 0; c < D_N; ++c) acc += (double)m[c] * (double)W[(size_t)c * K_N + j];
  mW[j] = (float)acc;
}

// ---------------------------------------------------------------------------
__global__ __launch_bounds__(256)
void count_sort_k(const int* lab, int* perm, int* counts, int* offs) {
  __shared__ int cnt[NLAB][256];
  __shared__ int labOff[NLAB + 1];
  const int tid = threadIdx.x;
  int lc[NLAB];
#pragma unroll
  for (int l = 0; l < NLAB; ++l) lc[l] = 0;
  for (int r = tid * 32; r < tid * 32 + 32; ++r) {
    int l = lab[r]; l = (l < 0) ? 0 : (l > 9 ? 9 : l);
    lc[l]++;
  }
#pragma unroll
  for (int l = 0; l < NLAB; ++l) cnt[l][tid] = lc[l];
  __syncthreads();
  if (tid < NLAB) {
    int run = 0;
    for (int i = 0; i < 256; ++i) { int v = cnt[tid][i]; cnt[tid][i] = run; run += v; }
    counts[tid] = run;
  }
  __syncthreads();
  if (tid == 0) {
    int run = 0;
    for (int l = 0; l < NLAB; ++l) { labOff[l] = run; run += counts[l]; }
    labOff[NLAB] = run;
    for (int l = 0; l <= NLAB; ++l) offs[l] = labOff[l];
  }
  __syncthreads();
  int lc2[NLAB];
#pragma unroll
  for (int l = 0; l < NLAB; ++l) lc2[l] = 0;
  for (int r = tid * 32; r < tid * 32 + 32; ++r) {
    int l = lab[r]; l = (l < 0) ? 0 : (l > 9 ? 9 : l);
    int pos = labOff[l] + cnt[l][tid] + lc2[l];
    lc2[l]++;
    perm[pos] = r;
  }
}

__global__ __launch_bounds__(256)
void gather_k(const float* z, const int* perm, float* zs) {
  int g = blockIdx.x * 256 + threadIdx.x;
  int row = g >> 5, q = g & 31;
  const float4* zf = (const float4*)z;
  float4* of = (float4*)zs;
  of[(size_t)row * 32 + q] = zf[(size_t)perm[row] * 32 + q];
}

__global__ __launch_bounds__(128)
void labstat_part_k(const float* zs, const int* offs, double* part) {
  int l = blockIdx.x >> 3, s = blockIdx.x & 7;
  int j = threadIdx.x;
  int r0, r1;
  if (l < NLAB) {
    int st = offs[l], en = offs[l + 1], len = en - st;
    r0 = st + (int)(((long long)len * s) >> 3);
    r1 = st + (int)(((long long)len * (s + 1)) >> 3);
  } else {
    r0 = s * 1024; r1 = r0 + 1024;
  }
  double acc = 0.0;
  for (int r = r0; r < r1; ++r) acc += (double)zs[(size_t)r * K_N + j];
  part[((size_t)l * 8 + s) * K_N + j] = acc;
}

__global__ __launch_bounds__(128)
void labstat_comb_k(const double* part, float* sum_mu, float* muT) {
  int j = threadIdx.x;
  for (int l = 0; l < NLAB; ++l) {
    double a = 0.0;
    for (int s = 0; s < 8; ++s) a += part[((size_t)l * 8 + s) * K_N + j];
    sum_mu[l * K_N + j] = (float)a;
  }
  double t = 0.0;
  for (int s = 0; s < 8; ++s) t += part[((size_t)NLAB * 8 + s) * K_N + j];
  muT[j] = (float)(t / (double)B_N);
}

__global__ __launch_bounds__(256)
void sigsum_k(const float* zs, const int* offs, const float* muT, float* SigS) {
  int l = blockIdx.x >> 2, t = blockIdx.x & 3;
  int i0 = (t >> 1) * 64, j0 = (t & 1) * 64;
  __shared__ float Zi[32][66], Zj[32][66];
  __shared__ float muL[128];
  int tid = threadIdx.x, tx = tid & 15, ty = tid >> 4;
  if (tid < 128) muL[tid] = muT[tid];
  __syncthreads();
  int start = offs[l], end = offs[l + 1];
  float acc[4][4] = {};
  for (int base = start; base < end; base += 32) {
#pragma unroll
    for (int p = 0; p < 8; ++p) {
      int idx = tid + p * 256;
      int rr = idx >> 6, cc = idx & 63;
      int r = base + rr;
      float vi = 0.0f, vj = 0.0f;
      if (r < end) {
        vi = zs[(size_t)r * K_N + i0 + cc] - muL[i0 + cc];
        vj = zs[(size_t)r * K_N + j0 + cc] - muL[j0 + cc];
      }
      Zi[rr][cc] = vi; Zj[rr][cc] = vj;
    }
    __syncthreads();
    for (int rr = 0; rr < 32; ++rr) {
      float ra[4], rb[4];
#pragma unroll
      for (int r = 0; r < 4; ++r) ra[r] = Zi[rr][ty * 4 + r];
#pragma unroll
      for (int c = 0; c < 4; ++c) rb[c] = Zj[rr][tx * 4 + c];
#pragma unroll
      for (int r = 0; r < 4; ++r)
#pragma unroll
        for (int c = 0; c < 4; ++c) acc[r][c] += ra[r] * rb[c];
    }
    __syncthreads();
  }
#pragma unroll
  for (int r = 0; r < 4; ++r)
#pragma unroll
    for (int c = 0; c < 4; ++c)
      SigS[((size_t)l * K_N + i0 + ty * 4 + r) * K_N + j0 + tx * 4 + c] = acc[r][c];
}

__global__ __launch_bounds__(256)
void sigt_comb_k(const float* SigS, float* SigT) {
  int idx = blockIdx.x * 256 + threadIdx.x;
  int i = idx >> 7, j = idx & 127;
  double s = 0.0;
  for (int l = 0; l < NLAB; ++l) s += (double)SigS[(size_t)l * 16384 + idx];
  SigT[idx] = (float)(s / (double)B_N) + ((i == j) ? 1.0f : 0.0f);
}

__global__ __launch_bounds__(256)
void perlabel_k(const float* SigS, const float* Sinv, const float* mu,
                const float* sum_mu, const int* counts, const double* logdet_t,
                double* klout, int* present) {
  int l = blockIdx.x, tid = threadIdx.x;
  __shared__ float Amat[128][129];
  __shared__ double red[256];
  __shared__ float dv[128];
  const int tx = tid & 15, ty = tid >> 4;
  int cnt = counts[l];
  float sc = (cnt > 0) ? (float)cnt : 1.0f;
  for (int idx = tid; idx < 128 * 128; idx += 256) {
    int i = idx >> 7, j = idx & 127;
    Amat[i][j] = SigS[((size_t)l * K_N + i) * K_N + j] / sc + ((i == j) ? 1.0f : 0.0f);
  }
  if (tid < 128) dv[tid] = mu[tid] - sum_mu[l * K_N + tid] / sc;
  __syncthreads();
  double tr = 0.0, mh = 0.0;
  for (int idx = tid; idx < 128 * 128; idx += 256) {
    int i = idx >> 7, j = idx & 127;
    double sv = (double)Sinv[idx];
    tr += sv * (double)Amat[i][j];
    mh += sv * (double)dv[i] * (double)dv[j];
  }
  red[tid] = tr; __syncthreads();
  for (int off = 128; off > 0; off >>= 1) { if (tid < off) red[tid] += red[tid + off]; __syncthreads(); }
  double trv = red[0]; __syncthreads();
  red[tid] = mh; __syncthreads();
  for (int off = 128; off > 0; off >>= 1) { if (tid < off) red[tid] += red[tid + off]; __syncthreads(); }
  double mhv = red[0]; __syncthreads();
  // One-barrier LDL^T (logdet only): det = prod D_j
  for (int j = 0; j < 127; ++j) {
    float dj = fmaxf(Amat[j][j], 1e-30f);
    float rj = 1.0f / dj;
    for (int i = j + 1 + ty; i < 128; i += 16) {
      float uij = Amat[i][j] * rj;
      for (int t = j + 1 + tx; t <= i; t += 16)
        Amat[i][t] -= uij * Amat[t][j];
    }
    __syncthreads();
  }
  if (tid == 0) {
    double ld = 0.0;
    for (int j = 0; j < 128; ++j) ld += log((double)fmaxf(Amat[j][j], 1e-30f));
    klout[l] = 0.5 * (trv + mhv - 128.0 + logdet_t[0] - ld);
    present[l] = (cnt > 0) ? 1 : 0;
  }
}

__global__ void finalize_k(const double* kl, const int* present, float* out) {
  if (threadIdx.x == 0 && blockIdx.x == 0) {
    double s = 0.0; int np = 0;
    for (int l = 0; l < NLAB; ++l)
      if (present[l]) { s += kl[l]; np++; }
    out[0] = (float)((np > 0) ? s / ((double)np * (double)B_N) : 0.0);
  }
}

// ===========================================================================
// Host side
// ===========================================================================
static inline GArgs mkg(const float* A, int lda, const float* B, int ldb,
                        float* C, int ldc, int K, float alpha) {
  GArgs g{};
  g.A = A; g.B = B; g.C = C; g.lda = lda; g.ldb = ldb; g.ldc = ldc;
  g.K = K; g.alpha = alpha;
  return g;
}

static inline void run_g(hipStream_t st, bool akm, bool bt, GArgs g,
                         int M, int N, int ks, float* Ppart) {
  if (ks > 1) {
    g.Cp = Ppart; g.mn = (size_t)M * N; g.pn = N;
    dim3 grid(M / 64, N / 64, ks);
    if (akm)     hipLaunchKernelGGL((gemm_k<true, false>),  grid, dim3(256), 0, st, g);
    else if (bt) hipLaunchKernelGGL((gemm_k<false, true>),  grid, dim3(256), 0, st, g);
    else         hipLaunchKernelGGL((gemm_k<false, false>), grid, dim3(256), 0, st, g);
    CArgs c{Ppart, g.C, (size_t)M * N, N, g.ldc, ks,
            g.C1, g.b1, g.ldc1, g.C2, g.b2, g.ldc2,
            g.r1u, g.r1v, g.r1c, g.radd, g.raddc, g.addI,
            g.out2, g.sc2, g.dg2};
    hipLaunchKernelGGL(combine_k, dim3((unsigned)(((size_t)M * N + 255) / 256)),
                       dim3(256), 0, st, c);
  } else {
    dim3 grid(M / 64, N / 64);
    if (akm)     hipLaunchKernelGGL((gemm_k<true, false>),  grid, dim3(256), 0, st, g);
    else if (bt) hipLaunchKernelGGL((gemm_k<false, true>),  grid, dim3(256), 0, st, g);
    else         hipLaunchKernelGGL((gemm_k<false, false>), grid, dim3(256), 0, st, g);
  }
}

extern "C" void kernel_launch(void* const* d_in, const int* in_sizes, int n_in,
                              void* d_out, int out_size, void* d_ws, size_t ws_size,
                              hipStream_t stream) {
  const float* x = (const float*)d_in[0];
  const int* lab = (const int*)d_in[1];
  float* out = (float*)d_out;

  size_t off = 0;
  auto alloc = [&](size_t nbytes) -> void* {
    void* r = (void*)((char*)d_ws + off);
    off += ((nbytes + 255) / 256) * 256;
    return r;
  };
  float*  m     = (float*) alloc(D_N * 4);
  float*  Cn    = (float*) alloc((size_t)D_N * D_N * 4);
  float*  At    = (float*) alloc((size_t)D_N * D_N * 4);  // Atilde -> T4 -> zs
  float*  T2    = (float*) alloc((size_t)D_N * D_N * 4);  // T2 -> z
  float*  Fo    = (float*) alloc((size_t)D_N * D_N * 4);  // outer filter T6
  float*  SA    = (float*) alloc((size_t)D_N * M_N * 4);
  float*  SB    = (float*) alloc((size_t)D_N * M_N * 4);
  float*  SC    = (float*) alloc((size_t)D_N * M_N * 4);
  float*  G256  = (float*) alloc((size_t)M_N * M_N * 4);  // -> F12i
  float*  Tm    = (float*) alloc((size_t)M_N * M_N * 4);
  float*  Li11T = (float*) alloc((size_t)K_N * K_N * 4);
  float*  Li22T = (float*) alloc((size_t)K_N * K_N * 4);
  float*  L21b  = (float*) alloc((size_t)K_N * K_N * 4);
  float*  S22b  = (float*) alloc((size_t)K_N * K_N * 4);
  float*  Pb    = (float*) alloc((size_t)K_N * K_N * 4);
  float*  XTb   = (float*) alloc((size_t)K_N * K_N * 4);
  float*  Tt    = (float*) alloc((size_t)M_N * M_N * 4);
  float*  T2i   = (float*) alloc((size_t)M_N * M_N * 4);
  float*  T4i   = (float*) alloc((size_t)M_N * M_N * 4);
  float*  F6i   = (float*) alloc((size_t)M_N * M_N * 4);
  float*  VA    = (float*) alloc((size_t)M_N * K_N * 4);
  float*  VB    = (float*) alloc((size_t)M_N * K_N * 4);
  float*  G128  = (float*) alloc((size_t)K_N * K_N * 4);
  float*  Li128 = (float*) alloc((size_t)K_N * K_N * 4);
  float*  Wa    = (float*) alloc((size_t)D_N * K_N * 4);
  float*  Wb    = (float*) alloc((size_t)D_N * K_N * 4);
  float*  mW    = (float*) alloc(K_N * 4);
  double* partM = (double*)alloc((size_t)16 * D_N * 8);
  double* partL = (double*)alloc((size_t)11 * 8 * K_N * 8);
  float*  sumMu = (float*) alloc(NLAB * K_N * 4);
  float*  muT   = (float*) alloc(K_N * 4);
  float*  SigT  = (float*) alloc((size_t)K_N * K_N * 4);
  float*  Sinv  = (float*) alloc((size_t)K_N * K_N * 4);
  float*  SigS  = (float*) alloc((size_t)NLAB * K_N * K_N * 4);
  double* logdet_t = (double*)alloc(16);
  double* klv      = (double*)alloc(NLAB * 8);
  int*    counts = (int*)alloc(16 * 4);
  int*    offs   = (int*)alloc(16 * 4);
  int*    present= (int*)alloc(16 * 4);
  int*    perm   = (int*)alloc(B_N * 4);
  float*  T4   = At;    // alias: At dead once T2 exists
  float*  F12i = G256;  // alias: G256 dead after outer segs
  float*  zs   = At;    // alias: T4 dead after Fo; zs written step 9
  float*  z    = T2;    // alias: T2 dead after Fo
  size_t rem = (ws_size > off) ? (ws_size - off) : 0;
  int KS = 1;
  if (rem >= (size_t)16 * 1024 * 1024 + 4096) KS = 4;
  else if (rem >= (size_t)8 * 1024 * 1024 + 4096) KS = 2;
  float* Ppart = (float*)alloc((size_t)KS * 4 * 1024 * 1024);
  const int gks = (KS == 4) ? 8 : KS;   // split factor for 256/128-sq Grams
  (void)in_sizes; (void)n_in; (void)out_size;

  // 1) column means; Cn = x^T x / B - m m^T ; At = 1.6*Cn - I (fused)
  hipLaunchKernelGGL(colmean_part_k, dim3(4, 16), dim3(256), 0, stream, x, partM);
  hipLaunchKernelGGL(colmean_comb_k, dim3(4), dim3(256), 0, stream, partM, m);
  {
    GArgs g = mkg(x, D_N, x, D_N, Cn, D_N, B_N, 1.0f / (float)B_N);
    g.r1u = m; g.r1v = m; g.r1c = -1.0f;
    if (KS > 1) { g.out2 = At; g.sc2 = 1.6f; g.dg2 = -1.0f; }
    run_g(stream, true, false, g, D_N, D_N, KS, Ppart);
    if (KS == 1)
      hipLaunchKernelGGL(scaleshift_k, dim3((D_N * D_N + 255) / 256), dim3(256),
                         0, stream, Cn, At, D_N, 1.6f, -1.0f);
  }

  // 2) Outer filter Fo = T6(At) = 2*T2*T4 - T2, band [0,1.25] (c=d=0.625)
  {
    GArgs g = mkg(At, D_N, At, D_N, T2, D_N, D_N, 2.0f);  // T2 = 2 At^2 - I
    g.addI = -1.0f;
    run_g(stream, true, false, g, D_N, D_N, KS, Ppart);
    g = mkg(T2, D_N, T2, D_N, T4, D_N, D_N, 2.0f);        // T4 = 2 T2^2 - I
    g.addI = -1.0f;
    run_g(stream, true, false, g, D_N, D_N, KS, Ppart);
    g = mkg(T2, D_N, T4, D_N, Fo, D_N, D_N, 2.0f);        // T6 = 2 T2 T4 - T2
    g.C1 = T2; g.b1 = -1.0f; g.ldc1 = D_N;
    run_g(stream, true, false, g, D_N, D_N, KS, Ppart);
  }

  // Blocked CholQR-256 (validated): S -> Snew
  auto qr256 = [&](float* S, float* Snew) {
    GArgs g = mkg(S, M_N, S, M_N, G256, M_N, D_N, 1.0f);
    run_g(stream, true, false, g, M_N, M_N, gks, Ppart);
    hipLaunchKernelGGL(chol128_k, dim3(1), dim3(256), 0, stream,
                       G256, M_N, Li11T, (double*)nullptr, (float*)nullptr);
    g = mkg(G256 + 128 * M_N, M_N, Li11T, K_N, L21b, K_N, K_N, 1.0f);
    run_g(stream, false, false, g, K_N, K_N, 1, nullptr);
    g = mkg(L21b, K_N, L21b, K_N, S22b, K_N, K_N, -1.0f);
    g.C1 = G256 + 128 * M_N + 128; g.b1 = 1.0f; g.ldc1 = M_N;
    run_g(stream, false, true, g, K_N, K_N, 1, nullptr);
    hipLaunchKernelGGL(chol128_k, dim3(1), dim3(256), 0, stream,
                       S22b, K_N, Li22T, (double*)nullptr, (float*)nullptr);
    g = mkg(L21b, K_N, Li11T, K_N, Pb, K_N, K_N, 1.0f);
    run_g(stream, false, true, g, K_N, K_N, 1, nullptr);
    g = mkg(Pb, K_N, Li22T, K_N, XTb, K_N, K_N, -1.0f);
    run_g(stream, true, false, g, K_N, K_N, 1, nullptr);
    g = mkg(S, M_N, Li11T, K_N, Snew, M_N, K_N, 1.0f);
    run_g(stream, false, false, g, D_N, K_N, 1, nullptr);
    g = mkg(S, M_N, XTb, K_N, Snew + 128, M_N, K_N, 1.0f);
    run_g(stream, false, false, g, D_N, K_N, 1, nullptr);
    g = mkg(S + 128, M_N, Li22T, K_N, Snew + 128, M_N, K_N, 1.0f);
    g.C1 = Snew + 128; g.b1 = 1.0f; g.ldc1 = M_N;
    run_g(stream, false, false, g, D_N, K_N, 1, nullptr);
  };

  // 3) Outer: 2 segments of {S <- Fo @ S ; CholQR-256}
  hipLaunchKernelGGL(inits_k, dim3((D_N * M_N + 255) / 256), dim3(256), 0, stream,
                     SA, D_N * M_N, 12345u);
  float* Scur = SA; float* t1 = SB; float* t2 = SC;
  for (int seg = 0; seg < 2; ++seg) {
    GArgs g = mkg(Fo, D_N, Scur, M_N, t1, M_N, D_N, 1.0f);
    run_g(stream, true, false, g, D_N, M_N, KS, Ppart);
    qr256(t1, t2);
    float* t = Scur; Scur = t2; t2 = t;
  }

  // 4) T = S^T (Cn S)
  {
    GArgs g = mkg(Cn, D_N, Scur, M_N, t1, M_N, D_N, 1.0f);
    run_g(stream, true, false, g, D_N, M_N, KS, Ppart);
    g = mkg(Scur, M_N, t1, M_N, Tm, M_N, D_N, 1.0f);
    run_g(stream, true, false, g, M_N, M_N, gks, Ppart);
  }

  // 5) Inner filter F12 = T12(Tt) = 2*T6(Tt)^2 - I, band [0,1.27] (c=d=0.635)
  hipLaunchKernelGGL(symscale_k, dim3((M_N * M_N + 255) / 256), dim3(256), 0,
                     stream, Tm, Tt, M_N, 1.0f / 0.635f, -1.0f);
  {
    GArgs g = mkg(Tt, M_N, Tt, M_N, T2i, M_N, M_N, 2.0f);
    g.addI = -1.0f;
    run_g(stream, true, false, g, M_N, M_N, 1, nullptr);
    g = mkg(T2i, M_N, T2i, M_N, T4i, M_N, M_N, 2.0f);
    g.addI = -1.0f;
    run_g(stream, true, false, g, M_N, M_N, 1, nullptr);
    g = mkg(T2i, M_N, T4i, M_N, F6i, M_N, M_N, 2.0f);
    g.C1 = T2i; g.b1 = -1.0f; g.ldc1 = M_N;
    run_g(stream, true, false, g, M_N, M_N, 1, nullptr);
    g = mkg(F6i, M_N, F6i, M_N, F12i, M_N, M_N, 2.0f);
    g.addI = -1.0f;
    run_g(stream, true, false, g, M_N, M_N, 1, nullptr);
  }

  // 6) Inner: 1 segment {V <- F12 @ V ; CholQR-128}
  hipLaunchKernelGGL(inits_k, dim3((M_N * K_N + 255) / 256), dim3(256), 0, stream,
                     VA, M_N * K_N, 777u);
  {
    GArgs g = mkg(F12i, M_N, VA, K_N, VB, K_N, M_N, 1.0f);
    run_g(stream, true, false, g, M_N, K_N, 1, nullptr);
    g = mkg(VB, K_N, VB, K_N, G128, K_N, M_N, 1.0f);
    run_g(stream, true, false, g, K_N, K_N, 1, nullptr);
    hipLaunchKernelGGL(chol128_k, dim3(1), dim3(256), 0, stream,
                       G128, K_N, Li128, (double*)nullptr, (float*)nullptr);
    g = mkg(VB, K_N, Li128, K_N, VA, K_N, K_N, 1.0f);
    run_g(stream, false, false, g, M_N, K_N, 1, nullptr);
  }

  // 7) W = S*V, exact CholQR-128 on W (CholQR2 pattern: fixes mid-QR drift)
  {
    GArgs g = mkg(Scur, M_N, VA, K_N, Wa, K_N, M_N, 1.0f);
    run_g(stream, false, false, g, D_N, K_N, 1, nullptr);
    g = mkg(Wa, K_N, Wa, K_N, G128, K_N, D_N, 1.0f);
    run_g(stream, true, false, g, K_N, K_N, gks, Ppart);
    hipLaunchKernelGGL(chol128_k, dim3(1), dim3(256), 0, stream,
                       G128, K_N, Li128, (double*)nullptr, (float*)nullptr);
    g = mkg(Wa, K_N, Li128, K_N, Wb, K_N, K_N, 1.0f);
    run_g(stream, false, false, g, D_N, K_N, 1, nullptr);
  }

  // 8) z = x W - 1 (m^T W)
  hipLaunchKernelGGL(mw_k, dim3(1), dim3(128), 0, stream, m, Wb, mW);
  {
    GArgs g = mkg(x, D_N, Wb, K_N, z, K_N, D_N, 1.0f);
    g.radd = mW; g.raddc = -1.0f;
    run_g(stream, false, false, g, B_N, K_N, KS, Ppart);
  }

  // 9) sort rows by label; gather into zs
  hipLaunchKernelGGL(count_sort_k, dim3(1), dim3(256), 0, stream,
                     lab, perm, counts, offs);
  hipLaunchKernelGGL(gather_k, dim3(B_N * 32 / 256), dim3(256), 0, stream,
                     z, perm, zs);

  // 10) label and global column sums
  hipLaunchKernelGGL(labstat_part_k, dim3(11 * 8), dim3(128), 0, stream,
                     zs, offs, partL);
  hipLaunchKernelGGL(labstat_comb_k, dim3(1), dim3(128), 0, stream,
                     partL, sumMu, muT);

  // 11) per-label Sigma sums; SigT; Sinv + logdet
  hipLaunchKernelGGL(sigsum_k, dim3(NLAB * 4), dim3(256), 0, stream,
                     zs, offs, muT, SigS);
  hipLaunchKernelGGL(sigt_comb_k, dim3(64), dim3(256), 0, stream, SigS, SigT);
  hipLaunchKernelGGL(chol128_k, dim3(1), dim3(256), 0, stream,
                     SigT, K_N, (float*)nullptr, logdet_t, Sinv);

  // 12) per-label KL, reduce
  hipLaunchKernelGGL(perlabel_k, dim3(NLAB), dim3(256), 0, stream,
                     SigS, Sinv, muT, sumMu, counts, logdet_t, klv, present);
  hipLaunchKernelGGL(finalize_k, dim3(1), dim3(64), 0, stream, klv, present, out);
}

// Round 7
// 2500.242 us; speedup vs baseline: 39.8431x; 1.4305x over previous
//
#include <hip/hip_runtime.h>
#include <hip/hip_bf16.h>
#include <math.h>

// ============================================================================
// GMMLoss2_pca v7: blocked register-panel LDL^T Cholesky (NB=16, one-wave
// shuffle panel + GEMM-style rank-16 trailing update, 512 threads) to kill the
// LDS-latency-chain bottleneck measured in v5/v6. Pipeline otherwise = v6:
// outer 2xT6 / inner 1xT12 Chebyshev filter matrices, split-K GEMMs.
// ============================================================================

#define B_N 8192
#define D_N 1024
#define K_N 128
#define M_N 256
#define NLAB 10

__device__ __forceinline__ float hashf(unsigned x) {
  x ^= x >> 16; x *= 0x7feb352du; x ^= x >> 15; x *= 0x846ca68bu; x ^= x >> 16;
  return (float)(x >> 8) * (1.0f / 16777216.0f) - 0.5f;
}

// ---------------------------------------------------------------------------
// Tiled f32 GEMM (validated v4-v6): C[i][j] = alpha * sum_k A(k,i)*B(k,j)
// [+ epilogue if ks==1; split-K partial mode otherwise]
// ---------------------------------------------------------------------------
struct GArgs {
  const float* A; const float* B; float* C;
  int lda, ldb, ldc, K;
  float alpha;
  const float* C1; float b1; int ldc1;
  const float* C2; float b2; int ldc2;
  const float* r1u; const float* r1v; float r1c;
  const float* radd; float raddc;
  float addI;
  float* Cp; size_t mn; int pn;      // partial-mode
  float* out2; float sc2, dg2;       // second output (combine only)
};

template <bool AKM, bool BT>
__global__ __launch_bounds__(256)
void gemm_k(GArgs g) {
  __shared__ __align__(16) float AsRaw[2304]; // AKM: [32][68]; !AKM: [64][36]
  __shared__ __align__(16) float Bs[2176];    // [32][68]
  const int tid = threadIdx.x;
  const int tx = tid & 15, ty = tid >> 4;
  const int i0 = blockIdx.x * 64, j0 = blockIdx.y * 64;
  const int ks = gridDim.z;
  const int Kc = g.K / ks;
  const int kbeg = blockIdx.z * Kc, kend = kbeg + Kc;
  float acc[4][4] = {};
  for (int k0 = kbeg; k0 < kend; k0 += 32) {
    if (AKM) {
#pragma unroll
      for (int p = 0; p < 2; ++p) {
        int f4 = tid + p * 256;
        int kk = f4 >> 4, i4 = f4 & 15;
        *(float4*)(AsRaw + kk * 68 + i4 * 4) =
            *(const float4*)(g.A + (size_t)(k0 + kk) * g.lda + i0 + i4 * 4);
      }
    } else {
#pragma unroll
      for (int p = 0; p < 2; ++p) {
        int f4 = tid + p * 256;
        int ii = f4 >> 3, k4 = f4 & 7;
        *(float4*)(AsRaw + ii * 36 + k4 * 4) =
            *(const float4*)(g.A + (size_t)(i0 + ii) * g.lda + k0 + k4 * 4);
      }
    }
    if (BT) {
#pragma unroll
      for (int p = 0; p < 8; ++p) {
        int idx = tid + p * 256;
        int jj = idx >> 5, kk = idx & 31;
        Bs[kk * 68 + jj] = g.B[(size_t)(j0 + jj) * g.ldb + k0 + kk];
      }
    } else {
#pragma unroll
      for (int p = 0; p < 2; ++p) {
        int f4 = tid + p * 256;
        int kk = f4 >> 4, j4 = f4 & 15;
        *(float4*)(Bs + kk * 68 + j4 * 4) =
            *(const float4*)(g.B + (size_t)(k0 + kk) * g.ldb + j0 + j4 * 4);
      }
    }
    __syncthreads();
#pragma unroll 8
    for (int kk = 0; kk < 32; ++kk) {
      float ra[4], rb[4];
      if (AKM) {
        const float4 va = *(const float4*)(AsRaw + kk * 68 + ty * 4);
        ra[0] = va.x; ra[1] = va.y; ra[2] = va.z; ra[3] = va.w;
      } else {
#pragma unroll
        for (int r = 0; r < 4; ++r) ra[r] = AsRaw[(ty * 4 + r) * 36 + kk];
      }
      const float4 vb = *(const float4*)(Bs + kk * 68 + tx * 4);
      rb[0] = vb.x; rb[1] = vb.y; rb[2] = vb.z; rb[3] = vb.w;
#pragma unroll
      for (int r = 0; r < 4; ++r)
#pragma unroll
        for (int c = 0; c < 4; ++c) acc[r][c] += ra[r] * rb[c];
    }
    __syncthreads();
  }
  if (ks > 1) {
    float* dst = g.Cp + (size_t)blockIdx.z * g.mn;
#pragma unroll
    for (int r = 0; r < 4; ++r)
#pragma unroll
      for (int c = 0; c < 4; ++c) {
        int gi = i0 + ty * 4 + r, gj = j0 + tx * 4 + c;
        dst[(size_t)gi * g.pn + gj] = g.alpha * acc[r][c];
      }
  } else {
#pragma unroll
    for (int r = 0; r < 4; ++r)
#pragma unroll
      for (int c = 0; c < 4; ++c) {
        int gi = i0 + ty * 4 + r, gj = j0 + tx * 4 + c;
        float v = g.alpha * acc[r][c];
        if (g.C1) v += g.b1 * g.C1[(size_t)gi * g.ldc1 + gj];
        if (g.C2) v += g.b2 * g.C2[(size_t)gi * g.ldc2 + gj];
        if (g.r1u) v += g.r1c * g.r1u[gi] * g.r1v[gj];
        if (g.radd) v += g.raddc * g.radd[gj];
        if (g.addI != 0.0f && gi == gj) v += g.addI;
        g.C[(size_t)gi * g.ldc + gj] = v;
      }
  }
}

// Deterministic split-K combine with full epilogue (+ optional 2nd output).
struct CArgs {
  const float* P; float* C; size_t mn; int N, ldc, ks;
  const float* C1; float b1; int ldc1;
  const float* C2; float b2; int ldc2;
  const float* r1u; const float* r1v; float r1c;
  const float* radd; float raddc;
  float addI;
  float* out2; float sc2, dg2;
};

__global__ __launch_bounds__(256)
void combine_k(CArgs c) {
  size_t idx = (size_t)blockIdx.x * 256 + threadIdx.x;
  if (idx >= c.mn) return;
  int i = (int)(idx / c.N), j = (int)(idx % c.N);
  float s = 0.0f;
  for (int z = 0; z < c.ks; ++z) s += c.P[(size_t)z * c.mn + idx];
  if (c.C1) s += c.b1 * c.C1[(size_t)i * c.ldc1 + j];
  if (c.C2) s += c.b2 * c.C2[(size_t)i * c.ldc2 + j];
  if (c.r1u) s += c.r1c * c.r1u[i] * c.r1v[j];
  if (c.radd) s += c.raddc * c.radd[j];
  if (c.addI != 0.0f && i == j) s += c.addI;
  c.C[(size_t)i * c.ldc + j] = s;
  if (c.out2) c.out2[(size_t)i * c.N + j] = s * c.sc2 + ((i == j) ? c.dg2 : 0.0f);
}

__global__ __launch_bounds__(256)
void scaleshift_k(const float* in, float* out, int n, float sc, float dg) {
  size_t idx = (size_t)blockIdx.x * 256 + threadIdx.x;
  if (idx >= (size_t)n * n) return;
  int i = (int)(idx / n), j = (int)(idx % n);
  out[idx] = in[idx] * sc + ((i == j) ? dg : 0.0f);
}

__global__ __launch_bounds__(256)
void symscale_k(const float* in, float* out, int n, float sc, float dg) {
  size_t idx = (size_t)blockIdx.x * 256 + threadIdx.x;
  if (idx >= (size_t)n * n) return;
  int i = (int)(idx / n), j = (int)(idx % n);
  out[idx] = 0.5f * (in[idx] + in[(size_t)j * n + i]) * sc + ((i == j) ? dg : 0.0f);
}

// ---------------------------------------------------------------------------
__global__ __launch_bounds__(256)
void colmean_part_k(const float* x, double* part) {
  int col = blockIdx.x * 256 + threadIdx.x;
  int rs = blockIdx.y;
  double acc = 0.0;
  for (int r = rs * 512; r < (rs + 1) * 512; ++r)
    acc += (double)x[(size_t)r * D_N + col];
  part[(size_t)rs * D_N + col] = acc;
}

__global__ __launch_bounds__(256)
void colmean_comb_k(const double* part, float* m) {
  int col = blockIdx.x * 256 + threadIdx.x;
  double acc = 0.0;
  for (int rs = 0; rs < 16; ++rs) acc += part[(size_t)rs * D_N + col];
  m[col] = (float)(acc / (double)B_N);
}

__global__ void inits_k(float* S, int n, unsigned seed) {
  int i = blockIdx.x * 256 + threadIdx.x;
  if (i < n) S[i] = hashf((unsigned)i * 2654435761u + seed);
}

// ---------------------------------------------------------------------------
// chol128 v2: blocked LDL^T (NB=16). Panel factored in registers by wave 0
// (lane L owns rows L, L+64; pivot/column broadcast via __shfl — lockstep, no
// barriers). Trailing rank-16 update GEMM-style with unrolled q-loop.
// Then L recovery (L = U * sqrt(D)), 2x2-blocked triangular inverse,
// optional logdet (= sum log D_j) and Sinv = Linv^T Linv. 512 threads.
// ---------------------------------------------------------------------------
__global__ __launch_bounds__(512)
void chol128_k(const float* Gin, int ldg, float* LinvT, double* logdet, float* Sinv) {
  __shared__ float A[128][132];
  __shared__ float Bm[128][132];
  __shared__ float Y[64][66];
  __shared__ float Dsh[128];
  __shared__ float sqv[128];
  const int tid = threadIdx.x;
  for (int idx = tid; idx < 128 * 128; idx += 512)
    A[idx >> 7][idx & 127] = Gin[(size_t)(idx >> 7) * ldg + (idx & 127)];
  for (int idx = tid; idx < 128 * 132; idx += 512)
    (&Bm[0][0])[idx] = 0.0f;
  __syncthreads();
  for (int b = 0; b < 8; ++b) {
    const int o = b * 16;
    if (tid < 64) {
      const int lane = tid;
      float ra[16], rb[16], Dv[16];
#pragma unroll
      for (int q = 0; q < 16; ++q) {
        ra[q] = A[lane][o + q];
        rb[q] = A[lane + 64][o + q];
      }
#pragma unroll
      for (int jj = 0; jj < 16; ++jj) {
        const int c = o + jj;
        float pj = (c < 64) ? __shfl(ra[jj], c) : __shfl(rb[jj], c - 64);
        pj = fmaxf(pj, 1e-30f);
        Dv[jj] = pj;
        const float rdj = 1.0f / pj;
        const float ua = ra[jj] * rdj;
        const float ub = rb[jj] * rdj;
#pragma unroll
        for (int t = jj + 1; t < 16; ++t) {
          const int rt = o + t;
          float atj = (rt < 64) ? __shfl(ra[jj], rt) : __shfl(rb[jj], rt - 64);
          ra[t] -= ua * atj;
          rb[t] -= ub * atj;
        }
        ra[jj] = ua; rb[jj] = ub;
      }
#pragma unroll
      for (int q = 0; q < 16; ++q) {
        A[lane][o + q] = ra[q];
        A[lane + 64][o + q] = rb[q];
      }
      if (lane < 16) Dsh[o + lane] = Dv[lane];
    }
    __syncthreads();
    if (o + 16 < 128) {
      const int tx = tid & 15, ty = tid >> 4;  // 16 x 32 thread grid
      for (int i = o + 16 + ty; i < 128; i += 32) {
        float w[16];
#pragma unroll
        for (int q = 0; q < 16; ++q) w[q] = A[i][o + q] * Dsh[o + q];
        for (int t = o + 16 + tx; t <= i; t += 16) {
          float s = A[i][t];
#pragma unroll
          for (int q = 0; q < 16; ++q) s -= w[q] * A[t][o + q];
          A[i][t] = s;
        }
      }
    }
    __syncthreads();
  }
  if (logdet && tid == 0) {
    double s = 0.0;
    for (int j = 0; j < 128; ++j) s += log((double)Dsh[j]);
    *logdet = s;
  }
  if (tid < 128) sqv[tid] = sqrtf(Dsh[tid]);
  __syncthreads();
  // Recover chol L: L[i][j] = U[i][j] * sqrt(D_j)  (diag U = 1)
  for (int idx = tid; idx < 128 * 128; idx += 512) {
    int i = idx >> 7, j = idx & 127;
    if (j <= i) A[i][j] *= sqv[j];
  }
  __syncthreads();
  // Blocked inverse: L=[[L00,0],[L10,L11]]; Bm[c][i] = Linv[i][c]
  if (tid < 128) {
    const int ob = (tid >> 6) * 64;
    const int c = tid & 63;
    for (int i = c; i < 64; ++i) {
      float s = (i == c) ? 1.0f : 0.0f;
      for (int t = c; t < i; ++t) s -= A[ob + i][ob + t] * Bm[ob + c][ob + t];
      Bm[ob + c][ob + i] = s / A[ob + i][ob + i];
    }
  }
  __syncthreads();
  for (int idx = tid; idx < 64 * 64; idx += 512) {
    int t = idx >> 6, c = idx & 63;
    float s = 0.0f;
    for (int s2 = c; s2 < 64; ++s2) s += A[64 + t][s2] * Bm[c][s2];
    Y[t][c] = s;
  }
  __syncthreads();
  for (int idx = tid; idx < 64 * 64; idx += 512) {
    int a = idx >> 6, c = idx & 63;
    float s = 0.0f;
    for (int t = 0; t <= a; ++t) s -= Bm[64 + t][64 + a] * Y[t][c];
    Bm[c][64 + a] = s;
  }
  __syncthreads();
  if (LinvT)
    for (int idx = tid; idx < 128 * 128; idx += 512)
      LinvT[idx] = Bm[idx >> 7][idx & 127];
  if (Sinv)
    for (int idx = tid; idx < 128 * 128; idx += 512) {
      int i = idx >> 7, j = idx & 127;
      int t0 = (i > j) ? i : j;
      float s = 0.0f;
      for (int t = t0; t < 128; ++t) s += Bm[i][t] * Bm[j][t];
      Sinv[idx] = s;
    }
}

__global__ __launch_bounds__(128)
void mw_k(const float* m, const float* W, float* mW) {
  int j = threadIdx.x;
  double acc = 0.0;
  for (int c = 0; c < D_N; ++c) acc += (double)m[c] * (double)W[(size_t)c * K_N + j];
  mW[j] = (float)acc;
}

// ---------------------------------------------------------------------------
__global__ __launch_bounds__(256)
void count_sort_k(const int* lab, int* perm, int* counts, int* offs) {
  __shared__ int cnt[NLAB][256];
  __shared__ int labOff[NLAB + 1];
  const int tid = threadIdx.x;
  int lc[NLAB];
#pragma unroll
  for (int l = 0; l < NLAB; ++l) lc[l] = 0;
  for (int r = tid * 32; r < tid * 32 + 32; ++r) {
    int l = lab[r]; l = (l < 0) ? 0 : (l > 9 ? 9 : l);
    lc[l]++;
  }
#pragma unroll
  for (int l = 0; l < NLAB; ++l) cnt[l][tid] = lc[l];
  __syncthreads();
  if (tid < NLAB) {
    int run = 0;
    for (int i = 0; i < 256; ++i) { int v = cnt[tid][i]; cnt[tid][i] = run; run += v; }
    counts[tid] = run;
  }
  __syncthreads();
  if (tid == 0) {
    int run = 0;
    for (int l = 0; l < NLAB; ++l) { labOff[l] = run; run += counts[l]; }
    labOff[NLAB] = run;
    for (int l = 0; l <= NLAB; ++l) offs[l] = labOff[l];
  }
  __syncthreads();
  int lc2[NLAB];
#pragma unroll
  for (int l = 0; l < NLAB; ++l) lc2[l] = 0;
  for (int r = tid * 32; r < tid * 32 + 32; ++r) {
    int l = lab[r]; l = (l < 0) ? 0 : (l > 9 ? 9 : l);
    int pos = labOff[l] + cnt[l][tid] + lc2[l];
    lc2[l]++;
    perm[pos] = r;
  }
}

__global__ __launch_bounds__(256)
void gather_k(const float* z, const int* perm, float* zs) {
  int g = blockIdx.x * 256 + threadIdx.x;
  int row = g >> 5, q = g & 31;
  const float4* zf = (const float4*)z;
  float4* of = (float4*)zs;
  of[(size_t)row * 32 + q] = zf[(size_t)perm[row] * 32 + q];
}

__global__ __launch_bounds__(128)
void labstat_part_k(const float* zs, const int* offs, double* part) {
  int l = blockIdx.x >> 3, s = blockIdx.x & 7;
  int j = threadIdx.x;
  int r0, r1;
  if (l < NLAB) {
    int st = offs[l], en = offs[l + 1], len = en - st;
    r0 = st + (int)(((long long)len * s) >> 3);
    r1 = st + (int)(((long long)len * (s + 1)) >> 3);
  } else {
    r0 = s * 1024; r1 = r0 + 1024;
  }
  double acc = 0.0;
  for (int r = r0; r < r1; ++r) acc += (double)zs[(size_t)r * K_N + j];
  part[((size_t)l * 8 + s) * K_N + j] = acc;
}

__global__ __launch_bounds__(128)
void labstat_comb_k(const double* part, float* sum_mu, float* muT) {
  int j = threadIdx.x;
  for (int l = 0; l < NLAB; ++l) {
    double a = 0.0;
    for (int s = 0; s < 8; ++s) a += part[((size_t)l * 8 + s) * K_N + j];
    sum_mu[l * K_N + j] = (float)a;
  }
  double t = 0.0;
  for (int s = 0; s < 8; ++s) t += part[((size_t)NLAB * 8 + s) * K_N + j];
  muT[j] = (float)(t / (double)B_N);
}

__global__ __launch_bounds__(256)
void sigsum_k(const float* zs, const int* offs, const float* muT, float* SigS) {
  int l = blockIdx.x >> 2, t = blockIdx.x & 3;
  int i0 = (t >> 1) * 64, j0 = (t & 1) * 64;
  __shared__ float Zi[32][66], Zj[32][66];
  __shared__ float muL[128];
  int tid = threadIdx.x, tx = tid & 15, ty = tid >> 4;
  if (tid < 128) muL[tid] = muT[tid];
  __syncthreads();
  int start = offs[l], end = offs[l + 1];
  float acc[4][4] = {};
  for (int base = start; base < end; base += 32) {
#pragma unroll
    for (int p = 0; p < 8; ++p) {
      int idx = tid + p * 256;
      int rr = idx >> 6, cc = idx & 63;
      int r = base + rr;
      float vi = 0.0f, vj = 0.0f;
      if (r < end) {
        vi = zs[(size_t)r * K_N + i0 + cc] - muL[i0 + cc];
        vj = zs[(size_t)r * K_N + j0 + cc] - muL[j0 + cc];
      }
      Zi[rr][cc] = vi; Zj[rr][cc] = vj;
    }
    __syncthreads();
    for (int rr = 0; rr < 32; ++rr) {
      float ra[4], rb[4];
#pragma unroll
      for (int r = 0; r < 4; ++r) ra[r] = Zi[rr][ty * 4 + r];
#pragma unroll
      for (int c = 0; c < 4; ++c) rb[c] = Zj[rr][tx * 4 + c];
#pragma unroll
      for (int r = 0; r < 4; ++r)
#pragma unroll
        for (int c = 0; c < 4; ++c) acc[r][c] += ra[r] * rb[c];
    }
    __syncthreads();
  }
#pragma unroll
  for (int r = 0; r < 4; ++r)
#pragma unroll
    for (int c = 0; c < 4; ++c)
      SigS[((size_t)l * K_N + i0 + ty * 4 + r) * K_N + j0 + tx * 4 + c] = acc[r][c];
}

__global__ __launch_bounds__(256)
void sigt_comb_k(const float* SigS, float* SigT) {
  int idx = blockIdx.x * 256 + threadIdx.x;
  int i = idx >> 7, j = idx & 127;
  double s = 0.0;
  for (int l = 0; l < NLAB; ++l) s += (double)SigS[(size_t)l * 16384 + idx];
  SigT[idx] = (float)(s / (double)B_N) + ((i == j) ? 1.0f : 0.0f);
}

// ---------------------------------------------------------------------------
// Per-label KL: tr/maha (f64 reductions) + blocked LDL^T logdet. 512 threads.
// ---------------------------------------------------------------------------
__global__ __launch_bounds__(512)
void perlabel_k(const float* SigS, const float* Sinv, const float* mu,
                const float* sum_mu, const int* counts, const double* logdet_t,
                double* klout, int* present) {
  int l = blockIdx.x, tid = threadIdx.x;
  __shared__ float Amat[128][132];
  __shared__ double red[512];
  __shared__ float dv[128];
  __shared__ float Dsh[128];
  int cnt = counts[l];
  float sc = (cnt > 0) ? (float)cnt : 1.0f;
  for (int idx = tid; idx < 128 * 128; idx += 512) {
    int i = idx >> 7, j = idx & 127;
    Amat[i][j] = SigS[((size_t)l * K_N + i) * K_N + j] / sc + ((i == j) ? 1.0f : 0.0f);
  }
  if (tid < 128) dv[tid] = mu[tid] - sum_mu[l * K_N + tid] / sc;
  __syncthreads();
  double tr = 0.0, mh = 0.0;
  for (int idx = tid; idx < 128 * 128; idx += 512) {
    int i = idx >> 7, j = idx & 127;
    double sv = (double)Sinv[idx];
    tr += sv * (double)Amat[i][j];
    mh += sv * (double)dv[i] * (double)dv[j];
  }
  red[tid] = tr; __syncthreads();
  for (int off = 256; off > 0; off >>= 1) { if (tid < off) red[tid] += red[tid + off]; __syncthreads(); }
  double trv = red[0]; __syncthreads();
  red[tid] = mh; __syncthreads();
  for (int off = 256; off > 0; off >>= 1) { if (tid < off) red[tid] += red[tid + off]; __syncthreads(); }
  double mhv = red[0]; __syncthreads();
  // Blocked LDL^T (logdet only)
  for (int b = 0; b < 8; ++b) {
    const int o = b * 16;
    if (tid < 64) {
      const int lane = tid;
      float ra[16], rb[16], Dv[16];
#pragma unroll
      for (int q = 0; q < 16; ++q) {
        ra[q] = Amat[lane][o + q];
        rb[q] = Amat[lane + 64][o + q];
      }
#pragma unroll
      for (int jj = 0; jj < 16; ++jj) {
        const int c = o + jj;
        float pj = (c < 64) ? __shfl(ra[jj], c) : __shfl(rb[jj], c - 64);
        pj = fmaxf(pj, 1e-30f);
        Dv[jj] = pj;
        const float rdj = 1.0f / pj;
        const float ua = ra[jj] * rdj;
        const float ub = rb[jj] * rdj;
#pragma unroll
        for (int t = jj + 1; t < 16; ++t) {
          const int rt = o + t;
          float atj = (rt < 64) ? __shfl(ra[jj], rt) : __shfl(rb[jj], rt - 64);
          ra[t] -= ua * atj;
          rb[t] -= ub * atj;
        }
        ra[jj] = ua; rb[jj] = ub;
      }
#pragma unroll
      for (int q = 0; q < 16; ++q) {
        Amat[lane][o + q] = ra[q];
        Amat[lane + 64][o + q] = rb[q];
      }
      if (lane < 16) Dsh[o + lane] = Dv[lane];
    }
    __syncthreads();
    if (o + 16 < 128) {
      const int tx = tid & 15, ty = tid >> 4;
      for (int i = o + 16 + ty; i < 128; i += 32) {
        float w[16];
#pragma unroll
        for (int q = 0; q < 16; ++q) w[q] = Amat[i][o + q] * Dsh[o + q];
        for (int t = o + 16 + tx; t <= i; t += 16) {
          float s = Amat[i][t];
#pragma unroll
          for (int q = 0; q < 16; ++q) s -= w[q] * Amat[t][o + q];
          Amat[i][t] = s;
        }
      }
    }
    __syncthreads();
  }
  if (tid == 0) {
    double ld = 0.0;
    for (int j = 0; j < 128; ++j) ld += log((double)Dsh[j]);
    klout[l] = 0.5 * (trv + mhv - 128.0 + logdet_t[0] - ld);
    present[l] = (cnt > 0) ? 1 : 0;
  }
}

__global__ void finalize_k(const double* kl, const int* present, float* out) {
  if (threadIdx.x == 0 && blockIdx.x == 0) {
    double s = 0.0; int np = 0;
    for (int l = 0; l < NLAB; ++l)
      if (present[l]) { s += kl[l]; np++; }
    out[0] = (float)((np > 0) ? s / ((double)np * (double)B_N) : 0.0);
  }
}

// ===========================================================================
// Host side
// ===========================================================================
static inline GArgs mkg(const float* A, int lda, const float* B, int ldb,
                        float* C, int ldc, int K, float alpha) {
  GArgs g{};
  g.A = A; g.B = B; g.C = C; g.lda = lda; g.ldb = ldb; g.ldc = ldc;
  g.K = K; g.alpha = alpha;
  return g;
}

static inline void run_g(hipStream_t st, bool akm, bool bt, GArgs g,
                         int M, int N, int ks, float* Ppart) {
  if (ks > 1) {
    g.Cp = Ppart; g.mn = (size_t)M * N; g.pn = N;
    dim3 grid(M / 64, N / 64, ks);
    if (akm)     hipLaunchKernelGGL((gemm_k<true, false>),  grid, dim3(256), 0, st, g);
    else if (bt) hipLaunchKernelGGL((gemm_k<false, true>),  grid, dim3(256), 0, st, g);
    else         hipLaunchKernelGGL((gemm_k<false, false>), grid, dim3(256), 0, st, g);
    CArgs c{Ppart, g.C, (size_t)M * N, N, g.ldc, ks,
            g.C1, g.b1, g.ldc1, g.C2, g.b2, g.ldc2,
            g.r1u, g.r1v, g.r1c, g.radd, g.raddc, g.addI,
            g.out2, g.sc2, g.dg2};
    hipLaunchKernelGGL(combine_k, dim3((unsigned)(((size_t)M * N + 255) / 256)),
                       dim3(256), 0, st, c);
  } else {
    dim3 grid(M / 64, N / 64);
    if (akm)     hipLaunchKernelGGL((gemm_k<true, false>),  grid, dim3(256), 0, st, g);
    else if (bt) hipLaunchKernelGGL((gemm_k<false, true>),  grid, dim3(256), 0, st, g);
    else         hipLaunchKernelGGL((gemm_k<false, false>), grid, dim3(256), 0, st, g);
  }
}

extern "C" void kernel_launch(void* const* d_in, const int* in_sizes, int n_in,
                              void* d_out, int out_size, void* d_ws, size_t ws_size,
                              hipStream_t stream) {
  const float* x = (const float*)d_in[0];
  const int* lab = (const int*)d_in[1];
  float* out = (float*)d_out;

  size_t off = 0;
  auto alloc = [&](size_t nbytes) -> void* {
    void* r = (void*)((char*)d_ws + off);
    off += ((nbytes + 255) / 256) * 256;
    return r;
  };
  float*  m     = (float*) alloc(D_N * 4);
  float*  Cn    = (float*) alloc((size_t)D_N * D_N * 4);
  float*  At    = (float*) alloc((size_t)D_N * D_N * 4);  // Atilde -> T4 -> zs
  float*  T2    = (float*) alloc((size_t)D_N * D_N * 4);  // T2 -> z
  float*  Fo    = (float*) alloc((size_t)D_N * D_N * 4);  // outer filter T6
  float*  SA    = (float*) alloc((size_t)D_N * M_N * 4);
  float*  SB    = (float*) alloc((size_t)D_N * M_N * 4);
  float*  SC    = (float*) alloc((size_t)D_N * M_N * 4);
  float*  G256  = (float*) alloc((size_t)M_N * M_N * 4);  // -> F12i
  float*  Tm    = (float*) alloc((size_t)M_N * M_N * 4);
  float*  Li11T = (float*) alloc((size_t)K_N * K_N * 4);
  float*  Li22T = (float*) alloc((size_t)K_N * K_N * 4);
  float*  L21b  = (float*) alloc((size_t)K_N * K_N * 4);
  float*  S22b  = (float*) alloc((size_t)K_N * K_N * 4);
  float*  Pb    = (float*) alloc((size_t)K_N * K_N * 4);
  float*  XTb   = (float*) alloc((size_t)K_N * K_N * 4);
  float*  Tt    = (float*) alloc((size_t)M_N * M_N * 4);
  float*  T2i   = (float*) alloc((size_t)M_N * M_N * 4);
  float*  T4i   = (float*) alloc((size_t)M_N * M_N * 4);
  float*  F6i   = (float*) alloc((size_t)M_N * M_N * 4);
  float*  VA    = (float*) alloc((size_t)M_N * K_N * 4);
  float*  VB    = (float*) alloc((size_t)M_N * K_N * 4);
  float*  G128  = (float*) alloc((size_t)K_N * K_N * 4);
  float*  Li128 = (float*) alloc((size_t)K_N * K_N * 4);
  float*  Wa    = (float*) alloc((size_t)D_N * K_N * 4);
  float*  Wb    = (float*) alloc((size_t)D_N * K_N * 4);
  float*  mW    = (float*) alloc(K_N * 4);
  double* partM = (double*)alloc((size_t)16 * D_N * 8);
  double* partL = (double*)alloc((size_t)11 * 8 * K_N * 8);
  float*  sumMu = (float*) alloc(NLAB * K_N * 4);
  float*  muT   = (float*) alloc(K_N * 4);
  float*  SigT  = (float*) alloc((size_t)K_N * K_N * 4);
  float*  Sinv  = (float*) alloc((size_t)K_N * K_N * 4);
  float*  SigS  = (float*) alloc((size_t)NLAB * K_N * K_N * 4);
  double* logdet_t = (double*)alloc(16);
  double* klv      = (double*)alloc(NLAB * 8);
  int*    counts = (int*)alloc(16 * 4);
  int*    offs   = (int*)alloc(16 * 4);
  int*    present= (int*)alloc(16 * 4);
  int*    perm   = (int*)alloc(B_N * 4);
  float*  T4   = At;    // alias: At dead once T2 exists
  float*  F12i = G256;  // alias: G256 dead after outer segs
  float*  zs   = At;    // alias: T4 dead after Fo; zs written step 9
  float*  z    = T2;    // alias: T2 dead after Fo
  size_t rem = (ws_size > off) ? (ws_size - off) : 0;
  int KS = 1;
  if (rem >= (size_t)16 * 1024 * 1024 + 4096) KS = 4;
  else if (rem >= (size_t)8 * 1024 * 1024 + 4096) KS = 2;
  float* Ppart = (float*)alloc((size_t)KS * 4 * 1024 * 1024);
  const int gks = (KS == 4) ? 8 : KS;   // split factor for 256/128-sq Grams
  (void)in_sizes; (void)n_in; (void)out_size;

  // 1) column means; Cn = x^T x / B - m m^T ; At = 1.6*Cn - I (fused)
  hipLaunchKernelGGL(colmean_part_k, dim3(4, 16), dim3(256), 0, stream, x, partM);
  hipLaunchKernelGGL(colmean_comb_k, dim3(4), dim3(256), 0, stream, partM, m);
  {
    GArgs g = mkg(x, D_N, x, D_N, Cn, D_N, B_N, 1.0f / (float)B_N);
    g.r1u = m; g.r1v = m; g.r1c = -1.0f;
    if (KS > 1) { g.out2 = At; g.sc2 = 1.6f; g.dg2 = -1.0f; }
    run_g(stream, true, false, g, D_N, D_N, KS, Ppart);
    if (KS == 1)
      hipLaunchKernelGGL(scaleshift_k, dim3((D_N * D_N + 255) / 256), dim3(256),
                         0, stream, Cn, At, D_N, 1.6f, -1.0f);
  }

  // 2) Outer filter Fo = T6(At) = 2*T2*T4 - T2, band [0,1.25] (c=d=0.625)
  {
    GArgs g = mkg(At, D_N, At, D_N, T2, D_N, D_N, 2.0f);  // T2 = 2 At^2 - I
    g.addI = -1.0f;
    run_g(stream, true, false, g, D_N, D_N, KS, Ppart);
    g = mkg(T2, D_N, T2, D_N, T4, D_N, D_N, 2.0f);        // T4 = 2 T2^2 - I
    g.addI = -1.0f;
    run_g(stream, true, false, g, D_N, D_N, KS, Ppart);
    g = mkg(T2, D_N, T4, D_N, Fo, D_N, D_N, 2.0f);        // T6 = 2 T2 T4 - T2
    g.C1 = T2; g.b1 = -1.0f; g.ldc1 = D_N;
    run_g(stream, true, false, g, D_N, D_N, KS, Ppart);
  }

  // Blocked CholQR-256 (validated): S -> Snew
  auto qr256 = [&](float* S, float* Snew) {
    GArgs g = mkg(S, M_N, S, M_N, G256, M_N, D_N, 1.0f);
    run_g(stream, true, false, g, M_N, M_N, gks, Ppart);
    hipLaunchKernelGGL(chol128_k, dim3(1), dim3(512), 0, stream,
                       G256, M_N, Li11T, (double*)nullptr, (float*)nullptr);
    g = mkg(G256 + 128 * M_N, M_N, Li11T, K_N, L21b, K_N, K_N, 1.0f);
    run_g(stream, false, false, g, K_N, K_N, 1, nullptr);
    g = mkg(L21b, K_N, L21b, K_N, S22b, K_N, K_N, -1.0f);
    g.C1 = G256 + 128 * M_N + 128; g.b1 = 1.0f; g.ldc1 = M_N;
    run_g(stream, false, true, g, K_N, K_N, 1, nullptr);
    hipLaunchKernelGGL(chol128_k, dim3(1), dim3(512), 0, stream,
                       S22b, K_N, Li22T, (double*)nullptr, (float*)nullptr);
    g = mkg(L21b, K_N, Li11T, K_N, Pb, K_N, K_N, 1.0f);
    run_g(stream, false, true, g, K_N, K_N, 1, nullptr);
    g = mkg(Pb, K_N, Li22T, K_N, XTb, K_N, K_N, -1.0f);
    run_g(stream, true, false, g, K_N, K_N, 1, nullptr);
    g = mkg(S, M_N, Li11T, K_N, Snew, M_N, K_N, 1.0f);
    run_g(stream, false, false, g, D_N, K_N, 1, nullptr);
    g = mkg(S, M_N, XTb, K_N, Snew + 128, M_N, K_N, 1.0f);
    run_g(stream, false, false, g, D_N, K_N, 1, nullptr);
    g = mkg(S + 128, M_N, Li22T, K_N, Snew + 128, M_N, K_N, 1.0f);
    g.C1 = Snew + 128; g.b1 = 1.0f; g.ldc1 = M_N;
    run_g(stream, false, false, g, D_N, K_N, 1, nullptr);
  };

  // 3) Outer: 2 segments of {S <- Fo @ S ; CholQR-256}
  hipLaunchKernelGGL(inits_k, dim3((D_N * M_N + 255) / 256), dim3(256), 0, stream,
                     SA, D_N * M_N, 12345u);
  float* Scur = SA; float* t1 = SB; float* t2 = SC;
  for (int seg = 0; seg < 2; ++seg) {
    GArgs g = mkg(Fo, D_N, Scur, M_N, t1, M_N, D_N, 1.0f);
    run_g(stream, true, false, g, D_N, M_N, KS, Ppart);
    qr256(t1, t2);
    float* t = Scur; Scur = t2; t2 = t;
  }

  // 4) T = S^T (Cn S)
  {
    GArgs g = mkg(Cn, D_N, Scur, M_N, t1, M_N, D_N, 1.0f);
    run_g(stream, true, false, g, D_N, M_N, KS, Ppart);
    g = mkg(Scur, M_N, t1, M_N, Tm, M_N, D_N, 1.0f);
    run_g(stream, true, false, g, M_N, M_N, gks, Ppart);
  }

  // 5) Inner filter F12 = T12(Tt) = 2*T6(Tt)^2 - I, band [0,1.27] (c=d=0.635)
  hipLaunchKernelGGL(symscale_k, dim3((M_N * M_N + 255) / 256), dim3(256), 0,
                     stream, Tm, Tt, M_N, 1.0f / 0.635f, -1.0f);
  {
    GArgs g = mkg(Tt, M_N, Tt, M_N, T2i, M_N, M_N, 2.0f);
    g.addI = -1.0f;
    run_g(stream, true, false, g, M_N, M_N, 1, nullptr);
    g = mkg(T2i, M_N, T2i, M_N, T4i, M_N, M_N, 2.0f);
    g.addI = -1.0f;
    run_g(stream, true, false, g, M_N, M_N, 1, nullptr);
    g = mkg(T2i, M_N, T4i, M_N, F6i, M_N, M_N, 2.0f);
    g.C1 = T2i; g.b1 = -1.0f; g.ldc1 = M_N;
    run_g(stream, true, false, g, M_N, M_N, 1, nullptr);
    g = mkg(F6i, M_N, F6i, M_N, F12i, M_N, M_N, 2.0f);
    g.addI = -1.0f;
    run_g(stream, true, false, g, M_N, M_N, 1, nullptr);
  }

  // 6) Inner: 1 segment {V <- F12 @ V ; CholQR-128}
  hipLaunchKernelGGL(inits_k, dim3((M_N * K_N + 255) / 256), dim3(256), 0, stream,
                     VA, M_N * K_N, 777u);
  {
    GArgs g = mkg(F12i, M_N, VA, K_N, VB, K_N, M_N, 1.0f);
    run_g(stream, true, false, g, M_N, K_N, 1, nullptr);
    g = mkg(VB, K_N, VB, K_N, G128, K_N, M_N, 1.0f);
    run_g(stream, true, false, g, K_N, K_N, 1, nullptr);
    hipLaunchKernelGGL(chol128_k, dim3(1), dim3(512), 0, stream,
                       G128, K_N, Li128, (double*)nullptr, (float*)nullptr);
    g = mkg(VB, K_N, Li128, K_N, VA, K_N, K_N, 1.0f);
    run_g(stream, false, false, g, M_N, K_N, 1, nullptr);
  }

  // 7) W = S*V, exact CholQR-128 on W (CholQR2 pattern: fixes mid-QR drift)
  {
    GArgs g = mkg(Scur, M_N, VA, K_N, Wa, K_N, M_N, 1.0f);
    run_g(stream, false, false, g, D_N, K_N, 1, nullptr);
    g = mkg(Wa, K_N, Wa, K_N, G128, K_N, D_N, 1.0f);
    run_g(stream, true, false, g, K_N, K_N, gks, Ppart);
    hipLaunchKernelGGL(chol128_k, dim3(1), dim3(512), 0, stream,
                       G128, K_N, Li128, (double*)nullptr, (float*)nullptr);
    g = mkg(Wa, K_N, Li128, K_N, Wb, K_N, K_N, 1.0f);
    run_g(stream, false, false, g, D_N, K_N, 1, nullptr);
  }

  // 8) z = x W - 1 (m^T W)
  hipLaunchKernelGGL(mw_k, dim3(1), dim3(128), 0, stream, m, Wb, mW);
  {
    GArgs g = mkg(x, D_N, Wb, K_N, z, K_N, D_N, 1.0f);
    g.radd = mW; g.raddc = -1.0f;
    run_g(stream, false, false, g, B_N, K_N, KS, Ppart);
  }

  // 9) sort rows by label; gather into zs
  hipLaunchKernelGGL(count_sort_k, dim3(1), dim3(256), 0, stream,
                     lab, perm, counts, offs);
  hipLaunchKernelGGL(gather_k, dim3(B_N * 32 / 256), dim3(256), 0, stream,
                     z, perm, zs);

  // 10) label and global column sums
  hipLaunchKernelGGL(labstat_part_k, dim3(11 * 8), dim3(128), 0, stream,
                     zs, offs, partL);
  hipLaunchKernelGGL(labstat_comb_k, dim3(1), dim3(128), 0, stream,
                     partL, sumMu, muT);

  // 11) per-label Sigma sums; SigT; Sinv + logdet
  hipLaunchKernelGGL(sigsum_k, dim3(NLAB * 4), dim3(256), 0, stream,
                     zs, offs, muT, SigS);
  hipLaunchKernelGGL(sigt_comb_k, dim3(64), dim3(256), 0, stream, SigS, SigT);
  hipLaunchKernelGGL(chol128_k, dim3(1), dim3(512), 0, stream,
                     SigT, K_N, (float*)nullptr, logdet_t, Sinv);

  // 12) per-label KL, reduce
  hipLaunchKernelGGL(perlabel_k, dim3(NLAB), dim3(512), 0, stream,
                     SigS, Sinv, muT, sumMu, counts, logdet_t, klv, present);
  hipLaunchKernelGGL(finalize_k, dim3(1), dim3(64), 0, stream, klv, present, out);
}